// Round 3
// baseline (442.124 us; speedup 1.0000x reference)
//
#include <hip/hip_runtime.h>
#include <hip/hip_bf16.h>

typedef unsigned int uint32;
typedef float floatx2 __attribute__((ext_vector_type(2)));
typedef __attribute__((ext_vector_type(8))) short bf16x8;
typedef __attribute__((ext_vector_type(4))) float f32x4;

#define CHUNK 16384

// ============ bucketed CSR build (dst>>8 buckets, LDS-atomic sort) ============

__global__ __launch_bounds__(256) void k_bhist(const int* __restrict__ dst,
                                               int* __restrict__ bcnt,
                                               int E, int NBUCK, int NCH) {
    __shared__ int h[512];
    int c = blockIdx.x, tid = threadIdx.x;
    for (int i = tid; i < NBUCK; i += 256) h[i] = 0;
    __syncthreads();
    int base = c * CHUNK;
#pragma unroll
    for (int k = 0; k < CHUNK / 256; ++k) {
        int e = base + k * 256 + tid;
        if (e < E) atomicAdd(&h[dst[e] >> 8], 1);
    }
    __syncthreads();
    for (int i = tid; i < NBUCK; i += 256) bcnt[(size_t)i * NCH + c] = h[i];
}

__global__ __launch_bounds__(128) void k_bscan1(const int* __restrict__ bcnt,
                                                int* __restrict__ bofs,
                                                int* __restrict__ btot, int NCH) {
    __shared__ int tmp[128];
    int b = blockIdx.x, t = threadIdx.x;
    int v = (t < NCH) ? bcnt[(size_t)b * NCH + t] : 0;
    tmp[t] = v;
    __syncthreads();
    for (int off = 1; off < 128; off <<= 1) {
        int u = (t >= off) ? tmp[t - off] : 0;
        __syncthreads();
        tmp[t] += u;
        __syncthreads();
    }
    if (t < NCH) bofs[(size_t)b * NCH + t] = tmp[t] - v;
    if (t == 127) btot[b] = tmp[127];
}

__global__ __launch_bounds__(512) void k_bscan2(const int* __restrict__ btot,
                                                int* __restrict__ bbase, int nb) {
    __shared__ int tmp[512];
    int t = threadIdx.x;
    int v = (t < nb) ? btot[t] : 0;
    tmp[t] = v;
    __syncthreads();
    for (int off = 1; off < 512; off <<= 1) {
        int u = (t >= off) ? tmp[t - off] : 0;
        __syncthreads();
        tmp[t] += u;
        __syncthreads();
    }
    if (t < nb) bbase[t] = tmp[t] - v;
    if (t == nb - 1) bbase[nb] = tmp[t];
}

__global__ __launch_bounds__(256) void k_bscatter(const int* __restrict__ ei,
                                                  const int* __restrict__ bbase,
                                                  const int* __restrict__ bofs,
                                                  uint32* __restrict__ ebuf,
                                                  int E, int NBUCK, int NCH) {
    __shared__ int cur[512];
    int c = blockIdx.x, tid = threadIdx.x;
    for (int i = tid; i < NBUCK; i += 256)
        cur[i] = bbase[i] + bofs[(size_t)i * NCH + c];
    __syncthreads();
    int base = c * CHUNK;
#pragma unroll
    for (int k = 0; k < CHUNK / 256; ++k) {
        int e = base + k * 256 + tid;
        if (e < E) {
            int s = ei[e];
            int d = ei[E + e];
            int p = atomicAdd(&cur[d >> 8], 1);
            ebuf[p] = (uint32)s | ((uint32)(d & 255) << 20);
        }
    }
}

__global__ __launch_bounds__(256) void k_bsort(const uint32* __restrict__ ebuf,
                                               const int* __restrict__ bbase,
                                               int* __restrict__ ssrc,
                                               int* __restrict__ rowptr,
                                               int* __restrict__ counts,
                                               float* __restrict__ dinv, int N) {
    __shared__ int h[256];
    __shared__ int sc[256];
    __shared__ int cur[256];
    int b = blockIdx.x, tid = threadIdx.x;
    int beg = bbase[b], end = bbase[b + 1];
    h[tid] = 0;
    __syncthreads();
    for (int j = beg + tid; j < end; j += 256)
        atomicAdd(&h[(ebuf[j] >> 20) & 255], 1);
    __syncthreads();
    int v = h[tid];
    sc[tid] = v;
    __syncthreads();
    for (int off = 1; off < 256; off <<= 1) {
        int u = (tid >= off) ? sc[tid - off] : 0;
        __syncthreads();
        sc[tid] += u;
        __syncthreads();
    }
    int rowbase = beg + sc[tid] - v;
    cur[tid] = rowbase;
    int d = b * 256 + tid;
    if (d < N) {
        rowptr[d] = rowbase;
        counts[d] = v;
        dinv[d] = rsqrtf((float)(v + 1));   // +1 self loop
    }
    __syncthreads();
    for (int j = beg + tid; j < end; j += 256) {
        uint32 w = ebuf[j];
        int p = atomicAdd(&cur[(w >> 20) & 255], 1);
        ssrc[p] = (int)(w & 0xFFFFFu);
    }
}

// ============ fp32 -> bf16 (RNE) helpers ============

__device__ __forceinline__ short f2bf(float f) {
    __hip_bfloat16 b = __float2bfloat16(f);
    return __builtin_bit_cast(short, b);
}

__device__ __forceinline__ bf16x8 pack_bf16x8(float4 v0, float4 v1) {
    bf16x8 r;
    r[0] = f2bf(v0.x); r[1] = f2bf(v0.y); r[2] = f2bf(v0.z); r[3] = f2bf(v0.w);
    r[4] = f2bf(v1.x); r[5] = f2bf(v1.y); r[6] = f2bf(v1.z); r[7] = f2bf(v1.w);
    return r;
}

// ============ embed GEMM via MFMA: h = x @ We^T ([N,128] @ [128,64]^T) ============
// 4 waves/block; wave w computes rows [base + w*64, +64) x all 64 cols.
// No LDS: A-frags straight from global, B-frags (We, 32KB, L2-resident) in regs.
// Layouts (m89-verified family): A[lane&15][(lane>>4)*8+j], B[(lane>>4)*8+j][lane&15],
// D[(lane>>4)*4+r][lane&15].

__global__ __launch_bounds__(256) void k_embed(const float* __restrict__ x,
                                               const float* __restrict__ We,
                                               float* __restrict__ h, int N) {
    int lane = threadIdx.x & 63;
    int w = threadIdx.x >> 6;
    int l15 = lane & 15;
    int lg = lane >> 4;                       // 0..3

    // B fragments: B[ct][ks], col = ct*16 + l15, k = ks*32 + lg*8 + j
    bf16x8 B[4][4];
#pragma unroll
    for (int ct = 0; ct < 4; ++ct) {
        const float* wr = We + (size_t)(ct * 16 + l15) * 128 + lg * 8;
#pragma unroll
        for (int ks = 0; ks < 4; ++ks) {
            float4 v0 = *(const float4*)(wr + ks * 32);
            float4 v1 = *(const float4*)(wr + ks * 32 + 4);
            B[ct][ks] = pack_bf16x8(v0, v1);
        }
    }

    int rowbase = blockIdx.x * 256 + w * 64;

    f32x4 acc[4][4];
#pragma unroll
    for (int rt = 0; rt < 4; ++rt)
#pragma unroll
        for (int ct = 0; ct < 4; ++ct)
            acc[rt][ct] = (f32x4){0.f, 0.f, 0.f, 0.f};

#pragma unroll
    for (int ks = 0; ks < 4; ++ks) {
#pragma unroll
        for (int rt = 0; rt < 4; ++rt) {
            int row = rowbase + rt * 16 + l15;
            row = (row < N) ? row : (N - 1);          // clamp; stores predicated
            const float* xr = x + (size_t)row * 128 + ks * 32 + lg * 8;
            float4 v0 = *(const float4*)xr;
            float4 v1 = *(const float4*)(xr + 4);
            bf16x8 a = pack_bf16x8(v0, v1);
#pragma unroll
            for (int ct = 0; ct < 4; ++ct)
                acc[rt][ct] = __builtin_amdgcn_mfma_f32_16x16x32_bf16(
                    a, B[ct][ks], acc[rt][ct], 0, 0, 0);
        }
    }

#pragma unroll
    for (int rt = 0; rt < 4; ++rt) {
        int row0 = rowbase + rt * 16 + lg * 4;
#pragma unroll
        for (int r = 0; r < 4; ++r) {
            int row = row0 + r;
            if (row < N) {
#pragma unroll
                for (int ct = 0; ct < 4; ++ct)
                    h[(size_t)row * 64 + ct * 16 + l15] = acc[rt][ct][r];
            }
        }
    }
}

// ============ GCN layer GEMM: tab = fp8_e4m3((act(hin) @ Wg^T) * dinv) ============

__global__ __launch_bounds__(256) void k_gcn(const float* __restrict__ hin,
                                             const float* __restrict__ Wg,
                                             const float* __restrict__ bias_prev, int act,
                                             const float* __restrict__ dinv,
                                             uint32* __restrict__ tab, int N) {
    __shared__ float Ws[64 * 65];
    __shared__ float xs[32 * 64];
    int tid = threadIdx.x;

#pragma unroll
    for (int i = 0; i < 16; ++i) {
        int m = tid + i * 256;
        Ws[(m >> 6) * 65 + (m & 63)] = Wg[m];
    }
    int base = blockIdx.x * 32;
    const float4* hin4 = (const float4*)(hin + (size_t)base * 64);
#pragma unroll
    for (int i = 0; i < 2; ++i) {
        int m = tid + i * 256;
        float4 v = hin4[m];
        if (act) {
            int kf = (m & 15) * 4;
            v.x = fmaxf(v.x + bias_prev[kf + 0], 0.f);
            v.y = fmaxf(v.y + bias_prev[kf + 1], 0.f);
            v.z = fmaxf(v.z + bias_prev[kf + 2], 0.f);
            v.w = fmaxf(v.w + bias_prev[kf + 3], 0.f);
        }
        ((float4*)xs)[m] = v;
    }
    __syncthreads();

    int f = tid & 63, g = tid >> 6;
    float acc[8] = {0, 0, 0, 0, 0, 0, 0, 0};
#pragma unroll 4
    for (int k = 0; k < 64; k += 4) {
        float w0 = Ws[f * 65 + k + 0];
        float w1 = Ws[f * 65 + k + 1];
        float w2 = Ws[f * 65 + k + 2];
        float w3 = Ws[f * 65 + k + 3];
#pragma unroll
        for (int j = 0; j < 8; ++j) {
            const float4 xv = *(const float4*)&xs[(g * 8 + j) * 64 + k];
            acc[j] = fmaf(xv.x, w0, acc[j]);
            acc[j] = fmaf(xv.y, w1, acc[j]);
            acc[j] = fmaf(xv.z, w2, acc[j]);
            acc[j] = fmaf(xv.w, w3, acc[j]);
        }
    }

    // epilogue: stage fp32 result back into xs, then pack to fp8
    __syncthreads();
#pragma unroll
    for (int j = 0; j < 8; ++j) {
        int r = g * 8 + j;
        xs[r * 64 + f] = acc[j] * dinv[base + r];
    }
    __syncthreads();
#pragma unroll
    for (int i = 0; i < 2; ++i) {
        int m = tid + i * 256;          // 512 uints = 32 rows x 16
        int row = m >> 4, idx = m & 15;
        const float4 v = *(const float4*)&xs[row * 64 + idx * 4];
        int u = 0;
        u = __builtin_amdgcn_cvt_pk_fp8_f32(v.x, v.y, u, false);
        u = __builtin_amdgcn_cvt_pk_fp8_f32(v.z, v.w, u, true);
        tab[(size_t)(base + row) * 16 + idx] = u;
    }
}

// ============ fp8 CSR gather-aggregate: one wave per dst, 8 edges/gather ============

__global__ __launch_bounds__(256) void k_agg(const int* __restrict__ rowptr,
                                             const int* __restrict__ counts,
                                             const int* __restrict__ ssrc,
                                             const float* __restrict__ dinv,
                                             const uint2* __restrict__ tab2,
                                             float* __restrict__ out, int N) {
    int lane = threadIdx.x & 63;
    int d = blockIdx.x * 4 + (threadIdx.x >> 6);
    if (d >= N) return;
    int q = lane & 7;
    int sub = lane >> 3;
    bool b1 = (sub & 1) != 0, b2 = (sub & 2) != 0, b4 = (sub & 4) != 0;

    float a[8] = {0, 0, 0, 0, 0, 0, 0, 0};
    auto accum = [&](uint2 v) {
        floatx2 f01 = __builtin_amdgcn_cvt_pk_f32_fp8((int)v.x, false);
        floatx2 f23 = __builtin_amdgcn_cvt_pk_f32_fp8((int)v.x, true);
        floatx2 f45 = __builtin_amdgcn_cvt_pk_f32_fp8((int)v.y, false);
        floatx2 f67 = __builtin_amdgcn_cvt_pk_f32_fp8((int)v.y, true);
        a[0] += f01.x; a[1] += f01.y; a[2] += f23.x; a[3] += f23.y;
        a[4] += f45.x; a[5] += f45.y; a[6] += f67.x; a[7] += f67.y;
    };

    if (sub == 0) accum(tab2[(size_t)d * 8 + q]);   // self loop counted once

    int beg = __builtin_amdgcn_readfirstlane(rowptr[d]);
    int cnt = __builtin_amdgcn_readfirstlane(counts[d]);
    const int* srow = ssrc + beg;

#define SEL8(e0,e1,e2,e3,e4,e5,e6,e7) \
    (b4 ? (b2 ? (b1 ? e7 : e6) : (b1 ? e5 : e4)) \
        : (b2 ? (b1 ? e3 : e2) : (b1 ? e1 : e0)))

    int j = 0;
    for (; j + 16 <= cnt; j += 16) {
        int e0 = srow[j + 0],  e1 = srow[j + 1],  e2 = srow[j + 2],  e3 = srow[j + 3];
        int e4 = srow[j + 4],  e5 = srow[j + 5],  e6 = srow[j + 6],  e7 = srow[j + 7];
        int e8 = srow[j + 8],  e9 = srow[j + 9],  ea = srow[j + 10], eb = srow[j + 11];
        int ec = srow[j + 12], ed = srow[j + 13], ee = srow[j + 14], ef = srow[j + 15];
        int t0 = SEL8(e0, e1, e2, e3, e4, e5, e6, e7);
        int t1 = SEL8(e8, e9, ea, eb, ec, ed, ee, ef);
        uint2 v0 = tab2[(size_t)t0 * 8 + q];
        uint2 v1 = tab2[(size_t)t1 * 8 + q];
        accum(v0);
        accum(v1);
    }
    int rem = cnt - j;   // 0..15, wave-uniform
    if (rem) {
        int e0 = srow[j + 0],  e1 = srow[j + 1],  e2 = srow[j + 2],  e3 = srow[j + 3];
        int e4 = srow[j + 4],  e5 = srow[j + 5],  e6 = srow[j + 6],  e7 = srow[j + 7];
        int t0 = SEL8(e0, e1, e2, e3, e4, e5, e6, e7);
        t0 = (sub < rem) ? t0 : N;
        accum(tab2[(size_t)t0 * 8 + q]);
        if (rem > 8) {
            int e8 = srow[j + 8],  e9 = srow[j + 9],  ea = srow[j + 10], eb = srow[j + 11];
            int ec = srow[j + 12], ed = srow[j + 13], ee = srow[j + 14], ef = srow[j + 15];
            int t1 = SEL8(e8, e9, ea, eb, ec, ed, ee, ef);
            t1 = (sub + 8 < rem) ? t1 : N;
            accum(tab2[(size_t)t1 * 8 + q]);
        }
    }
#undef SEL8

#pragma unroll
    for (int i = 0; i < 8; ++i) {
        a[i] += __shfl_xor(a[i], 8);
        a[i] += __shfl_xor(a[i], 16);
        a[i] += __shfl_xor(a[i], 32);
    }

    if (sub == 0) {
        float dd = dinv[d];
        float4* o4 = (float4*)out;
        o4[(size_t)d * 16 + 2 * q + 0] = make_float4(dd * a[0], dd * a[1], dd * a[2], dd * a[3]);
        o4[(size_t)d * 16 + 2 * q + 1] = make_float4(dd * a[4], dd * a[5], dd * a[6], dd * a[7]);
    }
}

// ============ centroid squared norms ============

__global__ void k_c2(const float* __restrict__ C, float* __restrict__ c2) {
    int k = threadIdx.x;
    if (k < 100) {
        float s = 0.f;
        for (int d = 0; d < 64; ++d) { float v = C[k * 64 + d]; s = fmaf(v, v, s); }
        c2[k] = s;
    }
}

// ============ centroid distances + pooling via MFMA ============
// G = relu(h + b2) @ C^T  ([N,64] @ [64,100], cols padded to 112).
// 4 waves/block, wave w owns rows [base + w*64, +64).
// dist = sqrt(max(h2 + c2 - 2G, 0) + eps).
// Per-block partial sums -> partials[block][128] (NO global atomics: 39100
// same-line atomicAdds serialized at the memory-side atomic unit = the ~55us
// wall seen in R1/R2 counters).

__global__ __launch_bounds__(256) void k_cent(const float* __restrict__ hin,
                                              const float* __restrict__ b2,
                                              const float* __restrict__ C,
                                              const float* __restrict__ c2g,
                                              float* __restrict__ partials, int N) {
    __shared__ float pool4[4][112];
    __shared__ float h2_s[256];
    int tid = threadIdx.x;
    int lane = tid & 63, w = tid >> 6;
    int l15 = lane & 15, lg = lane >> 4;      // lg = 0..3

    // B fragments from centroids: B[ct][ks], col = ct*16+l15, k = ks*32+lg*8+j
    bf16x8 B[7][2];
#pragma unroll
    for (int ct = 0; ct < 7; ++ct) {
        int col = ct * 16 + l15;
#pragma unroll
        for (int ks = 0; ks < 2; ++ks) {
            float4 v0 = make_float4(0.f, 0.f, 0.f, 0.f);
            float4 v1 = make_float4(0.f, 0.f, 0.f, 0.f);
            if (col < 100) {
                const float* cr = C + (size_t)col * 64 + ks * 32 + lg * 8;
                v0 = *(const float4*)cr;
                v1 = *(const float4*)(cr + 4);
            }
            B[ct][ks] = pack_bf16x8(v0, v1);
        }
    }

    // bias slice for this lane's k positions
    float bv[16];
#pragma unroll
    for (int ks = 0; ks < 2; ++ks) {
        float4 b0 = *(const float4*)(b2 + ks * 32 + lg * 8);
        float4 b1 = *(const float4*)(b2 + ks * 32 + lg * 8 + 4);
        bv[ks * 8 + 0] = b0.x; bv[ks * 8 + 1] = b0.y;
        bv[ks * 8 + 2] = b0.z; bv[ks * 8 + 3] = b0.w;
        bv[ks * 8 + 4] = b1.x; bv[ks * 8 + 5] = b1.y;
        bv[ks * 8 + 6] = b1.z; bv[ks * 8 + 7] = b1.w;
    }

    int rowbase = blockIdx.x * 256 + w * 64;

    f32x4 acc[4][7];
#pragma unroll
    for (int rt = 0; rt < 4; ++rt)
#pragma unroll
        for (int ct = 0; ct < 7; ++ct)
            acc[rt][ct] = (f32x4){0.f, 0.f, 0.f, 0.f};

#pragma unroll
    for (int rt = 0; rt < 4; ++rt) {
        int row = rowbase + rt * 16 + l15;
        int rowc = (row < N) ? row : (N - 1);     // clamp; excluded from pooling
        const float* hr = hin + ((size_t)rowc << 6);
        float hp[16];
        float h2p = 0.f;
#pragma unroll
        for (int ks = 0; ks < 2; ++ks) {
            float4 v0 = *(const float4*)(hr + ks * 32 + lg * 8);
            float4 v1 = *(const float4*)(hr + ks * 32 + lg * 8 + 4);
            float t0 = fmaxf(v0.x + bv[ks * 8 + 0], 0.f);
            float t1 = fmaxf(v0.y + bv[ks * 8 + 1], 0.f);
            float t2 = fmaxf(v0.z + bv[ks * 8 + 2], 0.f);
            float t3 = fmaxf(v0.w + bv[ks * 8 + 3], 0.f);
            float t4 = fmaxf(v1.x + bv[ks * 8 + 4], 0.f);
            float t5 = fmaxf(v1.y + bv[ks * 8 + 5], 0.f);
            float t6 = fmaxf(v1.z + bv[ks * 8 + 6], 0.f);
            float t7 = fmaxf(v1.w + bv[ks * 8 + 7], 0.f);
            hp[ks * 8 + 0] = t0; hp[ks * 8 + 1] = t1;
            hp[ks * 8 + 2] = t2; hp[ks * 8 + 3] = t3;
            hp[ks * 8 + 4] = t4; hp[ks * 8 + 5] = t5;
            hp[ks * 8 + 6] = t6; hp[ks * 8 + 7] = t7;
            h2p = fmaf(t0, t0, h2p); h2p = fmaf(t1, t1, h2p);
            h2p = fmaf(t2, t2, h2p); h2p = fmaf(t3, t3, h2p);
            h2p = fmaf(t4, t4, h2p); h2p = fmaf(t5, t5, h2p);
            h2p = fmaf(t6, t6, h2p); h2p = fmaf(t7, t7, h2p);
        }
        // full h2 for row (rt, l15): sum partials across the 4 lane-groups
        h2p += __shfl_xor(h2p, 16);
        h2p += __shfl_xor(h2p, 32);
        if (lg == 0) h2_s[w * 64 + rt * 16 + l15] = h2p;

#pragma unroll
        for (int ks = 0; ks < 2; ++ks) {
            bf16x8 a;
#pragma unroll
            for (int j = 0; j < 8; ++j) a[j] = f2bf(hp[ks * 8 + j]);
#pragma unroll
            for (int ct = 0; ct < 7; ++ct)
                acc[rt][ct] = __builtin_amdgcn_mfma_f32_16x16x32_bf16(
                    a, B[ct][ks], acc[rt][ct], 0, 0, 0);
        }
    }

    // epilogue: dist + pooling. D-layout: row_in_tile = lg*4+r, col = l15.
    float S[7] = {0.f, 0.f, 0.f, 0.f, 0.f, 0.f, 0.f};
#pragma unroll
    for (int rt = 0; rt < 4; ++rt) {
#pragma unroll
        for (int r = 0; r < 4; ++r) {
            int row = rowbase + rt * 16 + lg * 4 + r;
            float h2v = h2_s[w * 64 + rt * 16 + lg * 4 + r];
            bool rv = row < N;
#pragma unroll
            for (int ct = 0; ct < 7; ++ct) {
                int col = ct * 16 + l15;
                float c2v = (col < 100) ? c2g[col] : 0.f;
                float G = acc[rt][ct][r];
                float d2 = fmaxf(h2v + c2v - 2.f * G, 0.f);
                float dist = sqrtf(d2 + 1e-12f);
                if (rv && col < 100) S[ct] += dist;
            }
        }
    }
#pragma unroll
    for (int ct = 0; ct < 7; ++ct) {
        float s = S[ct];
        s += __shfl_xor(s, 16);
        s += __shfl_xor(s, 32);
        if (lg == 0) pool4[w][ct * 16 + l15] = s;   // S[ct]=0 for padded cols
    }
    __syncthreads();
    if (tid < 112) {
        float s = pool4[0][tid] + pool4[1][tid] + pool4[2][tid] + pool4[3][tid];
        partials[(size_t)blockIdx.x * 128 + tid] = s;
    }
}

// ============ output head: reduce partials + apply W_out ============
// 1024 threads = 8 groups x 128; group g sums blocks b = g, g+8, ...

__global__ __launch_bounds__(1024) void k_out(const float* __restrict__ partials, int nb,
                                              const float* __restrict__ Wout,
                                              const float* __restrict__ bout,
                                              float* __restrict__ out, float invN) {
    __shared__ float ps[8][112];
    int t = threadIdx.x & 127, g = threadIdx.x >> 7;
    if (t < 112) {
        float s = 0.f;
        for (int b = g; b < nb; b += 8) s += partials[(size_t)b * 128 + t];
        ps[g][t] = s;
    }
    __syncthreads();
    if (threadIdx.x < 10) {
        int tt = threadIdx.x;
        float s = 0.f;
        for (int k = 0; k < 100; ++k) {
            float p = ps[0][k] + ps[1][k] + ps[2][k] + ps[3][k]
                    + ps[4][k] + ps[5][k] + ps[6][k] + ps[7][k];
            s = fmaf(p, Wout[tt * 100 + k], s);
        }
        out[tt] = s * invN + bout[tt];
    }
}

// ============ launcher ============

extern "C" void kernel_launch(void* const* d_in, const int* in_sizes, int n_in,
                              void* d_out, int out_size, void* d_ws, size_t ws_size,
                              hipStream_t stream) {
    const float* x    = (const float*)d_in[0];
    const int*   ei   = (const int*)d_in[1];
    const float* We   = (const float*)d_in[2];
    const float* Wg   = (const float*)d_in[3];
    const float* bg   = (const float*)d_in[4];
    const float* C    = (const float*)d_in[5];
    const float* Wout = (const float*)d_in[6];
    const float* bout = (const float*)d_in[7];
    float*       out  = (float*)d_out;

    const int N = in_sizes[0] / 128;          // 100000
    const int E = in_sizes[1] / 2;            // 1600000
    const int NBUCK = (N + 255) >> 8;         // 391 dst-buckets
    const int NCH = (E + CHUNK - 1) / CHUNK;  // 98 chunks
    const int NBN = (N + 255) / 256;

    char* ws = (char*)d_ws;
    size_t off = 0;
    auto alloc = [&](size_t bytes) { void* p = ws + off; off += (bytes + 511) & ~(size_t)511; return p; };
    float*  dinv   = (float*)alloc((size_t)N * 4);
    int*    counts = (int*)  alloc((size_t)N * 4);
    int*    rowptr = (int*)  alloc((size_t)N * 4);
    int*    bcnt   = (int*)  alloc((size_t)NBUCK * NCH * 4);
    int*    bofs   = (int*)  alloc((size_t)NBUCK * NCH * 4);
    int*    btot   = (int*)  alloc((size_t)NBUCK * 4);
    int*    bbase  = (int*)  alloc((size_t)(NBUCK + 1) * 4);
    uint32* ebuf   = (uint32*)alloc((size_t)E * 4);
    int*    ssrc   = (int*)  alloc((size_t)(E + 16) * 4);     // +16 pad for agg reads
    float*  hA     = (float*)alloc((size_t)N * 64 * 4);
    uint32* tab    = (uint32*)alloc((size_t)(N + 1) * 64);    // fp8 table + sentinel row
    float*  c2     = (float*)alloc(512);
    float*  partials = (float*)alloc((size_t)NBN * 128 * 4);

    hipMemsetAsync(tab + (size_t)N * 16, 0, 64, stream);      // sentinel row N = 0

    // bucketed CSR build (no global atomics)
    k_bhist<<<NCH, 256, 0, stream>>>(ei + E, bcnt, E, NBUCK, NCH);
    k_bscan1<<<NBUCK, 128, 0, stream>>>(bcnt, bofs, btot, NCH);
    k_bscan2<<<1, 512, 0, stream>>>(btot, bbase, NBUCK);
    k_bscatter<<<NCH, 256, 0, stream>>>(ei, bbase, bofs, ebuf, E, NBUCK, NCH);
    k_bsort<<<NBUCK, 256, 0, stream>>>(ebuf, bbase, ssrc, rowptr, counts, dinv, N);
    k_c2<<<1, 128, 0, stream>>>(C, c2);

    // embed (MFMA bf16, 256 rows/block)
    k_embed<<<(N + 255) / 256, 256, 0, stream>>>(x, We, hA, N);

    // 3 GCN layers: gemm (hA -> fp8 tab, scaled by dinv), aggregate (tab -> hA fp32)
    for (int l = 0; l < 3; ++l) {
        const float* bias_prev = (l == 0) ? bg : (bg + (l - 1) * 64);
        int act = (l == 0) ? 0 : 1;
        k_gcn<<<N / 32, 256, 0, stream>>>(hA, Wg + (size_t)l * 64 * 64, bias_prev, act,
                                          dinv, tab, N);
        k_agg<<<(N + 3) / 4, 256, 0, stream>>>(rowptr, counts, ssrc, dinv,
                                               (const uint2*)tab, hA, N);
    }

    // centroid distances + pooling via MFMA (applies relu + b_gcn[2])
    k_cent<<<NBN, 256, 0, stream>>>(hA, bg + 2 * 64, C, c2, partials, N);

    // head: reduce partials + W_out
    k_out<<<1, 1024, 0, stream>>>(partials, NBN, Wout, bout, out, 1.0f / (float)N);
}

// Round 4
// 403.498 us; speedup vs baseline: 1.0957x; 1.0957x over previous
//
#include <hip/hip_runtime.h>
#include <hip/hip_bf16.h>

typedef unsigned int uint32;
typedef float floatx2 __attribute__((ext_vector_type(2)));
typedef __attribute__((ext_vector_type(8))) short bf16x8;
typedef __attribute__((ext_vector_type(4))) float f32x4;

#define CHUNK 16384

// ============ bucketed CSR build (dst>>8 buckets, LDS-atomic sort) ============

__global__ __launch_bounds__(256) void k_bhist(const int* __restrict__ dst,
                                               int* __restrict__ bcnt,
                                               int E, int NBUCK, int NCH) {
    __shared__ int h[512];
    int c = blockIdx.x, tid = threadIdx.x;
    for (int i = tid; i < NBUCK; i += 256) h[i] = 0;
    __syncthreads();
    int base = c * CHUNK;
#pragma unroll
    for (int k = 0; k < CHUNK / 256; ++k) {
        int e = base + k * 256 + tid;
        if (e < E) atomicAdd(&h[dst[e] >> 8], 1);
    }
    __syncthreads();
    for (int i = tid; i < NBUCK; i += 256) bcnt[(size_t)i * NCH + c] = h[i];
}

__global__ __launch_bounds__(128) void k_bscan1(const int* __restrict__ bcnt,
                                                int* __restrict__ bofs,
                                                int* __restrict__ btot, int NCH) {
    __shared__ int tmp[128];
    int b = blockIdx.x, t = threadIdx.x;
    int v = (t < NCH) ? bcnt[(size_t)b * NCH + t] : 0;
    tmp[t] = v;
    __syncthreads();
    for (int off = 1; off < 128; off <<= 1) {
        int u = (t >= off) ? tmp[t - off] : 0;
        __syncthreads();
        tmp[t] += u;
        __syncthreads();
    }
    if (t < NCH) bofs[(size_t)b * NCH + t] = tmp[t] - v;
    if (t == 127) btot[b] = tmp[127];
}

__global__ __launch_bounds__(512) void k_bscan2(const int* __restrict__ btot,
                                                int* __restrict__ bbase, int nb) {
    __shared__ int tmp[512];
    int t = threadIdx.x;
    int v = (t < nb) ? btot[t] : 0;
    tmp[t] = v;
    __syncthreads();
    for (int off = 1; off < 512; off <<= 1) {
        int u = (t >= off) ? tmp[t - off] : 0;
        __syncthreads();
        tmp[t] += u;
        __syncthreads();
    }
    if (t < nb) bbase[t] = tmp[t] - v;
    if (t == nb - 1) bbase[nb] = tmp[t];
}

__global__ __launch_bounds__(256) void k_bscatter(const int* __restrict__ ei,
                                                  const int* __restrict__ bbase,
                                                  const int* __restrict__ bofs,
                                                  uint32* __restrict__ ebuf,
                                                  int E, int NBUCK, int NCH) {
    __shared__ int cur[512];
    int c = blockIdx.x, tid = threadIdx.x;
    for (int i = tid; i < NBUCK; i += 256)
        cur[i] = bbase[i] + bofs[(size_t)i * NCH + c];
    __syncthreads();
    int base = c * CHUNK;
#pragma unroll
    for (int k = 0; k < CHUNK / 256; ++k) {
        int e = base + k * 256 + tid;
        if (e < E) {
            int s = ei[e];
            int d = ei[E + e];
            int p = atomicAdd(&cur[d >> 8], 1);
            ebuf[p] = (uint32)s | ((uint32)(d & 255) << 20);
        }
    }
}

__global__ __launch_bounds__(256) void k_bsort(const uint32* __restrict__ ebuf,
                                               const int* __restrict__ bbase,
                                               int* __restrict__ ssrc,
                                               int* __restrict__ rowptr,
                                               int* __restrict__ counts,
                                               float* __restrict__ dinv, int N) {
    __shared__ int h[256];
    __shared__ int sc[256];
    __shared__ int cur[256];
    int b = blockIdx.x, tid = threadIdx.x;
    int beg = bbase[b], end = bbase[b + 1];
    h[tid] = 0;
    __syncthreads();
    for (int j = beg + tid; j < end; j += 256)
        atomicAdd(&h[(ebuf[j] >> 20) & 255], 1);
    __syncthreads();
    int v = h[tid];
    sc[tid] = v;
    __syncthreads();
    for (int off = 1; off < 256; off <<= 1) {
        int u = (tid >= off) ? sc[tid - off] : 0;
        __syncthreads();
        sc[tid] += u;
        __syncthreads();
    }
    int rowbase = beg + sc[tid] - v;
    cur[tid] = rowbase;
    int d = b * 256 + tid;
    if (d < N) {
        rowptr[d] = rowbase;
        counts[d] = v;
        dinv[d] = rsqrtf((float)(v + 1));   // +1 self loop
    }
    __syncthreads();
    for (int j = beg + tid; j < end; j += 256) {
        uint32 w = ebuf[j];
        int p = atomicAdd(&cur[(w >> 20) & 255], 1);
        ssrc[p] = (int)(w & 0xFFFFFu);
    }
}

// ============ fp32 -> bf16 (RNE) helpers ============

__device__ __forceinline__ short f2bf(float f) {
    __hip_bfloat16 b = __float2bfloat16(f);
    return __builtin_bit_cast(short, b);
}

__device__ __forceinline__ bf16x8 pack_bf16x8(float4 v0, float4 v1) {
    bf16x8 r;
    r[0] = f2bf(v0.x); r[1] = f2bf(v0.y); r[2] = f2bf(v0.z); r[3] = f2bf(v0.w);
    r[4] = f2bf(v1.x); r[5] = f2bf(v1.y); r[6] = f2bf(v1.z); r[7] = f2bf(v1.w);
    return r;
}

// ============ embed GEMM via MFMA: h = x @ We^T ([N,128] @ [128,64]^T) ============
// 4 waves/block; wave w computes rows [base + w*64, +64) x all 64 cols.
// Layouts (m89-verified): A[lane&15][(lane>>4)*8+j], B[(lane>>4)*8+j][lane&15],
// D[(lane>>4)*4+r][lane&15].

__global__ __launch_bounds__(256) void k_embed(const float* __restrict__ x,
                                               const float* __restrict__ We,
                                               float* __restrict__ h, int N) {
    int lane = threadIdx.x & 63;
    int w = threadIdx.x >> 6;
    int l15 = lane & 15;
    int lg = lane >> 4;                       // 0..3

    // B fragments: B[ct][ks], col = ct*16 + l15, k = ks*32 + lg*8 + j
    bf16x8 B[4][4];
#pragma unroll
    for (int ct = 0; ct < 4; ++ct) {
        const float* wr = We + (size_t)(ct * 16 + l15) * 128 + lg * 8;
#pragma unroll
        for (int ks = 0; ks < 4; ++ks) {
            float4 v0 = *(const float4*)(wr + ks * 32);
            float4 v1 = *(const float4*)(wr + ks * 32 + 4);
            B[ct][ks] = pack_bf16x8(v0, v1);
        }
    }

    int rowbase = blockIdx.x * 256 + w * 64;

    f32x4 acc[4][4];
#pragma unroll
    for (int rt = 0; rt < 4; ++rt)
#pragma unroll
        for (int ct = 0; ct < 4; ++ct)
            acc[rt][ct] = (f32x4){0.f, 0.f, 0.f, 0.f};

#pragma unroll
    for (int ks = 0; ks < 4; ++ks) {
#pragma unroll
        for (int rt = 0; rt < 4; ++rt) {
            int row = rowbase + rt * 16 + l15;
            row = (row < N) ? row : (N - 1);          // clamp; stores predicated
            const float* xr = x + (size_t)row * 128 + ks * 32 + lg * 8;
            float4 v0 = *(const float4*)xr;
            float4 v1 = *(const float4*)(xr + 4);
            bf16x8 a = pack_bf16x8(v0, v1);
#pragma unroll
            for (int ct = 0; ct < 4; ++ct)
                acc[rt][ct] = __builtin_amdgcn_mfma_f32_16x16x32_bf16(
                    a, B[ct][ks], acc[rt][ct], 0, 0, 0);
        }
    }

#pragma unroll
    for (int rt = 0; rt < 4; ++rt) {
        int row0 = rowbase + rt * 16 + lg * 4;
#pragma unroll
        for (int r = 0; r < 4; ++r) {
            int row = row0 + r;
            if (row < N) {
#pragma unroll
                for (int ct = 0; ct < 4; ++ct)
                    h[(size_t)row * 64 + ct * 16 + l15] = acc[rt][ct][r];
            }
        }
    }
}

// ============ GCN layer GEMM via MFMA (swapped operands, direct fp8 pack) ====
// Computes D = Wg . act(h)^T: A-frag = Wg[out][k], B-frag = act(h)[node][k].
// D-layout: lane holds node col=l15, out-features lg*4+r (r=0..3) per rt tile
// -> the 4 acc regs are 4 CONSECUTIVE features = one fp8 uint32. No LDS.

__global__ __launch_bounds__(256) void k_gcn(const float* __restrict__ hin,
                                             const float* __restrict__ Wg,
                                             const float* __restrict__ bias_prev, int act,
                                             const float* __restrict__ dinv,
                                             uint32* __restrict__ tab, int N) {
    int lane = threadIdx.x & 63;
    int w = threadIdx.x >> 6;
    int l15 = lane & 15, lg = lane >> 4;

    // A-frags from Wg: A[rt][ks], row(out) = rt*16+l15, k = ks*32+lg*8+j
    bf16x8 A[4][2];
#pragma unroll
    for (int rt = 0; rt < 4; ++rt) {
        const float* wr = Wg + (size_t)(rt * 16 + l15) * 64 + lg * 8;
#pragma unroll
        for (int ks = 0; ks < 2; ++ks) {
            float4 v0 = *(const float4*)(wr + ks * 32);
            float4 v1 = *(const float4*)(wr + ks * 32 + 4);
            A[rt][ks] = pack_bf16x8(v0, v1);
        }
    }

    // bias slice for this lane's k positions (only used when act)
    float bv[16];
#pragma unroll
    for (int ks = 0; ks < 2; ++ks) {
        float4 b0 = *(const float4*)(bias_prev + ks * 32 + lg * 8);
        float4 b1 = *(const float4*)(bias_prev + ks * 32 + lg * 8 + 4);
        bv[ks * 8 + 0] = b0.x; bv[ks * 8 + 1] = b0.y;
        bv[ks * 8 + 2] = b0.z; bv[ks * 8 + 3] = b0.w;
        bv[ks * 8 + 4] = b1.x; bv[ks * 8 + 5] = b1.y;
        bv[ks * 8 + 6] = b1.z; bv[ks * 8 + 7] = b1.w;
    }

    int nodebase = blockIdx.x * 256 + w * 64;   // wave: 64 nodes = 4 tiles of 16

#pragma unroll
    for (int nt = 0; nt < 4; ++nt) {
        int node = nodebase + nt * 16 + l15;
        int nodec = (node < N) ? node : (N - 1);
        const float* hr = hin + ((size_t)nodec << 6) + lg * 8;

        bf16x8 Bf[2];
#pragma unroll
        for (int ks = 0; ks < 2; ++ks) {
            float4 v0 = *(const float4*)(hr + ks * 32);
            float4 v1 = *(const float4*)(hr + ks * 32 + 4);
            if (act) {
                v0.x = fmaxf(v0.x + bv[ks * 8 + 0], 0.f);
                v0.y = fmaxf(v0.y + bv[ks * 8 + 1], 0.f);
                v0.z = fmaxf(v0.z + bv[ks * 8 + 2], 0.f);
                v0.w = fmaxf(v0.w + bv[ks * 8 + 3], 0.f);
                v1.x = fmaxf(v1.x + bv[ks * 8 + 4], 0.f);
                v1.y = fmaxf(v1.y + bv[ks * 8 + 5], 0.f);
                v1.z = fmaxf(v1.z + bv[ks * 8 + 6], 0.f);
                v1.w = fmaxf(v1.w + bv[ks * 8 + 7], 0.f);
            }
            Bf[ks] = pack_bf16x8(v0, v1);
        }

        f32x4 acc[4];
#pragma unroll
        for (int rt = 0; rt < 4; ++rt) acc[rt] = (f32x4){0.f, 0.f, 0.f, 0.f};
#pragma unroll
        for (int ks = 0; ks < 2; ++ks)
#pragma unroll
            for (int rt = 0; rt < 4; ++rt)
                acc[rt] = __builtin_amdgcn_mfma_f32_16x16x32_bf16(
                    A[rt][ks], Bf[ks], acc[rt], 0, 0, 0);

        float s = dinv[nodec];
        if (node < N) {
#pragma unroll
            for (int rt = 0; rt < 4; ++rt) {
                int u = 0;
                u = __builtin_amdgcn_cvt_pk_fp8_f32(acc[rt][0] * s, acc[rt][1] * s, u, false);
                u = __builtin_amdgcn_cvt_pk_fp8_f32(acc[rt][2] * s, acc[rt][3] * s, u, true);
                tab[(size_t)node * 16 + rt * 4 + lg] = u;
            }
        }
    }
}

// ============ fp8 CSR gather-aggregate: one wave per dst, 8 edges/gather ============

__global__ __launch_bounds__(256) void k_agg(const int* __restrict__ rowptr,
                                             const int* __restrict__ counts,
                                             const int* __restrict__ ssrc,
                                             const float* __restrict__ dinv,
                                             const uint2* __restrict__ tab2,
                                             float* __restrict__ out, int N) {
    int lane = threadIdx.x & 63;
    int d = blockIdx.x * 4 + (threadIdx.x >> 6);
    if (d >= N) return;
    int q = lane & 7;
    int sub = lane >> 3;
    bool b1 = (sub & 1) != 0, b2 = (sub & 2) != 0, b4 = (sub & 4) != 0;

    float a[8] = {0, 0, 0, 0, 0, 0, 0, 0};
    auto accum = [&](uint2 v) {
        floatx2 f01 = __builtin_amdgcn_cvt_pk_f32_fp8((int)v.x, false);
        floatx2 f23 = __builtin_amdgcn_cvt_pk_f32_fp8((int)v.x, true);
        floatx2 f45 = __builtin_amdgcn_cvt_pk_f32_fp8((int)v.y, false);
        floatx2 f67 = __builtin_amdgcn_cvt_pk_f32_fp8((int)v.y, true);
        a[0] += f01.x; a[1] += f01.y; a[2] += f23.x; a[3] += f23.y;
        a[4] += f45.x; a[5] += f45.y; a[6] += f67.x; a[7] += f67.y;
    };

    if (sub == 0) accum(tab2[(size_t)d * 8 + q]);   // self loop counted once

    int beg = __builtin_amdgcn_readfirstlane(rowptr[d]);
    int cnt = __builtin_amdgcn_readfirstlane(counts[d]);
    const int* srow = ssrc + beg;

#define SEL8(e0,e1,e2,e3,e4,e5,e6,e7) \
    (b4 ? (b2 ? (b1 ? e7 : e6) : (b1 ? e5 : e4)) \
        : (b2 ? (b1 ? e3 : e2) : (b1 ? e1 : e0)))

    int j = 0;
    for (; j + 16 <= cnt; j += 16) {
        int e0 = srow[j + 0],  e1 = srow[j + 1],  e2 = srow[j + 2],  e3 = srow[j + 3];
        int e4 = srow[j + 4],  e5 = srow[j + 5],  e6 = srow[j + 6],  e7 = srow[j + 7];
        int e8 = srow[j + 8],  e9 = srow[j + 9],  ea = srow[j + 10], eb = srow[j + 11];
        int ec = srow[j + 12], ed = srow[j + 13], ee = srow[j + 14], ef = srow[j + 15];
        int t0 = SEL8(e0, e1, e2, e3, e4, e5, e6, e7);
        int t1 = SEL8(e8, e9, ea, eb, ec, ed, ee, ef);
        uint2 v0 = tab2[(size_t)t0 * 8 + q];
        uint2 v1 = tab2[(size_t)t1 * 8 + q];
        accum(v0);
        accum(v1);
    }
    int rem = cnt - j;   // 0..15, wave-uniform
    if (rem) {
        int e0 = srow[j + 0],  e1 = srow[j + 1],  e2 = srow[j + 2],  e3 = srow[j + 3];
        int e4 = srow[j + 4],  e5 = srow[j + 5],  e6 = srow[j + 6],  e7 = srow[j + 7];
        int t0 = SEL8(e0, e1, e2, e3, e4, e5, e6, e7);
        t0 = (sub < rem) ? t0 : N;
        accum(tab2[(size_t)t0 * 8 + q]);
        if (rem > 8) {
            int e8 = srow[j + 8],  e9 = srow[j + 9],  ea = srow[j + 10], eb = srow[j + 11];
            int ec = srow[j + 12], ed = srow[j + 13], ee = srow[j + 14], ef = srow[j + 15];
            int t1 = SEL8(e8, e9, ea, eb, ec, ed, ee, ef);
            t1 = (sub + 8 < rem) ? t1 : N;
            accum(tab2[(size_t)t1 * 8 + q]);
        }
    }
#undef SEL8

#pragma unroll
    for (int i = 0; i < 8; ++i) {
        a[i] += __shfl_xor(a[i], 8);
        a[i] += __shfl_xor(a[i], 16);
        a[i] += __shfl_xor(a[i], 32);
    }

    if (sub == 0) {
        float dd = dinv[d];
        float4* o4 = (float4*)out;
        o4[(size_t)d * 16 + 2 * q + 0] = make_float4(dd * a[0], dd * a[1], dd * a[2], dd * a[3]);
        o4[(size_t)d * 16 + 2 * q + 1] = make_float4(dd * a[4], dd * a[5], dd * a[6], dd * a[7]);
    }
}

// ============ centroid squared norms ============

__global__ void k_c2(const float* __restrict__ C, float* __restrict__ c2) {
    int k = threadIdx.x;
    if (k < 100) {
        float s = 0.f;
        for (int d = 0; d < 64; ++d) { float v = C[k * 64 + d]; s = fmaf(v, v, s); }
        c2[k] = s;
    }
}

// ============ centroid distances + pooling via MFMA ============
// 128 rows/block (4 waves x 32 rows) -> 782 blocks for latency hiding.
// dist = x * rsqrt(x), x = d2 + eps (1 trans op instead of precise sqrt seq).

__global__ __launch_bounds__(256) void k_cent(const float* __restrict__ hin,
                                              const float* __restrict__ b2,
                                              const float* __restrict__ C,
                                              const float* __restrict__ c2g,
                                              float* __restrict__ partials, int N) {
    __shared__ float pool4[4][112];
    __shared__ float h2_s[128];
    int tid = threadIdx.x;
    int lane = tid & 63, w = tid >> 6;
    int l15 = lane & 15, lg = lane >> 4;      // lg = 0..3

    // B fragments from centroids: B[ct][ks], col = ct*16+l15, k = ks*32+lg*8+j
    bf16x8 B[7][2];
#pragma unroll
    for (int ct = 0; ct < 7; ++ct) {
        int col = ct * 16 + l15;
#pragma unroll
        for (int ks = 0; ks < 2; ++ks) {
            float4 v0 = make_float4(0.f, 0.f, 0.f, 0.f);
            float4 v1 = make_float4(0.f, 0.f, 0.f, 0.f);
            if (col < 100) {
                const float* cr = C + (size_t)col * 64 + ks * 32 + lg * 8;
                v0 = *(const float4*)cr;
                v1 = *(const float4*)(cr + 4);
            }
            B[ct][ks] = pack_bf16x8(v0, v1);
        }
    }

    // bias slice for this lane's k positions
    float bv[16];
#pragma unroll
    for (int ks = 0; ks < 2; ++ks) {
        float4 b0 = *(const float4*)(b2 + ks * 32 + lg * 8);
        float4 b1 = *(const float4*)(b2 + ks * 32 + lg * 8 + 4);
        bv[ks * 8 + 0] = b0.x; bv[ks * 8 + 1] = b0.y;
        bv[ks * 8 + 2] = b0.z; bv[ks * 8 + 3] = b0.w;
        bv[ks * 8 + 4] = b1.x; bv[ks * 8 + 5] = b1.y;
        bv[ks * 8 + 6] = b1.z; bv[ks * 8 + 7] = b1.w;
    }

    int rowbase = blockIdx.x * 128 + w * 32;

    f32x4 acc[2][7];
#pragma unroll
    for (int rt = 0; rt < 2; ++rt)
#pragma unroll
        for (int ct = 0; ct < 7; ++ct)
            acc[rt][ct] = (f32x4){0.f, 0.f, 0.f, 0.f};

#pragma unroll
    for (int rt = 0; rt < 2; ++rt) {
        int row = rowbase + rt * 16 + l15;
        int rowc = (row < N) ? row : (N - 1);     // clamp; excluded from pooling
        const float* hr = hin + ((size_t)rowc << 6);
        float hp[16];
        float h2p = 0.f;
#pragma unroll
        for (int ks = 0; ks < 2; ++ks) {
            float4 v0 = *(const float4*)(hr + ks * 32 + lg * 8);
            float4 v1 = *(const float4*)(hr + ks * 32 + lg * 8 + 4);
            float t0 = fmaxf(v0.x + bv[ks * 8 + 0], 0.f);
            float t1 = fmaxf(v0.y + bv[ks * 8 + 1], 0.f);
            float t2 = fmaxf(v0.z + bv[ks * 8 + 2], 0.f);
            float t3 = fmaxf(v0.w + bv[ks * 8 + 3], 0.f);
            float t4 = fmaxf(v1.x + bv[ks * 8 + 4], 0.f);
            float t5 = fmaxf(v1.y + bv[ks * 8 + 5], 0.f);
            float t6 = fmaxf(v1.z + bv[ks * 8 + 6], 0.f);
            float t7 = fmaxf(v1.w + bv[ks * 8 + 7], 0.f);
            hp[ks * 8 + 0] = t0; hp[ks * 8 + 1] = t1;
            hp[ks * 8 + 2] = t2; hp[ks * 8 + 3] = t3;
            hp[ks * 8 + 4] = t4; hp[ks * 8 + 5] = t5;
            hp[ks * 8 + 6] = t6; hp[ks * 8 + 7] = t7;
            h2p = fmaf(t0, t0, h2p); h2p = fmaf(t1, t1, h2p);
            h2p = fmaf(t2, t2, h2p); h2p = fmaf(t3, t3, h2p);
            h2p = fmaf(t4, t4, h2p); h2p = fmaf(t5, t5, h2p);
            h2p = fmaf(t6, t6, h2p); h2p = fmaf(t7, t7, h2p);
        }
        // full h2 for row (rt, l15): sum partials across the 4 lane-groups
        h2p += __shfl_xor(h2p, 16);
        h2p += __shfl_xor(h2p, 32);
        if (lg == 0) h2_s[w * 32 + rt * 16 + l15] = h2p;

#pragma unroll
        for (int ks = 0; ks < 2; ++ks) {
            bf16x8 a;
#pragma unroll
            for (int j = 0; j < 8; ++j) a[j] = f2bf(hp[ks * 8 + j]);
#pragma unroll
            for (int ct = 0; ct < 7; ++ct)
                acc[rt][ct] = __builtin_amdgcn_mfma_f32_16x16x32_bf16(
                    a, B[ct][ks], acc[rt][ct], 0, 0, 0);
        }
    }

    // epilogue: dist + pooling. D-layout: row_in_tile = lg*4+r, col = l15.
    float S[7] = {0.f, 0.f, 0.f, 0.f, 0.f, 0.f, 0.f};
#pragma unroll
    for (int rt = 0; rt < 2; ++rt) {
#pragma unroll
        for (int r = 0; r < 4; ++r) {
            int row = rowbase + rt * 16 + lg * 4 + r;
            float h2v = h2_s[w * 32 + rt * 16 + lg * 4 + r];
            bool rv = row < N;
#pragma unroll
            for (int ct = 0; ct < 7; ++ct) {
                int col = ct * 16 + l15;
                float c2v = (col < 100) ? c2g[col] : 0.f;
                float G = acc[rt][ct][r];
                float d2 = fmaxf(h2v + c2v - 2.f * G, 0.f);
                float xx = d2 + 1e-12f;
                float dist = xx * __frsqrt_rn(xx);       // sqrt via rsq, 1 trans op
                S[ct] += (rv && col < 100) ? dist : 0.f;
            }
        }
    }
#pragma unroll
    for (int ct = 0; ct < 7; ++ct) {
        float s = S[ct];
        s += __shfl_xor(s, 16);
        s += __shfl_xor(s, 32);
        if (lg == 0) pool4[w][ct * 16 + l15] = s;   // S[ct]=0 for padded cols
    }
    __syncthreads();
    if (tid < 112) {
        float s = pool4[0][tid] + pool4[1][tid] + pool4[2][tid] + pool4[3][tid];
        partials[(size_t)blockIdx.x * 128 + tid] = s;
    }
}

// ============ output head: reduce partials + apply W_out ============
// 1024 threads = 8 groups x 128; group g sums blocks b = g, g+8, ...

__global__ __launch_bounds__(1024) void k_out(const float* __restrict__ partials, int nb,
                                              const float* __restrict__ Wout,
                                              const float* __restrict__ bout,
                                              float* __restrict__ out, float invN) {
    __shared__ float ps[8][112];
    int t = threadIdx.x & 127, g = threadIdx.x >> 7;
    if (t < 112) {
        float s = 0.f;
        for (int b = g; b < nb; b += 8) s += partials[(size_t)b * 128 + t];
        ps[g][t] = s;
    }
    __syncthreads();
    if (threadIdx.x < 10) {
        int tt = threadIdx.x;
        float s = 0.f;
        for (int k = 0; k < 100; ++k) {
            float p = ps[0][k] + ps[1][k] + ps[2][k] + ps[3][k]
                    + ps[4][k] + ps[5][k] + ps[6][k] + ps[7][k];
            s = fmaf(p, Wout[tt * 100 + k], s);
        }
        out[tt] = s * invN + bout[tt];
    }
}

// ============ launcher ============

extern "C" void kernel_launch(void* const* d_in, const int* in_sizes, int n_in,
                              void* d_out, int out_size, void* d_ws, size_t ws_size,
                              hipStream_t stream) {
    const float* x    = (const float*)d_in[0];
    const int*   ei   = (const int*)d_in[1];
    const float* We   = (const float*)d_in[2];
    const float* Wg   = (const float*)d_in[3];
    const float* bg   = (const float*)d_in[4];
    const float* C    = (const float*)d_in[5];
    const float* Wout = (const float*)d_in[6];
    const float* bout = (const float*)d_in[7];
    float*       out  = (float*)d_out;

    const int N = in_sizes[0] / 128;          // 100000
    const int E = in_sizes[1] / 2;            // 1600000
    const int NBUCK = (N + 255) >> 8;         // 391 dst-buckets
    const int NCH = (E + CHUNK - 1) / CHUNK;  // 98 chunks
    const int NBC = (N + 127) / 128;          // k_cent blocks (782)

    char* ws = (char*)d_ws;
    size_t off = 0;
    auto alloc = [&](size_t bytes) { void* p = ws + off; off += (bytes + 511) & ~(size_t)511; return p; };
    float*  dinv   = (float*)alloc((size_t)N * 4);
    int*    counts = (int*)  alloc((size_t)N * 4);
    int*    rowptr = (int*)  alloc((size_t)N * 4);
    int*    bcnt   = (int*)  alloc((size_t)NBUCK * NCH * 4);
    int*    bofs   = (int*)  alloc((size_t)NBUCK * NCH * 4);
    int*    btot   = (int*)  alloc((size_t)NBUCK * 4);
    int*    bbase  = (int*)  alloc((size_t)(NBUCK + 1) * 4);
    uint32* ebuf   = (uint32*)alloc((size_t)E * 4);
    int*    ssrc   = (int*)  alloc((size_t)(E + 16) * 4);     // +16 pad for agg reads
    float*  hA     = (float*)alloc((size_t)N * 64 * 4);
    uint32* tab    = (uint32*)alloc((size_t)(N + 1) * 64);    // fp8 table + sentinel row
    float*  c2     = (float*)alloc(512);
    float*  partials = (float*)alloc((size_t)NBC * 128 * 4);

    hipMemsetAsync(tab + (size_t)N * 16, 0, 64, stream);      // sentinel row N = 0

    // bucketed CSR build (no global atomics)
    k_bhist<<<NCH, 256, 0, stream>>>(ei + E, bcnt, E, NBUCK, NCH);
    k_bscan1<<<NBUCK, 128, 0, stream>>>(bcnt, bofs, btot, NCH);
    k_bscan2<<<1, 512, 0, stream>>>(btot, bbase, NBUCK);
    k_bscatter<<<NCH, 256, 0, stream>>>(ei, bbase, bofs, ebuf, E, NBUCK, NCH);
    k_bsort<<<NBUCK, 256, 0, stream>>>(ebuf, bbase, ssrc, rowptr, counts, dinv, N);
    k_c2<<<1, 128, 0, stream>>>(C, c2);

    // embed (MFMA bf16, 256 rows/block)
    k_embed<<<(N + 255) / 256, 256, 0, stream>>>(x, We, hA, N);

    // 3 GCN layers: gemm (hA -> fp8 tab, scaled by dinv), aggregate (tab -> hA fp32)
    for (int l = 0; l < 3; ++l) {
        const float* bias_prev = (l == 0) ? bg : (bg + (l - 1) * 64);
        int act = (l == 0) ? 0 : 1;
        k_gcn<<<(N + 255) / 256, 256, 0, stream>>>(hA, Wg + (size_t)l * 64 * 64,
                                                   bias_prev, act, dinv, tab, N);
        k_agg<<<(N + 3) / 4, 256, 0, stream>>>(rowptr, counts, ssrc, dinv,
                                               (const uint2*)tab, hA, N);
    }

    // centroid distances + pooling via MFMA (applies relu + b_gcn[2])
    k_cent<<<NBC, 256, 0, stream>>>(hA, bg + 2 * 64, C, c2, partials, N);

    // head: reduce partials + W_out
    k_out<<<1, 1024, 0, stream>>>(partials, NBC, Wout, bout, out, 1.0f / (float)N);
}

// Round 5
// 397.945 us; speedup vs baseline: 1.1110x; 1.0140x over previous
//
#include <hip/hip_runtime.h>
#include <hip/hip_bf16.h>

typedef unsigned int uint32;
typedef float floatx2 __attribute__((ext_vector_type(2)));
typedef __attribute__((ext_vector_type(8))) short bf16x8;
typedef __attribute__((ext_vector_type(4))) float f32x4;

#define CHUNK 16384

// ============ bucketed CSR build (dst>>8 buckets, LDS-atomic sort) ============

__global__ __launch_bounds__(256) void k_bhist(const int* __restrict__ dst,
                                               int* __restrict__ bcnt,
                                               int E, int NBUCK, int NCH) {
    __shared__ int h[512];
    int c = blockIdx.x, tid = threadIdx.x;
    for (int i = tid; i < NBUCK; i += 256) h[i] = 0;
    __syncthreads();
    int base = c * CHUNK;
#pragma unroll
    for (int k = 0; k < CHUNK / 256; ++k) {
        int e = base + k * 256 + tid;
        if (e < E) atomicAdd(&h[dst[e] >> 8], 1);
    }
    __syncthreads();
    for (int i = tid; i < NBUCK; i += 256) bcnt[(size_t)i * NCH + c] = h[i];
}

__global__ __launch_bounds__(128) void k_bscan1(const int* __restrict__ bcnt,
                                                int* __restrict__ bofs,
                                                int* __restrict__ btot, int NCH) {
    __shared__ int tmp[128];
    int b = blockIdx.x, t = threadIdx.x;
    int v = (t < NCH) ? bcnt[(size_t)b * NCH + t] : 0;
    tmp[t] = v;
    __syncthreads();
    for (int off = 1; off < 128; off <<= 1) {
        int u = (t >= off) ? tmp[t - off] : 0;
        __syncthreads();
        tmp[t] += u;
        __syncthreads();
    }
    if (t < NCH) bofs[(size_t)b * NCH + t] = tmp[t] - v;
    if (t == 127) btot[b] = tmp[127];
}

__global__ __launch_bounds__(512) void k_bscan2(const int* __restrict__ btot,
                                                int* __restrict__ bbase, int nb) {
    __shared__ int tmp[512];
    int t = threadIdx.x;
    int v = (t < nb) ? btot[t] : 0;
    tmp[t] = v;
    __syncthreads();
    for (int off = 1; off < 512; off <<= 1) {
        int u = (t >= off) ? tmp[t - off] : 0;
        __syncthreads();
        tmp[t] += u;
        __syncthreads();
    }
    if (t < nb) bbase[t] = tmp[t] - v;
    if (t == nb - 1) bbase[nb] = tmp[t];
}

__global__ __launch_bounds__(256) void k_bscatter(const int* __restrict__ ei,
                                                  const int* __restrict__ bbase,
                                                  const int* __restrict__ bofs,
                                                  uint32* __restrict__ ebuf,
                                                  int E, int NBUCK, int NCH) {
    __shared__ int cur[512];
    int c = blockIdx.x, tid = threadIdx.x;
    for (int i = tid; i < NBUCK; i += 256)
        cur[i] = bbase[i] + bofs[(size_t)i * NCH + c];
    __syncthreads();
    int base = c * CHUNK;
#pragma unroll
    for (int k = 0; k < CHUNK / 256; ++k) {
        int e = base + k * 256 + tid;
        if (e < E) {
            int s = ei[e];
            int d = ei[E + e];
            int p = atomicAdd(&cur[d >> 8], 1);
            ebuf[p] = (uint32)s | ((uint32)(d & 255) << 20);
        }
    }
}

__global__ __launch_bounds__(256) void k_bsort(const uint32* __restrict__ ebuf,
                                               const int* __restrict__ bbase,
                                               int* __restrict__ ssrc,
                                               int* __restrict__ rowptr,
                                               int* __restrict__ counts,
                                               float* __restrict__ dinv, int N) {
    __shared__ int h[256];
    __shared__ int sc[256];
    __shared__ int cur[256];
    int b = blockIdx.x, tid = threadIdx.x;
    int beg = bbase[b], end = bbase[b + 1];
    h[tid] = 0;
    __syncthreads();
    for (int j = beg + tid; j < end; j += 256)
        atomicAdd(&h[(ebuf[j] >> 20) & 255], 1);
    __syncthreads();
    int v = h[tid];
    sc[tid] = v;
    __syncthreads();
    for (int off = 1; off < 256; off <<= 1) {
        int u = (tid >= off) ? sc[tid - off] : 0;
        __syncthreads();
        sc[tid] += u;
        __syncthreads();
    }
    int rowbase = beg + sc[tid] - v;
    cur[tid] = rowbase;
    int d = b * 256 + tid;
    if (d < N) {
        rowptr[d] = rowbase;
        counts[d] = v;
        dinv[d] = rsqrtf((float)(v + 1));   // +1 self loop
    }
    __syncthreads();
    for (int j = beg + tid; j < end; j += 256) {
        uint32 w = ebuf[j];
        int p = atomicAdd(&cur[(w >> 20) & 255], 1);
        ssrc[p] = (int)(w & 0xFFFFFu);
    }
}

// ============ fp32 -> bf16 (RNE) helpers ============

__device__ __forceinline__ short f2bf(float f) {
    __hip_bfloat16 b = __float2bfloat16(f);
    return __builtin_bit_cast(short, b);
}

__device__ __forceinline__ bf16x8 pack_bf16x8(float4 v0, float4 v1) {
    bf16x8 r;
    r[0] = f2bf(v0.x); r[1] = f2bf(v0.y); r[2] = f2bf(v0.z); r[3] = f2bf(v0.w);
    r[4] = f2bf(v1.x); r[5] = f2bf(v1.y); r[6] = f2bf(v1.z); r[7] = f2bf(v1.w);
    return r;
}

// ============ embed GEMM via MFMA: h = x @ We^T ([N,128] @ [128,64]^T) ============
// Layouts (m89-verified): A[lane&15][(lane>>4)*8+j], B[(lane>>4)*8+j][lane&15],
// D[(lane>>4)*4+r][lane&15].

__global__ __launch_bounds__(256) void k_embed(const float* __restrict__ x,
                                               const float* __restrict__ We,
                                               float* __restrict__ h, int N) {
    int lane = threadIdx.x & 63;
    int w = threadIdx.x >> 6;
    int l15 = lane & 15;
    int lg = lane >> 4;                       // 0..3

    bf16x8 B[4][4];
#pragma unroll
    for (int ct = 0; ct < 4; ++ct) {
        const float* wr = We + (size_t)(ct * 16 + l15) * 128 + lg * 8;
#pragma unroll
        for (int ks = 0; ks < 4; ++ks) {
            float4 v0 = *(const float4*)(wr + ks * 32);
            float4 v1 = *(const float4*)(wr + ks * 32 + 4);
            B[ct][ks] = pack_bf16x8(v0, v1);
        }
    }

    int rowbase = blockIdx.x * 256 + w * 64;

    f32x4 acc[4][4];
#pragma unroll
    for (int rt = 0; rt < 4; ++rt)
#pragma unroll
        for (int ct = 0; ct < 4; ++ct)
            acc[rt][ct] = (f32x4){0.f, 0.f, 0.f, 0.f};

#pragma unroll
    for (int ks = 0; ks < 4; ++ks) {
#pragma unroll
        for (int rt = 0; rt < 4; ++rt) {
            int row = rowbase + rt * 16 + l15;
            row = (row < N) ? row : (N - 1);          // clamp; stores predicated
            const float* xr = x + (size_t)row * 128 + ks * 32 + lg * 8;
            float4 v0 = *(const float4*)xr;
            float4 v1 = *(const float4*)(xr + 4);
            bf16x8 a = pack_bf16x8(v0, v1);
#pragma unroll
            for (int ct = 0; ct < 4; ++ct)
                acc[rt][ct] = __builtin_amdgcn_mfma_f32_16x16x32_bf16(
                    a, B[ct][ks], acc[rt][ct], 0, 0, 0);
        }
    }

#pragma unroll
    for (int rt = 0; rt < 4; ++rt) {
        int row0 = rowbase + rt * 16 + lg * 4;
#pragma unroll
        for (int r = 0; r < 4; ++r) {
            int row = row0 + r;
            if (row < N) {
#pragma unroll
                for (int ct = 0; ct < 4; ++ct)
                    h[(size_t)row * 64 + ct * 16 + l15] = acc[rt][ct][r];
            }
        }
    }
}

// ============ GCN layer GEMM via MFMA (swapped operands, direct fp8 pack) ====
// D = Wg . act(h)^T: lane holds node col=l15, out-features lg*4+r per rt tile
// -> 4 acc regs = 4 consecutive features = one fp8 uint32. No LDS.

__global__ __launch_bounds__(256) void k_gcn(const float* __restrict__ hin,
                                             const float* __restrict__ Wg,
                                             const float* __restrict__ bias_prev, int act,
                                             const float* __restrict__ dinv,
                                             uint32* __restrict__ tab, int N) {
    int lane = threadIdx.x & 63;
    int w = threadIdx.x >> 6;
    int l15 = lane & 15, lg = lane >> 4;

    bf16x8 A[4][2];
#pragma unroll
    for (int rt = 0; rt < 4; ++rt) {
        const float* wr = Wg + (size_t)(rt * 16 + l15) * 64 + lg * 8;
#pragma unroll
        for (int ks = 0; ks < 2; ++ks) {
            float4 v0 = *(const float4*)(wr + ks * 32);
            float4 v1 = *(const float4*)(wr + ks * 32 + 4);
            A[rt][ks] = pack_bf16x8(v0, v1);
        }
    }

    float bv[16];
#pragma unroll
    for (int ks = 0; ks < 2; ++ks) {
        float4 b0 = *(const float4*)(bias_prev + ks * 32 + lg * 8);
        float4 b1 = *(const float4*)(bias_prev + ks * 32 + lg * 8 + 4);
        bv[ks * 8 + 0] = b0.x; bv[ks * 8 + 1] = b0.y;
        bv[ks * 8 + 2] = b0.z; bv[ks * 8 + 3] = b0.w;
        bv[ks * 8 + 4] = b1.x; bv[ks * 8 + 5] = b1.y;
        bv[ks * 8 + 6] = b1.z; bv[ks * 8 + 7] = b1.w;
    }

    int nodebase = blockIdx.x * 256 + w * 64;   // wave: 64 nodes = 4 tiles of 16

#pragma unroll
    for (int nt = 0; nt < 4; ++nt) {
        int node = nodebase + nt * 16 + l15;
        int nodec = (node < N) ? node : (N - 1);
        const float* hr = hin + ((size_t)nodec << 6) + lg * 8;

        bf16x8 Bf[2];
#pragma unroll
        for (int ks = 0; ks < 2; ++ks) {
            float4 v0 = *(const float4*)(hr + ks * 32);
            float4 v1 = *(const float4*)(hr + ks * 32 + 4);
            if (act) {
                v0.x = fmaxf(v0.x + bv[ks * 8 + 0], 0.f);
                v0.y = fmaxf(v0.y + bv[ks * 8 + 1], 0.f);
                v0.z = fmaxf(v0.z + bv[ks * 8 + 2], 0.f);
                v0.w = fmaxf(v0.w + bv[ks * 8 + 3], 0.f);
                v1.x = fmaxf(v1.x + bv[ks * 8 + 4], 0.f);
                v1.y = fmaxf(v1.y + bv[ks * 8 + 5], 0.f);
                v1.z = fmaxf(v1.z + bv[ks * 8 + 6], 0.f);
                v1.w = fmaxf(v1.w + bv[ks * 8 + 7], 0.f);
            }
            Bf[ks] = pack_bf16x8(v0, v1);
        }

        f32x4 acc[4];
#pragma unroll
        for (int rt = 0; rt < 4; ++rt) acc[rt] = (f32x4){0.f, 0.f, 0.f, 0.f};
#pragma unroll
        for (int ks = 0; ks < 2; ++ks)
#pragma unroll
            for (int rt = 0; rt < 4; ++rt)
                acc[rt] = __builtin_amdgcn_mfma_f32_16x16x32_bf16(
                    A[rt][ks], Bf[ks], acc[rt], 0, 0, 0);

        float s = dinv[nodec];
        if (node < N) {
#pragma unroll
            for (int rt = 0; rt < 4; ++rt) {
                int u = 0;
                u = __builtin_amdgcn_cvt_pk_fp8_f32(acc[rt][0] * s, acc[rt][1] * s, u, false);
                u = __builtin_amdgcn_cvt_pk_fp8_f32(acc[rt][2] * s, acc[rt][3] * s, u, true);
                tab[(size_t)node * 16 + rt * 4 + lg] = u;
            }
        }
    }
}

// ============ fp8 CSR gather-aggregate: TWO dsts per wave, interleaved chains ====
// Per-dst chain rowptr->srow->tab gather is ~3 memory round-trips with ~1
// iteration at avg degree 16 (no ILP). Interleaving 2 dsts' chains in one wave
// doubles memory-level parallelism and halves wave count.

__global__ __launch_bounds__(256) void k_agg(const int* __restrict__ rowptr,
                                             const int* __restrict__ counts,
                                             const int* __restrict__ ssrc,
                                             const float* __restrict__ dinv,
                                             const uint2* __restrict__ tab2,
                                             float* __restrict__ out, int N) {
    int lane = threadIdx.x & 63;
    int dA = blockIdx.x * 8 + (threadIdx.x >> 6) * 2;
    if (dA >= N) return;
    int dB = dA + 1;
    bool hasB = dB < N;
    int dBc = hasB ? dB : N;                  // sentinel row N = zeros
    int q = lane & 7;
    int sub = lane >> 3;
    bool b1 = (sub & 1) != 0, b2 = (sub & 2) != 0, b4 = (sub & 4) != 0;

    float aA[8] = {0, 0, 0, 0, 0, 0, 0, 0};
    float aB[8] = {0, 0, 0, 0, 0, 0, 0, 0};

#define ACC(arr, v) do { \
        floatx2 f01 = __builtin_amdgcn_cvt_pk_f32_fp8((int)(v).x, false); \
        floatx2 f23 = __builtin_amdgcn_cvt_pk_f32_fp8((int)(v).x, true);  \
        floatx2 f45 = __builtin_amdgcn_cvt_pk_f32_fp8((int)(v).y, false); \
        floatx2 f67 = __builtin_amdgcn_cvt_pk_f32_fp8((int)(v).y, true);  \
        arr[0] += f01.x; arr[1] += f01.y; arr[2] += f23.x; arr[3] += f23.y; \
        arr[4] += f45.x; arr[5] += f45.y; arr[6] += f67.x; arr[7] += f67.y; \
    } while (0)

    // self loops (counted once); both gathers issued before use
    {
        uint2 vA = tab2[(size_t)dA * 8 + q];
        uint2 vB = tab2[(size_t)dBc * 8 + q];
        if (sub == 0) {
            ACC(aA, vA);
            if (hasB) ACC(aB, vB);
        }
    }

    int begA = __builtin_amdgcn_readfirstlane(rowptr[dA]);
    int cntA = __builtin_amdgcn_readfirstlane(counts[dA]);
    int begB = hasB ? __builtin_amdgcn_readfirstlane(rowptr[dB]) : 0;
    int cntB = hasB ? __builtin_amdgcn_readfirstlane(counts[dB]) : 0;
    const int* srowA = ssrc + begA;
    const int* srowB = ssrc + begB;

#define SEL8(e0,e1,e2,e3,e4,e5,e6,e7) \
    (b4 ? (b2 ? (b1 ? e7 : e6) : (b1 ? e5 : e4)) \
        : (b2 ? (b1 ? e3 : e2) : (b1 ? e1 : e0)))

    int jA = 0, jB = 0;
    // joint loop: both streams have a full 16-edge batch
    while (jA + 16 <= cntA && jB + 16 <= cntB) {
        int a0 = srowA[jA + 0],  a1 = srowA[jA + 1],  a2 = srowA[jA + 2],  a3 = srowA[jA + 3];
        int a4 = srowA[jA + 4],  a5 = srowA[jA + 5],  a6 = srowA[jA + 6],  a7 = srowA[jA + 7];
        int a8 = srowA[jA + 8],  a9 = srowA[jA + 9],  aa = srowA[jA + 10], ab = srowA[jA + 11];
        int ac = srowA[jA + 12], ad = srowA[jA + 13], ae = srowA[jA + 14], af = srowA[jA + 15];
        int c0 = srowB[jB + 0],  c1 = srowB[jB + 1],  c2 = srowB[jB + 2],  c3 = srowB[jB + 3];
        int c4 = srowB[jB + 4],  c5 = srowB[jB + 5],  c6 = srowB[jB + 6],  c7 = srowB[jB + 7];
        int c8 = srowB[jB + 8],  c9 = srowB[jB + 9],  ca = srowB[jB + 10], cb = srowB[jB + 11];
        int cc = srowB[jB + 12], cd = srowB[jB + 13], ce = srowB[jB + 14], cf = srowB[jB + 15];
        int tA0 = SEL8(a0, a1, a2, a3, a4, a5, a6, a7);
        int tA1 = SEL8(a8, a9, aa, ab, ac, ad, ae, af);
        int tB0 = SEL8(c0, c1, c2, c3, c4, c5, c6, c7);
        int tB1 = SEL8(c8, c9, ca, cb, cc, cd, ce, cf);
        uint2 vA0 = tab2[(size_t)tA0 * 8 + q];
        uint2 vA1 = tab2[(size_t)tA1 * 8 + q];
        uint2 vB0 = tab2[(size_t)tB0 * 8 + q];
        uint2 vB1 = tab2[(size_t)tB1 * 8 + q];
        ACC(aA, vA0); ACC(aA, vA1);
        ACC(aB, vB0); ACC(aB, vB1);
        jA += 16; jB += 16;
    }
    // drain A
    for (; jA + 16 <= cntA; jA += 16) {
        int a0 = srowA[jA + 0],  a1 = srowA[jA + 1],  a2 = srowA[jA + 2],  a3 = srowA[jA + 3];
        int a4 = srowA[jA + 4],  a5 = srowA[jA + 5],  a6 = srowA[jA + 6],  a7 = srowA[jA + 7];
        int a8 = srowA[jA + 8],  a9 = srowA[jA + 9],  aa = srowA[jA + 10], ab = srowA[jA + 11];
        int ac = srowA[jA + 12], ad = srowA[jA + 13], ae = srowA[jA + 14], af = srowA[jA + 15];
        int tA0 = SEL8(a0, a1, a2, a3, a4, a5, a6, a7);
        int tA1 = SEL8(a8, a9, aa, ab, ac, ad, ae, af);
        uint2 vA0 = tab2[(size_t)tA0 * 8 + q];
        uint2 vA1 = tab2[(size_t)tA1 * 8 + q];
        ACC(aA, vA0); ACC(aA, vA1);
    }
    // drain B
    for (; jB + 16 <= cntB; jB += 16) {
        int c0 = srowB[jB + 0],  c1 = srowB[jB + 1],  c2 = srowB[jB + 2],  c3 = srowB[jB + 3];
        int c4 = srowB[jB + 4],  c5 = srowB[jB + 5],  c6 = srowB[jB + 6],  c7 = srowB[jB + 7];
        int c8 = srowB[jB + 8],  c9 = srowB[jB + 9],  ca = srowB[jB + 10], cb = srowB[jB + 11];
        int cc = srowB[jB + 12], cd = srowB[jB + 13], ce = srowB[jB + 14], cf = srowB[jB + 15];
        int tB0 = SEL8(c0, c1, c2, c3, c4, c5, c6, c7);
        int tB1 = SEL8(c8, c9, ca, cb, cc, cd, ce, cf);
        uint2 vB0 = tab2[(size_t)tB0 * 8 + q];
        uint2 vB1 = tab2[(size_t)tB1 * 8 + q];
        ACC(aB, vB0); ACC(aB, vB1);
    }
    // interleaved tails (rem 0..15 each); sentinel row N for unused slots
    int remA = cntA - jA, remB = cntB - jB;
    if ((remA | remB) != 0) {
        int tA0 = N, tA1 = N, tB0 = N, tB1 = N;
        if (remA) {
            int a0 = srowA[jA + 0], a1 = srowA[jA + 1], a2 = srowA[jA + 2], a3 = srowA[jA + 3];
            int a4 = srowA[jA + 4], a5 = srowA[jA + 5], a6 = srowA[jA + 6], a7 = srowA[jA + 7];
            int t = SEL8(a0, a1, a2, a3, a4, a5, a6, a7);
            tA0 = (sub < remA) ? t : N;
        }
        if (remA > 8) {
            int a8 = srowA[jA + 8],  a9 = srowA[jA + 9],  aa = srowA[jA + 10], ab = srowA[jA + 11];
            int ac = srowA[jA + 12], ad = srowA[jA + 13], ae = srowA[jA + 14], af = srowA[jA + 15];
            int t = SEL8(a8, a9, aa, ab, ac, ad, ae, af);
            tA1 = (sub + 8 < remA) ? t : N;
        }
        if (remB) {
            int c0 = srowB[jB + 0], c1 = srowB[jB + 1], c2 = srowB[jB + 2], c3 = srowB[jB + 3];
            int c4 = srowB[jB + 4], c5 = srowB[jB + 5], c6 = srowB[jB + 6], c7 = srowB[jB + 7];
            int t = SEL8(c0, c1, c2, c3, c4, c5, c6, c7);
            tB0 = (sub < remB) ? t : N;
        }
        if (remB > 8) {
            int c8 = srowB[jB + 8],  c9 = srowB[jB + 9],  ca = srowB[jB + 10], cb = srowB[jB + 11];
            int cc = srowB[jB + 12], cd = srowB[jB + 13], ce = srowB[jB + 14], cf = srowB[jB + 15];
            int t = SEL8(c8, c9, ca, cb, cc, cd, ce, cf);
            tB1 = (sub + 8 < remB) ? t : N;
        }
        uint2 vA0 = tab2[(size_t)tA0 * 8 + q];
        uint2 vA1 = tab2[(size_t)tA1 * 8 + q];
        uint2 vB0 = tab2[(size_t)tB0 * 8 + q];
        uint2 vB1 = tab2[(size_t)tB1 * 8 + q];
        ACC(aA, vA0); ACC(aA, vA1);   // sentinel rows add zeros
        ACC(aB, vB0); ACC(aB, vB1);
    }
#undef SEL8
#undef ACC

#pragma unroll
    for (int i = 0; i < 8; ++i) {
        aA[i] += __shfl_xor(aA[i], 8);
        aA[i] += __shfl_xor(aA[i], 16);
        aA[i] += __shfl_xor(aA[i], 32);
        aB[i] += __shfl_xor(aB[i], 8);
        aB[i] += __shfl_xor(aB[i], 16);
        aB[i] += __shfl_xor(aB[i], 32);
    }

    if (sub == 0) {
        float4* o4 = (float4*)out;
        float ddA = dinv[dA];
        o4[(size_t)dA * 16 + 2 * q + 0] = make_float4(ddA * aA[0], ddA * aA[1], ddA * aA[2], ddA * aA[3]);
        o4[(size_t)dA * 16 + 2 * q + 1] = make_float4(ddA * aA[4], ddA * aA[5], ddA * aA[6], ddA * aA[7]);
        if (hasB) {
            float ddB = dinv[dB];
            o4[(size_t)dB * 16 + 2 * q + 0] = make_float4(ddB * aB[0], ddB * aB[1], ddB * aB[2], ddB * aB[3]);
            o4[(size_t)dB * 16 + 2 * q + 1] = make_float4(ddB * aB[4], ddB * aB[5], ddB * aB[6], ddB * aB[7]);
        }
    }
}

// ============ centroid squared norms ============

__global__ void k_c2(const float* __restrict__ C, float* __restrict__ c2) {
    int k = threadIdx.x;
    if (k < 100) {
        float s = 0.f;
        for (int d = 0; d < 64; ++d) { float v = C[k * 64 + d]; s = fmaf(v, v, s); }
        c2[k] = s;
    }
}

// ============ centroid distances + pooling via MFMA ============
// 128 rows/block (4 waves x 32 rows) -> 782 blocks for latency hiding.

__global__ __launch_bounds__(256) void k_cent(const float* __restrict__ hin,
                                              const float* __restrict__ b2,
                                              const float* __restrict__ C,
                                              const float* __restrict__ c2g,
                                              float* __restrict__ partials, int N) {
    __shared__ float pool4[4][112];
    __shared__ float h2_s[128];
    int tid = threadIdx.x;
    int lane = tid & 63, w = tid >> 6;
    int l15 = lane & 15, lg = lane >> 4;      // lg = 0..3

    bf16x8 B[7][2];
#pragma unroll
    for (int ct = 0; ct < 7; ++ct) {
        int col = ct * 16 + l15;
#pragma unroll
        for (int ks = 0; ks < 2; ++ks) {
            float4 v0 = make_float4(0.f, 0.f, 0.f, 0.f);
            float4 v1 = make_float4(0.f, 0.f, 0.f, 0.f);
            if (col < 100) {
                const float* cr = C + (size_t)col * 64 + ks * 32 + lg * 8;
                v0 = *(const float4*)cr;
                v1 = *(const float4*)(cr + 4);
            }
            B[ct][ks] = pack_bf16x8(v0, v1);
        }
    }

    float bv[16];
#pragma unroll
    for (int ks = 0; ks < 2; ++ks) {
        float4 b0 = *(const float4*)(b2 + ks * 32 + lg * 8);
        float4 b1 = *(const float4*)(b2 + ks * 32 + lg * 8 + 4);
        bv[ks * 8 + 0] = b0.x; bv[ks * 8 + 1] = b0.y;
        bv[ks * 8 + 2] = b0.z; bv[ks * 8 + 3] = b0.w;
        bv[ks * 8 + 4] = b1.x; bv[ks * 8 + 5] = b1.y;
        bv[ks * 8 + 6] = b1.z; bv[ks * 8 + 7] = b1.w;
    }

    int rowbase = blockIdx.x * 128 + w * 32;

    f32x4 acc[2][7];
#pragma unroll
    for (int rt = 0; rt < 2; ++rt)
#pragma unroll
        for (int ct = 0; ct < 7; ++ct)
            acc[rt][ct] = (f32x4){0.f, 0.f, 0.f, 0.f};

#pragma unroll
    for (int rt = 0; rt < 2; ++rt) {
        int row = rowbase + rt * 16 + l15;
        int rowc = (row < N) ? row : (N - 1);     // clamp; excluded from pooling
        const float* hr = hin + ((size_t)rowc << 6);
        float hp[16];
        float h2p = 0.f;
#pragma unroll
        for (int ks = 0; ks < 2; ++ks) {
            float4 v0 = *(const float4*)(hr + ks * 32 + lg * 8);
            float4 v1 = *(const float4*)(hr + ks * 32 + lg * 8 + 4);
            float t0 = fmaxf(v0.x + bv[ks * 8 + 0], 0.f);
            float t1 = fmaxf(v0.y + bv[ks * 8 + 1], 0.f);
            float t2 = fmaxf(v0.z + bv[ks * 8 + 2], 0.f);
            float t3 = fmaxf(v0.w + bv[ks * 8 + 3], 0.f);
            float t4 = fmaxf(v1.x + bv[ks * 8 + 4], 0.f);
            float t5 = fmaxf(v1.y + bv[ks * 8 + 5], 0.f);
            float t6 = fmaxf(v1.z + bv[ks * 8 + 6], 0.f);
            float t7 = fmaxf(v1.w + bv[ks * 8 + 7], 0.f);
            hp[ks * 8 + 0] = t0; hp[ks * 8 + 1] = t1;
            hp[ks * 8 + 2] = t2; hp[ks * 8 + 3] = t3;
            hp[ks * 8 + 4] = t4; hp[ks * 8 + 5] = t5;
            hp[ks * 8 + 6] = t6; hp[ks * 8 + 7] = t7;
            h2p = fmaf(t0, t0, h2p); h2p = fmaf(t1, t1, h2p);
            h2p = fmaf(t2, t2, h2p); h2p = fmaf(t3, t3, h2p);
            h2p = fmaf(t4, t4, h2p); h2p = fmaf(t5, t5, h2p);
            h2p = fmaf(t6, t6, h2p); h2p = fmaf(t7, t7, h2p);
        }
        h2p += __shfl_xor(h2p, 16);
        h2p += __shfl_xor(h2p, 32);
        if (lg == 0) h2_s[w * 32 + rt * 16 + l15] = h2p;

#pragma unroll
        for (int ks = 0; ks < 2; ++ks) {
            bf16x8 a;
#pragma unroll
            for (int j = 0; j < 8; ++j) a[j] = f2bf(hp[ks * 8 + j]);
#pragma unroll
            for (int ct = 0; ct < 7; ++ct)
                acc[rt][ct] = __builtin_amdgcn_mfma_f32_16x16x32_bf16(
                    a, B[ct][ks], acc[rt][ct], 0, 0, 0);
        }
    }

    float S[7] = {0.f, 0.f, 0.f, 0.f, 0.f, 0.f, 0.f};
#pragma unroll
    for (int rt = 0; rt < 2; ++rt) {
#pragma unroll
        for (int r = 0; r < 4; ++r) {
            int row = rowbase + rt * 16 + lg * 4 + r;
            float h2v = h2_s[w * 32 + rt * 16 + lg * 4 + r];
            bool rv = row < N;
#pragma unroll
            for (int ct = 0; ct < 7; ++ct) {
                int col = ct * 16 + l15;
                float c2v = (col < 100) ? c2g[col] : 0.f;
                float G = acc[rt][ct][r];
                float d2 = fmaxf(h2v + c2v - 2.f * G, 0.f);
                float xx = d2 + 1e-12f;
                float dist = xx * __frsqrt_rn(xx);       // sqrt via rsq, 1 trans op
                S[ct] += (rv && col < 100) ? dist : 0.f;
            }
        }
    }
#pragma unroll
    for (int ct = 0; ct < 7; ++ct) {
        float s = S[ct];
        s += __shfl_xor(s, 16);
        s += __shfl_xor(s, 32);
        if (lg == 0) pool4[w][ct * 16 + l15] = s;   // S[ct]=0 for padded cols
    }
    __syncthreads();
    if (tid < 112) {
        float s = pool4[0][tid] + pool4[1][tid] + pool4[2][tid] + pool4[3][tid];
        partials[(size_t)blockIdx.x * 128 + tid] = s;
    }
}

// ============ output head: reduce partials + apply W_out ============
// 8 groups x 128; 8-wide unrolled strided sum (independent accumulators for MLP
// -- the rolled loop was a 98-deep latency chain = 50us on one CU).

__global__ __launch_bounds__(1024) void k_out(const float* __restrict__ partials, int nb,
                                              const float* __restrict__ Wout,
                                              const float* __restrict__ bout,
                                              float* __restrict__ out, float invN) {
    __shared__ float ps[8][112];
    int t = threadIdx.x & 127, g = threadIdx.x >> 7;
    if (t < 112) {
        float s0 = 0.f, s1 = 0.f, s2 = 0.f, s3 = 0.f;
        float s4 = 0.f, s5 = 0.f, s6 = 0.f, s7 = 0.f;
        int b = g;
        for (; b + 56 < nb; b += 64) {
            s0 += partials[(size_t)(b     ) * 128 + t];
            s1 += partials[(size_t)(b +  8) * 128 + t];
            s2 += partials[(size_t)(b + 16) * 128 + t];
            s3 += partials[(size_t)(b + 24) * 128 + t];
            s4 += partials[(size_t)(b + 32) * 128 + t];
            s5 += partials[(size_t)(b + 40) * 128 + t];
            s6 += partials[(size_t)(b + 48) * 128 + t];
            s7 += partials[(size_t)(b + 56) * 128 + t];
        }
        for (; b < nb; b += 8) s0 += partials[(size_t)b * 128 + t];
        ps[g][t] = ((s0 + s1) + (s2 + s3)) + ((s4 + s5) + (s6 + s7));
    }
    __syncthreads();
    if (threadIdx.x < 10) {
        int tt = threadIdx.x;
        float s = 0.f;
        for (int k = 0; k < 100; ++k) {
            float p = ps[0][k] + ps[1][k] + ps[2][k] + ps[3][k]
                    + ps[4][k] + ps[5][k] + ps[6][k] + ps[7][k];
            s = fmaf(p, Wout[tt * 100 + k], s);
        }
        out[tt] = s * invN + bout[tt];
    }
}

// ============ launcher ============

extern "C" void kernel_launch(void* const* d_in, const int* in_sizes, int n_in,
                              void* d_out, int out_size, void* d_ws, size_t ws_size,
                              hipStream_t stream) {
    const float* x    = (const float*)d_in[0];
    const int*   ei   = (const int*)d_in[1];
    const float* We   = (const float*)d_in[2];
    const float* Wg   = (const float*)d_in[3];
    const float* bg   = (const float*)d_in[4];
    const float* C    = (const float*)d_in[5];
    const float* Wout = (const float*)d_in[6];
    const float* bout = (const float*)d_in[7];
    float*       out  = (float*)d_out;

    const int N = in_sizes[0] / 128;          // 100000
    const int E = in_sizes[1] / 2;            // 1600000
    const int NBUCK = (N + 255) >> 8;         // 391 dst-buckets
    const int NCH = (E + CHUNK - 1) / CHUNK;  // 98 chunks
    const int NBC = (N + 127) / 128;          // k_cent blocks (782)

    char* ws = (char*)d_ws;
    size_t off = 0;
    auto alloc = [&](size_t bytes) { void* p = ws + off; off += (bytes + 511) & ~(size_t)511; return p; };
    float*  dinv   = (float*)alloc((size_t)N * 4);
    int*    counts = (int*)  alloc((size_t)N * 4);
    int*    rowptr = (int*)  alloc((size_t)N * 4);
    int*    bcnt   = (int*)  alloc((size_t)NBUCK * NCH * 4);
    int*    bofs   = (int*)  alloc((size_t)NBUCK * NCH * 4);
    int*    btot   = (int*)  alloc((size_t)NBUCK * 4);
    int*    bbase  = (int*)  alloc((size_t)(NBUCK + 1) * 4);
    uint32* ebuf   = (uint32*)alloc((size_t)E * 4);
    int*    ssrc   = (int*)  alloc((size_t)(E + 16) * 4);     // +16 pad for agg reads
    float*  hA     = (float*)alloc((size_t)N * 64 * 4);
    uint32* tab    = (uint32*)alloc((size_t)(N + 1) * 64);    // fp8 table + sentinel row
    float*  c2     = (float*)alloc(512);
    float*  partials = (float*)alloc((size_t)NBC * 128 * 4);

    hipMemsetAsync(tab + (size_t)N * 16, 0, 64, stream);      // sentinel row N = 0

    // bucketed CSR build (no global atomics)
    k_bhist<<<NCH, 256, 0, stream>>>(ei + E, bcnt, E, NBUCK, NCH);
    k_bscan1<<<NBUCK, 128, 0, stream>>>(bcnt, bofs, btot, NCH);
    k_bscan2<<<1, 512, 0, stream>>>(btot, bbase, NBUCK);
    k_bscatter<<<NCH, 256, 0, stream>>>(ei, bbase, bofs, ebuf, E, NBUCK, NCH);
    k_bsort<<<NBUCK, 256, 0, stream>>>(ebuf, bbase, ssrc, rowptr, counts, dinv, N);
    k_c2<<<1, 128, 0, stream>>>(C, c2);

    // embed (MFMA bf16, 256 rows/block)
    k_embed<<<(N + 255) / 256, 256, 0, stream>>>(x, We, hA, N);

    // 3 GCN layers: gemm (hA -> fp8 tab, scaled by dinv), aggregate (tab -> hA fp32)
    for (int l = 0; l < 3; ++l) {
        const float* bias_prev = (l == 0) ? bg : (bg + (l - 1) * 64);
        int act = (l == 0) ? 0 : 1;
        k_gcn<<<(N + 255) / 256, 256, 0, stream>>>(hA, Wg + (size_t)l * 64 * 64,
                                                   bias_prev, act, dinv, tab, N);
        k_agg<<<(N + 7) / 8, 256, 0, stream>>>(rowptr, counts, ssrc, dinv,
                                               (const uint2*)tab, hA, N);
    }

    // centroid distances + pooling via MFMA (applies relu + b_gcn[2])
    k_cent<<<NBC, 256, 0, stream>>>(hA, bg + 2 * 64, C, c2, partials, N);

    // head: reduce partials + W_out
    k_out<<<1, 1024, 0, stream>>>(partials, NBC, Wout, bout, out, 1.0f / (float)N);
}

// Round 6
// 383.940 us; speedup vs baseline: 1.1515x; 1.0365x over previous
//
#include <hip/hip_runtime.h>
#include <hip/hip_bf16.h>

typedef unsigned int uint32;
typedef float floatx2 __attribute__((ext_vector_type(2)));
typedef __attribute__((ext_vector_type(8))) short bf16x8;
typedef __attribute__((ext_vector_type(4))) float f32x4;

#define CHUNK 16384

// ============ bucketed CSR build (dst>>8 buckets, LDS-atomic sort) ============

__global__ __launch_bounds__(256) void k_bhist(const int* __restrict__ dst,
                                               int* __restrict__ bcnt,
                                               int E, int NBUCK, int NCH) {
    __shared__ int h[512];
    int c = blockIdx.x, tid = threadIdx.x;
    for (int i = tid; i < NBUCK; i += 256) h[i] = 0;
    __syncthreads();
    int base = c * CHUNK;
#pragma unroll
    for (int k = 0; k < CHUNK / 256; ++k) {
        int e = base + k * 256 + tid;
        if (e < E) atomicAdd(&h[dst[e] >> 8], 1);
    }
    __syncthreads();
    for (int i = tid; i < NBUCK; i += 256) bcnt[(size_t)i * NCH + c] = h[i];
}

__global__ __launch_bounds__(128) void k_bscan1(const int* __restrict__ bcnt,
                                                int* __restrict__ bofs,
                                                int* __restrict__ btot, int NCH) {
    __shared__ int tmp[128];
    int b = blockIdx.x, t = threadIdx.x;
    int v = (t < NCH) ? bcnt[(size_t)b * NCH + t] : 0;
    tmp[t] = v;
    __syncthreads();
    for (int off = 1; off < 128; off <<= 1) {
        int u = (t >= off) ? tmp[t - off] : 0;
        __syncthreads();
        tmp[t] += u;
        __syncthreads();
    }
    if (t < NCH) bofs[(size_t)b * NCH + t] = tmp[t] - v;
    if (t == 127) btot[b] = tmp[127];
}

__global__ __launch_bounds__(512) void k_bscan2(const int* __restrict__ btot,
                                                int* __restrict__ bbase, int nb) {
    __shared__ int tmp[512];
    int t = threadIdx.x;
    int v = (t < nb) ? btot[t] : 0;
    tmp[t] = v;
    __syncthreads();
    for (int off = 1; off < 512; off <<= 1) {
        int u = (t >= off) ? tmp[t - off] : 0;
        __syncthreads();
        tmp[t] += u;
        __syncthreads();
    }
    if (t < nb) bbase[t] = tmp[t] - v;
    if (t == nb - 1) bbase[nb] = tmp[t];
}

__global__ __launch_bounds__(256) void k_bscatter(const int* __restrict__ ei,
                                                  const int* __restrict__ bbase,
                                                  const int* __restrict__ bofs,
                                                  uint32* __restrict__ ebuf,
                                                  int E, int NBUCK, int NCH) {
    __shared__ int cur[512];
    int c = blockIdx.x, tid = threadIdx.x;
    for (int i = tid; i < NBUCK; i += 256)
        cur[i] = bbase[i] + bofs[(size_t)i * NCH + c];
    __syncthreads();
    int base = c * CHUNK;
#pragma unroll
    for (int k = 0; k < CHUNK / 256; ++k) {
        int e = base + k * 256 + tid;
        if (e < E) {
            int s = ei[e];
            int d = ei[E + e];
            int p = atomicAdd(&cur[d >> 8], 1);
            ebuf[p] = (uint32)s | ((uint32)(d & 255) << 20);
        }
    }
}

__global__ __launch_bounds__(256) void k_bsort(const uint32* __restrict__ ebuf,
                                               const int* __restrict__ bbase,
                                               int* __restrict__ ssrc,
                                               int2* __restrict__ rc,
                                               float* __restrict__ dinv, int N) {
    __shared__ int h[256];
    __shared__ int sc[256];
    __shared__ int cur[256];
    int b = blockIdx.x, tid = threadIdx.x;
    int beg = bbase[b], end = bbase[b + 1];
    h[tid] = 0;
    __syncthreads();
    for (int j = beg + tid; j < end; j += 256)
        atomicAdd(&h[(ebuf[j] >> 20) & 255], 1);
    __syncthreads();
    int v = h[tid];
    sc[tid] = v;
    __syncthreads();
    for (int off = 1; off < 256; off <<= 1) {
        int u = (tid >= off) ? sc[tid - off] : 0;
        __syncthreads();
        sc[tid] += u;
        __syncthreads();
    }
    int rowbase = beg + sc[tid] - v;
    cur[tid] = rowbase;
    int d = b * 256 + tid;
    if (d < N) {
        rc[d] = make_int2(rowbase, v);
        dinv[d] = rsqrtf((float)(v + 1));   // +1 self loop
    }
    __syncthreads();
    for (int j = beg + tid; j < end; j += 256) {
        uint32 w = ebuf[j];
        int p = atomicAdd(&cur[(w >> 20) & 255], 1);
        ssrc[p] = (int)(w & 0xFFFFFu);
    }
}

// ============ fp32 -> bf16 (RNE) helpers ============

__device__ __forceinline__ short f2bf(float f) {
    __hip_bfloat16 b = __float2bfloat16(f);
    return __builtin_bit_cast(short, b);
}

__device__ __forceinline__ bf16x8 pack_bf16x8(float4 v0, float4 v1) {
    bf16x8 r;
    r[0] = f2bf(v0.x); r[1] = f2bf(v0.y); r[2] = f2bf(v0.z); r[3] = f2bf(v0.w);
    r[4] = f2bf(v1.x); r[5] = f2bf(v1.y); r[6] = f2bf(v1.z); r[7] = f2bf(v1.w);
    return r;
}

// ============ embed GEMM via MFMA: h = x @ We^T ([N,128] @ [128,64]^T) ============
// Layouts (m89-verified): A[lane&15][(lane>>4)*8+j], B[(lane>>4)*8+j][lane&15],
// D[(lane>>4)*4+r][lane&15].

__global__ __launch_bounds__(256) void k_embed(const float* __restrict__ x,
                                               const float* __restrict__ We,
                                               float* __restrict__ h, int N) {
    int lane = threadIdx.x & 63;
    int w = threadIdx.x >> 6;
    int l15 = lane & 15;
    int lg = lane >> 4;                       // 0..3

    bf16x8 B[4][4];
#pragma unroll
    for (int ct = 0; ct < 4; ++ct) {
        const float* wr = We + (size_t)(ct * 16 + l15) * 128 + lg * 8;
#pragma unroll
        for (int ks = 0; ks < 4; ++ks) {
            float4 v0 = *(const float4*)(wr + ks * 32);
            float4 v1 = *(const float4*)(wr + ks * 32 + 4);
            B[ct][ks] = pack_bf16x8(v0, v1);
        }
    }

    int rowbase = blockIdx.x * 256 + w * 64;

    f32x4 acc[4][4];
#pragma unroll
    for (int rt = 0; rt < 4; ++rt)
#pragma unroll
        for (int ct = 0; ct < 4; ++ct)
            acc[rt][ct] = (f32x4){0.f, 0.f, 0.f, 0.f};

#pragma unroll
    for (int ks = 0; ks < 4; ++ks) {
#pragma unroll
        for (int rt = 0; rt < 4; ++rt) {
            int row = rowbase + rt * 16 + l15;
            row = (row < N) ? row : (N - 1);          // clamp; stores predicated
            const float* xr = x + (size_t)row * 128 + ks * 32 + lg * 8;
            float4 v0 = *(const float4*)xr;
            float4 v1 = *(const float4*)(xr + 4);
            bf16x8 a = pack_bf16x8(v0, v1);
#pragma unroll
            for (int ct = 0; ct < 4; ++ct)
                acc[rt][ct] = __builtin_amdgcn_mfma_f32_16x16x32_bf16(
                    a, B[ct][ks], acc[rt][ct], 0, 0, 0);
        }
    }

#pragma unroll
    for (int rt = 0; rt < 4; ++rt) {
        int row0 = rowbase + rt * 16 + lg * 4;
#pragma unroll
        for (int r = 0; r < 4; ++r) {
            int row = row0 + r;
            if (row < N) {
#pragma unroll
                for (int ct = 0; ct < 4; ++ct)
                    h[(size_t)row * 64 + ct * 16 + l15] = acc[rt][ct][r];
            }
        }
    }
}

// ============ GCN layer GEMM via MFMA (swapped operands, direct fp8 pack) ====
// D = Wg . act(h)^T: lane holds node col=l15, out-features lg*4+r per rt tile
// -> 4 acc regs = 4 consecutive features = one fp8 uint32. No LDS.

__global__ __launch_bounds__(256) void k_gcn(const float* __restrict__ hin,
                                             const float* __restrict__ Wg,
                                             const float* __restrict__ bias_prev, int act,
                                             const float* __restrict__ dinv,
                                             uint32* __restrict__ tab, int N) {
    int lane = threadIdx.x & 63;
    int w = threadIdx.x >> 6;
    int l15 = lane & 15, lg = lane >> 4;

    bf16x8 A[4][2];
#pragma unroll
    for (int rt = 0; rt < 4; ++rt) {
        const float* wr = Wg + (size_t)(rt * 16 + l15) * 64 + lg * 8;
#pragma unroll
        for (int ks = 0; ks < 2; ++ks) {
            float4 v0 = *(const float4*)(wr + ks * 32);
            float4 v1 = *(const float4*)(wr + ks * 32 + 4);
            A[rt][ks] = pack_bf16x8(v0, v1);
        }
    }

    float bv[16];
#pragma unroll
    for (int ks = 0; ks < 2; ++ks) {
        float4 b0 = *(const float4*)(bias_prev + ks * 32 + lg * 8);
        float4 b1 = *(const float4*)(bias_prev + ks * 32 + lg * 8 + 4);
        bv[ks * 8 + 0] = b0.x; bv[ks * 8 + 1] = b0.y;
        bv[ks * 8 + 2] = b0.z; bv[ks * 8 + 3] = b0.w;
        bv[ks * 8 + 4] = b1.x; bv[ks * 8 + 5] = b1.y;
        bv[ks * 8 + 6] = b1.z; bv[ks * 8 + 7] = b1.w;
    }

    int nodebase = blockIdx.x * 256 + w * 64;   // wave: 64 nodes = 4 tiles of 16

#pragma unroll
    for (int nt = 0; nt < 4; ++nt) {
        int node = nodebase + nt * 16 + l15;
        int nodec = (node < N) ? node : (N - 1);
        const float* hr = hin + ((size_t)nodec << 6) + lg * 8;

        bf16x8 Bf[2];
#pragma unroll
        for (int ks = 0; ks < 2; ++ks) {
            float4 v0 = *(const float4*)(hr + ks * 32);
            float4 v1 = *(const float4*)(hr + ks * 32 + 4);
            if (act) {
                v0.x = fmaxf(v0.x + bv[ks * 8 + 0], 0.f);
                v0.y = fmaxf(v0.y + bv[ks * 8 + 1], 0.f);
                v0.z = fmaxf(v0.z + bv[ks * 8 + 2], 0.f);
                v0.w = fmaxf(v0.w + bv[ks * 8 + 3], 0.f);
                v1.x = fmaxf(v1.x + bv[ks * 8 + 4], 0.f);
                v1.y = fmaxf(v1.y + bv[ks * 8 + 5], 0.f);
                v1.z = fmaxf(v1.z + bv[ks * 8 + 6], 0.f);
                v1.w = fmaxf(v1.w + bv[ks * 8 + 7], 0.f);
            }
            Bf[ks] = pack_bf16x8(v0, v1);
        }

        f32x4 acc[4];
#pragma unroll
        for (int rt = 0; rt < 4; ++rt) acc[rt] = (f32x4){0.f, 0.f, 0.f, 0.f};
#pragma unroll
        for (int ks = 0; ks < 2; ++ks)
#pragma unroll
            for (int rt = 0; rt < 4; ++rt)
                acc[rt] = __builtin_amdgcn_mfma_f32_16x16x32_bf16(
                    A[rt][ks], Bf[ks], acc[rt], 0, 0, 0);

        float s = dinv[nodec];
        if (node < N) {
#pragma unroll
            for (int rt = 0; rt < 4; ++rt) {
                int u = 0;
                u = __builtin_amdgcn_cvt_pk_fp8_f32(acc[rt][0] * s, acc[rt][1] * s, u, false);
                u = __builtin_amdgcn_cvt_pk_fp8_f32(acc[rt][2] * s, acc[rt][3] * s, u, true);
                tab[(size_t)node * 16 + rt * 4 + lg] = u;
            }
        }
    }
}

// ============ fp8 CSR gather-aggregate: one wave per dst ====================
// Edge indices: ONE coalesced per-lane load (srow[j + (lane&15)]) + two __shfl
// replaces 16 broadcast loads + two 7-deep cndmask SEL trees (R4 post-mortem:
// instruction issue, not chain latency, was the throttle). floatx2 accumulators
// -> v_pk_add_f32. Tails are branch-free via sentinel row N (zeros).

__global__ __launch_bounds__(256) void k_agg(const int2* __restrict__ rc,
                                             const int* __restrict__ ssrc,
                                             const float* __restrict__ dinv,
                                             const uint2* __restrict__ tab2,
                                             float* __restrict__ out, int N) {
    int lane = threadIdx.x & 63;
    int d = blockIdx.x * 4 + (threadIdx.x >> 6);
    if (d >= N) return;
    int q = lane & 7;
    int sub = lane >> 3;
    int l15 = lane & 15;
    int hi = lane & 48;

    floatx2 a01 = {0.f, 0.f}, a23 = {0.f, 0.f}, a45 = {0.f, 0.f}, a67 = {0.f, 0.f};
    auto accum = [&](uint2 v) {
        a01 += __builtin_amdgcn_cvt_pk_f32_fp8((int)v.x, false);
        a23 += __builtin_amdgcn_cvt_pk_f32_fp8((int)v.x, true);
        a45 += __builtin_amdgcn_cvt_pk_f32_fp8((int)v.y, false);
        a67 += __builtin_amdgcn_cvt_pk_f32_fp8((int)v.y, true);
    };

    // self loop (counted once)
    {
        uint2 v = tab2[(size_t)d * 8 + q];
        if (sub == 0) accum(v);
    }

    int2 r = rc[d];
    int beg = __builtin_amdgcn_readfirstlane(r.x);
    int cnt = __builtin_amdgcn_readfirstlane(r.y);
    const int* srow = ssrc + beg;

    int j = 0;
    for (; j + 16 <= cnt; j += 16) {
        int ev = srow[j + l15];                    // one coalesced load, 16 edges
        int t0 = __shfl(ev, hi | sub);             // srow[j + sub]
        int t1 = __shfl(ev, hi | 8 | sub);         // srow[j + 8 + sub]
        uint2 v0 = tab2[(size_t)t0 * 8 + q];
        uint2 v1 = tab2[(size_t)t1 * 8 + q];
        accum(v0);
        accum(v1);
    }
    int rem = cnt - j;                             // 0..15, wave-uniform
    if (rem) {
        int ev = srow[j + l15];                    // ssrc has +16 pad
        int t0 = __shfl(ev, hi | sub);
        int t1 = __shfl(ev, hi | 8 | sub);
        t0 = (sub < rem) ? t0 : N;                 // sentinel row N = zeros
        t1 = (sub + 8 < rem) ? t1 : N;
        uint2 v0 = tab2[(size_t)t0 * 8 + q];
        uint2 v1 = tab2[(size_t)t1 * 8 + q];
        accum(v0);
        accum(v1);
    }

    float a[8] = {a01.x, a01.y, a23.x, a23.y, a45.x, a45.y, a67.x, a67.y};
#pragma unroll
    for (int i = 0; i < 8; ++i) {
        a[i] += __shfl_xor(a[i], 8);
        a[i] += __shfl_xor(a[i], 16);
        a[i] += __shfl_xor(a[i], 32);
    }

    if (sub == 0) {
        float dd = dinv[d];
        float4* o4 = (float4*)out;
        o4[(size_t)d * 16 + 2 * q + 0] = make_float4(dd * a[0], dd * a[1], dd * a[2], dd * a[3]);
        o4[(size_t)d * 16 + 2 * q + 1] = make_float4(dd * a[4], dd * a[5], dd * a[6], dd * a[7]);
    }
}

// ============ centroid squared norms ============

__global__ void k_c2(const float* __restrict__ C, float* __restrict__ c2) {
    int k = threadIdx.x;
    if (k < 100) {
        float s = 0.f;
        for (int d = 0; d < 64; ++d) { float v = C[k * 64 + d]; s = fmaf(v, v, s); }
        c2[k] = s;
    }
}

// ============ centroid distances + pooling via MFMA ============
// 128 rows/block (4 waves x 32 rows) -> 782 blocks for latency hiding.

__global__ __launch_bounds__(256) void k_cent(const float* __restrict__ hin,
                                              const float* __restrict__ b2,
                                              const float* __restrict__ C,
                                              const float* __restrict__ c2g,
                                              float* __restrict__ partials, int N) {
    __shared__ float pool4[4][112];
    __shared__ float h2_s[128];
    int tid = threadIdx.x;
    int lane = tid & 63, w = tid >> 6;
    int l15 = lane & 15, lg = lane >> 4;      // lg = 0..3

    bf16x8 B[7][2];
#pragma unroll
    for (int ct = 0; ct < 7; ++ct) {
        int col = ct * 16 + l15;
#pragma unroll
        for (int ks = 0; ks < 2; ++ks) {
            float4 v0 = make_float4(0.f, 0.f, 0.f, 0.f);
            float4 v1 = make_float4(0.f, 0.f, 0.f, 0.f);
            if (col < 100) {
                const float* cr = C + (size_t)col * 64 + ks * 32 + lg * 8;
                v0 = *(const float4*)cr;
                v1 = *(const float4*)(cr + 4);
            }
            B[ct][ks] = pack_bf16x8(v0, v1);
        }
    }

    float bv[16];
#pragma unroll
    for (int ks = 0; ks < 2; ++ks) {
        float4 b0 = *(const float4*)(b2 + ks * 32 + lg * 8);
        float4 b1 = *(const float4*)(b2 + ks * 32 + lg * 8 + 4);
        bv[ks * 8 + 0] = b0.x; bv[ks * 8 + 1] = b0.y;
        bv[ks * 8 + 2] = b0.z; bv[ks * 8 + 3] = b0.w;
        bv[ks * 8 + 4] = b1.x; bv[ks * 8 + 5] = b1.y;
        bv[ks * 8 + 6] = b1.z; bv[ks * 8 + 7] = b1.w;
    }

    int rowbase = blockIdx.x * 128 + w * 32;

    f32x4 acc[2][7];
#pragma unroll
    for (int rt = 0; rt < 2; ++rt)
#pragma unroll
        for (int ct = 0; ct < 7; ++ct)
            acc[rt][ct] = (f32x4){0.f, 0.f, 0.f, 0.f};

#pragma unroll
    for (int rt = 0; rt < 2; ++rt) {
        int row = rowbase + rt * 16 + l15;
        int rowc = (row < N) ? row : (N - 1);     // clamp; excluded from pooling
        const float* hr = hin + ((size_t)rowc << 6);
        float hp[16];
        float h2p = 0.f;
#pragma unroll
        for (int ks = 0; ks < 2; ++ks) {
            float4 v0 = *(const float4*)(hr + ks * 32 + lg * 8);
            float4 v1 = *(const float4*)(hr + ks * 32 + lg * 8 + 4);
            float t0 = fmaxf(v0.x + bv[ks * 8 + 0], 0.f);
            float t1 = fmaxf(v0.y + bv[ks * 8 + 1], 0.f);
            float t2 = fmaxf(v0.z + bv[ks * 8 + 2], 0.f);
            float t3 = fmaxf(v0.w + bv[ks * 8 + 3], 0.f);
            float t4 = fmaxf(v1.x + bv[ks * 8 + 4], 0.f);
            float t5 = fmaxf(v1.y + bv[ks * 8 + 5], 0.f);
            float t6 = fmaxf(v1.z + bv[ks * 8 + 6], 0.f);
            float t7 = fmaxf(v1.w + bv[ks * 8 + 7], 0.f);
            hp[ks * 8 + 0] = t0; hp[ks * 8 + 1] = t1;
            hp[ks * 8 + 2] = t2; hp[ks * 8 + 3] = t3;
            hp[ks * 8 + 4] = t4; hp[ks * 8 + 5] = t5;
            hp[ks * 8 + 6] = t6; hp[ks * 8 + 7] = t7;
            h2p = fmaf(t0, t0, h2p); h2p = fmaf(t1, t1, h2p);
            h2p = fmaf(t2, t2, h2p); h2p = fmaf(t3, t3, h2p);
            h2p = fmaf(t4, t4, h2p); h2p = fmaf(t5, t5, h2p);
            h2p = fmaf(t6, t6, h2p); h2p = fmaf(t7, t7, h2p);
        }
        h2p += __shfl_xor(h2p, 16);
        h2p += __shfl_xor(h2p, 32);
        if (lg == 0) h2_s[w * 32 + rt * 16 + l15] = h2p;

#pragma unroll
        for (int ks = 0; ks < 2; ++ks) {
            bf16x8 a;
#pragma unroll
            for (int j = 0; j < 8; ++j) a[j] = f2bf(hp[ks * 8 + j]);
#pragma unroll
            for (int ct = 0; ct < 7; ++ct)
                acc[rt][ct] = __builtin_amdgcn_mfma_f32_16x16x32_bf16(
                    a, B[ct][ks], acc[rt][ct], 0, 0, 0);
        }
    }

    float S[7] = {0.f, 0.f, 0.f, 0.f, 0.f, 0.f, 0.f};
#pragma unroll
    for (int rt = 0; rt < 2; ++rt) {
#pragma unroll
        for (int r = 0; r < 4; ++r) {
            int row = rowbase + rt * 16 + lg * 4 + r;
            float h2v = h2_s[w * 32 + rt * 16 + lg * 4 + r];
            bool rv = row < N;
#pragma unroll
            for (int ct = 0; ct < 7; ++ct) {
                int col = ct * 16 + l15;
                float c2v = (col < 100) ? c2g[col] : 0.f;
                float G = acc[rt][ct][r];
                float d2 = fmaxf(h2v + c2v - 2.f * G, 0.f);
                float xx = d2 + 1e-12f;
                float dist = xx * __frsqrt_rn(xx);       // sqrt via rsq, 1 trans op
                S[ct] += (rv && col < 100) ? dist : 0.f;
            }
        }
    }
#pragma unroll
    for (int ct = 0; ct < 7; ++ct) {
        float s = S[ct];
        s += __shfl_xor(s, 16);
        s += __shfl_xor(s, 32);
        if (lg == 0) pool4[w][ct * 16 + l15] = s;   // S[ct]=0 for padded cols
    }
    __syncthreads();
    if (tid < 112) {
        float s = pool4[0][tid] + pool4[1][tid] + pool4[2][tid] + pool4[3][tid];
        partials[(size_t)blockIdx.x * 128 + tid] = s;
    }
}

// ============ output head: reduce partials + apply W_out ============
// 8 groups x 128; 8-wide unrolled strided sum (independent accumulators for MLP).

__global__ __launch_bounds__(1024) void k_out(const float* __restrict__ partials, int nb,
                                              const float* __restrict__ Wout,
                                              const float* __restrict__ bout,
                                              float* __restrict__ out, float invN) {
    __shared__ float ps[8][112];
    int t = threadIdx.x & 127, g = threadIdx.x >> 7;
    if (t < 112) {
        float s0 = 0.f, s1 = 0.f, s2 = 0.f, s3 = 0.f;
        float s4 = 0.f, s5 = 0.f, s6 = 0.f, s7 = 0.f;
        int b = g;
        for (; b + 56 < nb; b += 64) {
            s0 += partials[(size_t)(b     ) * 128 + t];
            s1 += partials[(size_t)(b +  8) * 128 + t];
            s2 += partials[(size_t)(b + 16) * 128 + t];
            s3 += partials[(size_t)(b + 24) * 128 + t];
            s4 += partials[(size_t)(b + 32) * 128 + t];
            s5 += partials[(size_t)(b + 40) * 128 + t];
            s6 += partials[(size_t)(b + 48) * 128 + t];
            s7 += partials[(size_t)(b + 56) * 128 + t];
        }
        for (; b < nb; b += 8) s0 += partials[(size_t)b * 128 + t];
        ps[g][t] = ((s0 + s1) + (s2 + s3)) + ((s4 + s5) + (s6 + s7));
    }
    __syncthreads();
    if (threadIdx.x < 10) {
        int tt = threadIdx.x;
        float s = 0.f;
        for (int k = 0; k < 100; ++k) {
            float p = ps[0][k] + ps[1][k] + ps[2][k] + ps[3][k]
                    + ps[4][k] + ps[5][k] + ps[6][k] + ps[7][k];
            s = fmaf(p, Wout[tt * 100 + k], s);
        }
        out[tt] = s * invN + bout[tt];
    }
}

// ============ launcher ============

extern "C" void kernel_launch(void* const* d_in, const int* in_sizes, int n_in,
                              void* d_out, int out_size, void* d_ws, size_t ws_size,
                              hipStream_t stream) {
    const float* x    = (const float*)d_in[0];
    const int*   ei   = (const int*)d_in[1];
    const float* We   = (const float*)d_in[2];
    const float* Wg   = (const float*)d_in[3];
    const float* bg   = (const float*)d_in[4];
    const float* C    = (const float*)d_in[5];
    const float* Wout = (const float*)d_in[6];
    const float* bout = (const float*)d_in[7];
    float*       out  = (float*)d_out;

    const int N = in_sizes[0] / 128;          // 100000
    const int E = in_sizes[1] / 2;            // 1600000
    const int NBUCK = (N + 255) >> 8;         // 391 dst-buckets
    const int NCH = (E + CHUNK - 1) / CHUNK;  // 98 chunks
    const int NBC = (N + 127) / 128;          // k_cent blocks (782)

    char* ws = (char*)d_ws;
    size_t off = 0;
    auto alloc = [&](size_t bytes) { void* p = ws + off; off += (bytes + 511) & ~(size_t)511; return p; };
    float*  dinv   = (float*)alloc((size_t)N * 4);
    int2*   rc     = (int2*) alloc((size_t)N * 8);
    int*    bcnt   = (int*)  alloc((size_t)NBUCK * NCH * 4);
    int*    bofs   = (int*)  alloc((size_t)NBUCK * NCH * 4);
    int*    btot   = (int*)  alloc((size_t)NBUCK * 4);
    int*    bbase  = (int*)  alloc((size_t)(NBUCK + 1) * 4);
    uint32* ebuf   = (uint32*)alloc((size_t)E * 4);
    int*    ssrc   = (int*)  alloc((size_t)(E + 16) * 4);     // +16 pad for agg reads
    float*  hA     = (float*)alloc((size_t)N * 64 * 4);
    uint32* tab    = (uint32*)alloc((size_t)(N + 1) * 64);    // fp8 table + sentinel row
    float*  c2     = (float*)alloc(512);
    float*  partials = (float*)alloc((size_t)NBC * 128 * 4);

    hipMemsetAsync(tab + (size_t)N * 16, 0, 64, stream);      // sentinel row N = 0

    // bucketed CSR build (no global atomics)
    k_bhist<<<NCH, 256, 0, stream>>>(ei + E, bcnt, E, NBUCK, NCH);
    k_bscan1<<<NBUCK, 128, 0, stream>>>(bcnt, bofs, btot, NCH);
    k_bscan2<<<1, 512, 0, stream>>>(btot, bbase, NBUCK);
    k_bscatter<<<NCH, 256, 0, stream>>>(ei, bbase, bofs, ebuf, E, NBUCK, NCH);
    k_bsort<<<NBUCK, 256, 0, stream>>>(ebuf, bbase, ssrc, rc, dinv, N);
    k_c2<<<1, 128, 0, stream>>>(C, c2);

    // embed (MFMA bf16, 256 rows/block)
    k_embed<<<(N + 255) / 256, 256, 0, stream>>>(x, We, hA, N);

    // 3 GCN layers: gemm (hA -> fp8 tab, scaled by dinv), aggregate (tab -> hA fp32)
    for (int l = 0; l < 3; ++l) {
        const float* bias_prev = (l == 0) ? bg : (bg + (l - 1) * 64);
        int act = (l == 0) ? 0 : 1;
        k_gcn<<<(N + 255) / 256, 256, 0, stream>>>(hA, Wg + (size_t)l * 64 * 64,
                                                   bias_prev, act, dinv, tab, N);
        k_agg<<<(N + 3) / 4, 256, 0, stream>>>(rc, ssrc, dinv,
                                               (const uint2*)tab, hA, N);
    }

    // centroid distances + pooling via MFMA (applies relu + b_gcn[2])
    k_cent<<<NBC, 256, 0, stream>>>(hA, bg + 2 * 64, C, c2, partials, N);

    // head: reduce partials + W_out
    k_out<<<1, 1024, 0, stream>>>(partials, NBC, Wout, bout, out, 1.0f / (float)N);
}

// Round 8
// 373.527 us; speedup vs baseline: 1.1836x; 1.0279x over previous
//
#include <hip/hip_runtime.h>
#include <hip/hip_bf16.h>

typedef unsigned int uint32;
typedef float floatx2 __attribute__((ext_vector_type(2)));
typedef __attribute__((ext_vector_type(8))) short bf16x8;
typedef __attribute__((ext_vector_type(4))) float f32x4;

#define CHUNK 16384

// ============ bucketed CSR build (dst>>8 buckets, LDS-atomic sort) ============

__global__ __launch_bounds__(256) void k_bhist(const int* __restrict__ dst,
                                               int* __restrict__ bcnt,
                                               int E, int NBUCK, int NCH) {
    __shared__ int h[512];
    int c = blockIdx.x, tid = threadIdx.x;
    for (int i = tid; i < NBUCK; i += 256) h[i] = 0;
    __syncthreads();
    int base = c * CHUNK;
#pragma unroll
    for (int k = 0; k < CHUNK / 256; ++k) {
        int e = base + k * 256 + tid;
        if (e < E) atomicAdd(&h[dst[e] >> 8], 1);
    }
    __syncthreads();
    for (int i = tid; i < NBUCK; i += 256) bcnt[(size_t)i * NCH + c] = h[i];
}

__global__ __launch_bounds__(128) void k_bscan1(const int* __restrict__ bcnt,
                                                int* __restrict__ bofs,
                                                int* __restrict__ btot, int NCH) {
    __shared__ int tmp[128];
    int b = blockIdx.x, t = threadIdx.x;
    int v = (t < NCH) ? bcnt[(size_t)b * NCH + t] : 0;
    tmp[t] = v;
    __syncthreads();
    for (int off = 1; off < 128; off <<= 1) {
        int u = (t >= off) ? tmp[t - off] : 0;
        __syncthreads();
        tmp[t] += u;
        __syncthreads();
    }
    if (t < NCH) bofs[(size_t)b * NCH + t] = tmp[t] - v;
    if (t == 127) btot[b] = tmp[127];
}

__global__ __launch_bounds__(512) void k_bscan2(const int* __restrict__ btot,
                                                int* __restrict__ bbase, int nb) {
    __shared__ int tmp[512];
    int t = threadIdx.x;
    int v = (t < nb) ? btot[t] : 0;
    tmp[t] = v;
    __syncthreads();
    for (int off = 1; off < 512; off <<= 1) {
        int u = (t >= off) ? tmp[t - off] : 0;
        __syncthreads();
        tmp[t] += u;
        __syncthreads();
    }
    if (t < nb) bbase[t] = tmp[t] - v;
    if (t == nb - 1) bbase[nb] = tmp[t];
}

__global__ __launch_bounds__(256) void k_bscatter(const int* __restrict__ ei,
                                                  const int* __restrict__ bbase,
                                                  const int* __restrict__ bofs,
                                                  uint32* __restrict__ ebuf,
                                                  int E, int NBUCK, int NCH) {
    __shared__ int cur[512];
    int c = blockIdx.x, tid = threadIdx.x;
    for (int i = tid; i < NBUCK; i += 256)
        cur[i] = bbase[i] + bofs[(size_t)i * NCH + c];
    __syncthreads();
    int base = c * CHUNK;
#pragma unroll
    for (int k = 0; k < CHUNK / 256; ++k) {
        int e = base + k * 256 + tid;
        if (e < E) {
            int s = ei[e];
            int d = ei[E + e];
            int p = atomicAdd(&cur[d >> 8], 1);
            ebuf[p] = (uint32)s | ((uint32)(d & 255) << 20);
        }
    }
}

__global__ __launch_bounds__(256) void k_bsort(const uint32* __restrict__ ebuf,
                                               const int* __restrict__ bbase,
                                               int* __restrict__ ssrc,
                                               int2* __restrict__ rc,
                                               float* __restrict__ dinv, int N) {
    __shared__ int h[256];
    __shared__ int sc[256];
    __shared__ int cur[256];
    int b = blockIdx.x, tid = threadIdx.x;
    int beg = bbase[b], end = bbase[b + 1];
    h[tid] = 0;
    __syncthreads();
    for (int j = beg + tid; j < end; j += 256)
        atomicAdd(&h[(ebuf[j] >> 20) & 255], 1);
    __syncthreads();
    int v = h[tid];
    sc[tid] = v;
    __syncthreads();
    for (int off = 1; off < 256; off <<= 1) {
        int u = (tid >= off) ? sc[tid - off] : 0;
        __syncthreads();
        sc[tid] += u;
        __syncthreads();
    }
    int rowbase = beg + sc[tid] - v;
    cur[tid] = rowbase;
    int d = b * 256 + tid;
    if (d < N) {
        rc[d] = make_int2(rowbase, v);
        dinv[d] = rsqrtf((float)(v + 1));   // +1 self loop
    }
    __syncthreads();
    for (int j = beg + tid; j < end; j += 256) {
        uint32 w = ebuf[j];
        int p = atomicAdd(&cur[(w >> 20) & 255], 1);
        ssrc[p] = (int)(w & 0xFFFFFu);
    }
}

// ============ fp32 -> bf16 (RNE) helpers ============

__device__ __forceinline__ short f2bf(float f) {
    __hip_bfloat16 b = __float2bfloat16(f);
    return __builtin_bit_cast(short, b);
}

__device__ __forceinline__ bf16x8 pack_bf16x8(float4 v0, float4 v1) {
    bf16x8 r;
    r[0] = f2bf(v0.x); r[1] = f2bf(v0.y); r[2] = f2bf(v0.z); r[3] = f2bf(v0.w);
    r[4] = f2bf(v1.x); r[5] = f2bf(v1.y); r[6] = f2bf(v1.z); r[7] = f2bf(v1.w);
    return r;
}

// ============ embed GEMM via MFMA: h = x @ We^T ([N,128] @ [128,64]^T) ============
// Layouts (m89-verified): A[lane&15][(lane>>4)*8+j], B[(lane>>4)*8+j][lane&15],
// D[(lane>>4)*4+r][lane&15].

__global__ __launch_bounds__(256) void k_embed(const float* __restrict__ x,
                                               const float* __restrict__ We,
                                               float* __restrict__ h, int N) {
    int lane = threadIdx.x & 63;
    int w = threadIdx.x >> 6;
    int l15 = lane & 15;
    int lg = lane >> 4;                       // 0..3

    bf16x8 B[4][4];
#pragma unroll
    for (int ct = 0; ct < 4; ++ct) {
        const float* wr = We + (size_t)(ct * 16 + l15) * 128 + lg * 8;
#pragma unroll
        for (int ks = 0; ks < 4; ++ks) {
            float4 v0 = *(const float4*)(wr + ks * 32);
            float4 v1 = *(const float4*)(wr + ks * 32 + 4);
            B[ct][ks] = pack_bf16x8(v0, v1);
        }
    }

    int rowbase = blockIdx.x * 256 + w * 64;

    f32x4 acc[4][4];
#pragma unroll
    for (int rt = 0; rt < 4; ++rt)
#pragma unroll
        for (int ct = 0; ct < 4; ++ct)
            acc[rt][ct] = (f32x4){0.f, 0.f, 0.f, 0.f};

#pragma unroll
    for (int ks = 0; ks < 4; ++ks) {
#pragma unroll
        for (int rt = 0; rt < 4; ++rt) {
            int row = rowbase + rt * 16 + l15;
            row = (row < N) ? row : (N - 1);          // clamp; stores predicated
            const float* xr = x + (size_t)row * 128 + ks * 32 + lg * 8;
            float4 v0 = *(const float4*)xr;
            float4 v1 = *(const float4*)(xr + 4);
            bf16x8 a = pack_bf16x8(v0, v1);
#pragma unroll
            for (int ct = 0; ct < 4; ++ct)
                acc[rt][ct] = __builtin_amdgcn_mfma_f32_16x16x32_bf16(
                    a, B[ct][ks], acc[rt][ct], 0, 0, 0);
        }
    }

#pragma unroll
    for (int rt = 0; rt < 4; ++rt) {
        int row0 = rowbase + rt * 16 + lg * 4;
#pragma unroll
        for (int r = 0; r < 4; ++r) {
            int row = row0 + r;
            if (row < N) {
#pragma unroll
                for (int ct = 0; ct < 4; ++ct)
                    h[(size_t)row * 64 + ct * 16 + l15] = acc[rt][ct][r];
            }
        }
    }
}

// ============ GCN layer GEMM via MFMA (swapped operands, split fp8 tables) ====
// D = Wg . act(h)^T. Output split by feature half into tab0 (features 0..31)
// and tab1 (features 32..63): 3.2 MB each -> each fits a 4 MB per-XCD L2 so the
// aggregation pass can keep its gather table L2-resident.

__global__ __launch_bounds__(256) void k_gcn(const float* __restrict__ hin,
                                             const float* __restrict__ Wg,
                                             const float* __restrict__ bias_prev, int act,
                                             const float* __restrict__ dinv,
                                             uint32* __restrict__ tab0,
                                             uint32* __restrict__ tab1, int N) {
    int lane = threadIdx.x & 63;
    int w = threadIdx.x >> 6;
    int l15 = lane & 15, lg = lane >> 4;

    bf16x8 A[4][2];
#pragma unroll
    for (int rt = 0; rt < 4; ++rt) {
        const float* wr = Wg + (size_t)(rt * 16 + l15) * 64 + lg * 8;
#pragma unroll
        for (int ks = 0; ks < 2; ++ks) {
            float4 v0 = *(const float4*)(wr + ks * 32);
            float4 v1 = *(const float4*)(wr + ks * 32 + 4);
            A[rt][ks] = pack_bf16x8(v0, v1);
        }
    }

    float bv[16];
#pragma unroll
    for (int ks = 0; ks < 2; ++ks) {
        float4 b0 = *(const float4*)(bias_prev + ks * 32 + lg * 8);
        float4 b1 = *(const float4*)(bias_prev + ks * 32 + lg * 8 + 4);
        bv[ks * 8 + 0] = b0.x; bv[ks * 8 + 1] = b0.y;
        bv[ks * 8 + 2] = b0.z; bv[ks * 8 + 3] = b0.w;
        bv[ks * 8 + 4] = b1.x; bv[ks * 8 + 5] = b1.y;
        bv[ks * 8 + 6] = b1.z; bv[ks * 8 + 7] = b1.w;
    }

    int nodebase = blockIdx.x * 256 + w * 64;   // wave: 64 nodes = 4 tiles of 16

#pragma unroll
    for (int nt = 0; nt < 4; ++nt) {
        int node = nodebase + nt * 16 + l15;
        int nodec = (node < N) ? node : (N - 1);
        const float* hr = hin + ((size_t)nodec << 6) + lg * 8;

        bf16x8 Bf[2];
#pragma unroll
        for (int ks = 0; ks < 2; ++ks) {
            float4 v0 = *(const float4*)(hr + ks * 32);
            float4 v1 = *(const float4*)(hr + ks * 32 + 4);
            if (act) {
                v0.x = fmaxf(v0.x + bv[ks * 8 + 0], 0.f);
                v0.y = fmaxf(v0.y + bv[ks * 8 + 1], 0.f);
                v0.z = fmaxf(v0.z + bv[ks * 8 + 2], 0.f);
                v0.w = fmaxf(v0.w + bv[ks * 8 + 3], 0.f);
                v1.x = fmaxf(v1.x + bv[ks * 8 + 4], 0.f);
                v1.y = fmaxf(v1.y + bv[ks * 8 + 5], 0.f);
                v1.z = fmaxf(v1.z + bv[ks * 8 + 6], 0.f);
                v1.w = fmaxf(v1.w + bv[ks * 8 + 7], 0.f);
            }
            Bf[ks] = pack_bf16x8(v0, v1);
        }

        f32x4 acc[4];
#pragma unroll
        for (int rt = 0; rt < 4; ++rt) acc[rt] = (f32x4){0.f, 0.f, 0.f, 0.f};
#pragma unroll
        for (int ks = 0; ks < 2; ++ks)
#pragma unroll
            for (int rt = 0; rt < 4; ++rt)
                acc[rt] = __builtin_amdgcn_mfma_f32_16x16x32_bf16(
                    A[rt][ks], Bf[ks], acc[rt], 0, 0, 0);

        float s = dinv[nodec];
        if (node < N) {
#pragma unroll
            for (int rt = 0; rt < 4; ++rt) {
                int u = 0;
                u = __builtin_amdgcn_cvt_pk_fp8_f32(acc[rt][0] * s, acc[rt][1] * s, u, false);
                u = __builtin_amdgcn_cvt_pk_fp8_f32(acc[rt][2] * s, acc[rt][3] * s, u, true);
                uint32* tp = (rt < 2) ? tab0 : tab1;
                tp[(size_t)node * 8 + (rt & 1) * 4 + lg] = u;
            }
        }
    }
}

// ============ fp8 CSR aggregate: half-feature pass, 16 dsts/wave =============
// Each 4-lane group owns ONE dst and iterates its edges serially (wave-uniform
// maxdeg loop, sentinel row N for finished groups). No cross-slot reduction.
// Gather = 16 rows x 32 B per instruction from a 3.2 MB L2-resident table.
// Output written with nontemporal stores so the write stream doesn't evict it.

__global__ __launch_bounds__(256) void k_agg(const int2* __restrict__ rc,
                                             const int* __restrict__ ssrc,
                                             const float* __restrict__ dinv,
                                             const uint2* __restrict__ tabh,
                                             float* __restrict__ outh,
                                             int N, int E) {
    int lane = threadIdx.x & 63;
    int wid = threadIdx.x >> 6;
    int q = lane & 3;
    int g = lane >> 2;                          // group 0..15
    int dbase = (blockIdx.x * 4 + wid) * 16;
    if (dbase >= N) return;

    int2 r = rc[min(dbase + (lane & 15), N - 1)];
    int beg = __shfl(r.x, g);
    int deg = __shfl(r.y, g);
    int dg = dbase + g;
    if (dg >= N) deg = 0;

    floatx2 a01 = {0.f, 0.f}, a23 = {0.f, 0.f}, a45 = {0.f, 0.f}, a67 = {0.f, 0.f};
    auto accum = [&](uint2 v) {
        a01 += __builtin_amdgcn_cvt_pk_f32_fp8((int)v.x, false);
        a23 += __builtin_amdgcn_cvt_pk_f32_fp8((int)v.x, true);
        a45 += __builtin_amdgcn_cvt_pk_f32_fp8((int)v.y, false);
        a67 += __builtin_amdgcn_cvt_pk_f32_fp8((int)v.y, true);
    };

    // self loop (each group reads its own dst row once)
    {
        int t = (dg < N) ? dg : N;
        accum(tabh[(size_t)t * 4 + q]);
    }

    int m = deg;
    m = max(m, __shfl_xor(m, 4));
    m = max(m, __shfl_xor(m, 8));
    m = max(m, __shfl_xor(m, 16));
    m = max(m, __shfl_xor(m, 32));
    int maxd = __builtin_amdgcn_readfirstlane(m);

    int ev = 0;
    for (int j = 0; j < maxd; ++j) {
        if ((j & 3) == 0) {
            int idx = beg + j + q;              // 4 edge indices per group
            ev = ssrc[idx < E ? idx : 0];       // clamp; masked by sentinel below
        }
        int t = __shfl(ev, (lane & 60) | (j & 3));
        t = (j < deg) ? t : N;                  // sentinel row N = zeros
        accum(tabh[(size_t)t * 4 + q]);
    }

    if (dg < N) {
        float dd = dinv[dg];
        float* orow = outh + (size_t)dg * 64 + q * 8;
        f32x4 o0 = {dd * a01.x, dd * a01.y, dd * a23.x, dd * a23.y};
        f32x4 o1 = {dd * a45.x, dd * a45.y, dd * a67.x, dd * a67.y};
        __builtin_nontemporal_store(o0, (f32x4*)orow);
        __builtin_nontemporal_store(o1, (f32x4*)(orow + 4));
    }
}

// ============ centroid squared norms ============

__global__ void k_c2(const float* __restrict__ C, float* __restrict__ c2) {
    int k = threadIdx.x;
    if (k < 100) {
        float s = 0.f;
        for (int d = 0; d < 64; ++d) { float v = C[k * 64 + d]; s = fmaf(v, v, s); }
        c2[k] = s;
    }
}

// ============ centroid distances + pooling via MFMA ============
// 128 rows/block (4 waves x 32 rows) -> 782 blocks for latency hiding.

__global__ __launch_bounds__(256) void k_cent(const float* __restrict__ hin,
                                              const float* __restrict__ b2,
                                              const float* __restrict__ C,
                                              const float* __restrict__ c2g,
                                              float* __restrict__ partials, int N) {
    __shared__ float pool4[4][112];
    __shared__ float h2_s[128];
    int tid = threadIdx.x;
    int lane = tid & 63, w = tid >> 6;
    int l15 = lane & 15, lg = lane >> 4;      // lg = 0..3

    bf16x8 B[7][2];
#pragma unroll
    for (int ct = 0; ct < 7; ++ct) {
        int col = ct * 16 + l15;
#pragma unroll
        for (int ks = 0; ks < 2; ++ks) {
            float4 v0 = make_float4(0.f, 0.f, 0.f, 0.f);
            float4 v1 = make_float4(0.f, 0.f, 0.f, 0.f);
            if (col < 100) {
                const float* cr = C + (size_t)col * 64 + ks * 32 + lg * 8;
                v0 = *(const float4*)cr;
                v1 = *(const float4*)(cr + 4);
            }
            B[ct][ks] = pack_bf16x8(v0, v1);
        }
    }

    float bv[16];
#pragma unroll
    for (int ks = 0; ks < 2; ++ks) {
        float4 b0 = *(const float4*)(b2 + ks * 32 + lg * 8);
        float4 b1 = *(const float4*)(b2 + ks * 32 + lg * 8 + 4);
        bv[ks * 8 + 0] = b0.x; bv[ks * 8 + 1] = b0.y;
        bv[ks * 8 + 2] = b0.z; bv[ks * 8 + 3] = b0.w;
        bv[ks * 8 + 4] = b1.x; bv[ks * 8 + 5] = b1.y;
        bv[ks * 8 + 6] = b1.z; bv[ks * 8 + 7] = b1.w;
    }

    int rowbase = blockIdx.x * 128 + w * 32;

    f32x4 acc[2][7];
#pragma unroll
    for (int rt = 0; rt < 2; ++rt)
#pragma unroll
        for (int ct = 0; ct < 7; ++ct)
            acc[rt][ct] = (f32x4){0.f, 0.f, 0.f, 0.f};

#pragma unroll
    for (int rt = 0; rt < 2; ++rt) {
        int row = rowbase + rt * 16 + l15;
        int rowc = (row < N) ? row : (N - 1);     // clamp; excluded from pooling
        const float* hr = hin + ((size_t)rowc << 6);
        float hp[16];
        float h2p = 0.f;
#pragma unroll
        for (int ks = 0; ks < 2; ++ks) {
            float4 v0 = *(const float4*)(hr + ks * 32 + lg * 8);
            float4 v1 = *(const float4*)(hr + ks * 32 + lg * 8 + 4);
            float t0 = fmaxf(v0.x + bv[ks * 8 + 0], 0.f);
            float t1 = fmaxf(v0.y + bv[ks * 8 + 1], 0.f);
            float t2 = fmaxf(v0.z + bv[ks * 8 + 2], 0.f);
            float t3 = fmaxf(v0.w + bv[ks * 8 + 3], 0.f);
            float t4 = fmaxf(v1.x + bv[ks * 8 + 4], 0.f);
            float t5 = fmaxf(v1.y + bv[ks * 8 + 5], 0.f);
            float t6 = fmaxf(v1.z + bv[ks * 8 + 6], 0.f);
            float t7 = fmaxf(v1.w + bv[ks * 8 + 7], 0.f);
            hp[ks * 8 + 0] = t0; hp[ks * 8 + 1] = t1;
            hp[ks * 8 + 2] = t2; hp[ks * 8 + 3] = t3;
            hp[ks * 8 + 4] = t4; hp[ks * 8 + 5] = t5;
            hp[ks * 8 + 6] = t6; hp[ks * 8 + 7] = t7;
            h2p = fmaf(t0, t0, h2p); h2p = fmaf(t1, t1, h2p);
            h2p = fmaf(t2, t2, h2p); h2p = fmaf(t3, t3, h2p);
            h2p = fmaf(t4, t4, h2p); h2p = fmaf(t5, t5, h2p);
            h2p = fmaf(t6, t6, h2p); h2p = fmaf(t7, t7, h2p);
        }
        h2p += __shfl_xor(h2p, 16);
        h2p += __shfl_xor(h2p, 32);
        if (lg == 0) h2_s[w * 32 + rt * 16 + l15] = h2p;

#pragma unroll
        for (int ks = 0; ks < 2; ++ks) {
            bf16x8 a;
#pragma unroll
            for (int j = 0; j < 8; ++j) a[j] = f2bf(hp[ks * 8 + j]);
#pragma unroll
            for (int ct = 0; ct < 7; ++ct)
                acc[rt][ct] = __builtin_amdgcn_mfma_f32_16x16x32_bf16(
                    a, B[ct][ks], acc[rt][ct], 0, 0, 0);
        }
    }

    float S[7] = {0.f, 0.f, 0.f, 0.f, 0.f, 0.f, 0.f};
#pragma unroll
    for (int rt = 0; rt < 2; ++rt) {
#pragma unroll
        for (int r = 0; r < 4; ++r) {
            int row = rowbase + rt * 16 + lg * 4 + r;
            float h2v = h2_s[w * 32 + rt * 16 + lg * 4 + r];
            bool rv = row < N;
#pragma unroll
            for (int ct = 0; ct < 7; ++ct) {
                int col = ct * 16 + l15;
                float c2v = (col < 100) ? c2g[col] : 0.f;
                float G = acc[rt][ct][r];
                float d2 = fmaxf(h2v + c2v - 2.f * G, 0.f);
                float xx = d2 + 1e-12f;
                float dist = xx * __frsqrt_rn(xx);       // sqrt via rsq, 1 trans op
                S[ct] += (rv && col < 100) ? dist : 0.f;
            }
        }
    }
#pragma unroll
    for (int ct = 0; ct < 7; ++ct) {
        float s = S[ct];
        s += __shfl_xor(s, 16);
        s += __shfl_xor(s, 32);
        if (lg == 0) pool4[w][ct * 16 + l15] = s;   // S[ct]=0 for padded cols
    }
    __syncthreads();
    if (tid < 112) {
        float s = pool4[0][tid] + pool4[1][tid] + pool4[2][tid] + pool4[3][tid];
        partials[(size_t)blockIdx.x * 128 + tid] = s;
    }
}

// ============ output head: reduce partials + apply W_out ============
// 8 groups x 128; 8-wide unrolled strided sum (independent accumulators for MLP).

__global__ __launch_bounds__(1024) void k_out(const float* __restrict__ partials, int nb,
                                              const float* __restrict__ Wout,
                                              const float* __restrict__ bout,
                                              float* __restrict__ out, float invN) {
    __shared__ float ps[8][112];
    int t = threadIdx.x & 127, g = threadIdx.x >> 7;
    if (t < 112) {
        float s0 = 0.f, s1 = 0.f, s2 = 0.f, s3 = 0.f;
        float s4 = 0.f, s5 = 0.f, s6 = 0.f, s7 = 0.f;
        int b = g;
        for (; b + 56 < nb; b += 64) {
            s0 += partials[(size_t)(b     ) * 128 + t];
            s1 += partials[(size_t)(b +  8) * 128 + t];
            s2 += partials[(size_t)(b + 16) * 128 + t];
            s3 += partials[(size_t)(b + 24) * 128 + t];
            s4 += partials[(size_t)(b + 32) * 128 + t];
            s5 += partials[(size_t)(b + 40) * 128 + t];
            s6 += partials[(size_t)(b + 48) * 128 + t];
            s7 += partials[(size_t)(b + 56) * 128 + t];
        }
        for (; b < nb; b += 8) s0 += partials[(size_t)b * 128 + t];
        ps[g][t] = ((s0 + s1) + (s2 + s3)) + ((s4 + s5) + (s6 + s7));
    }
    __syncthreads();
    if (threadIdx.x < 10) {
        int tt = threadIdx.x;
        float s = 0.f;
        for (int k = 0; k < 100; ++k) {
            float p = ps[0][k] + ps[1][k] + ps[2][k] + ps[3][k]
                    + ps[4][k] + ps[5][k] + ps[6][k] + ps[7][k];
            s = fmaf(p, Wout[tt * 100 + k], s);
        }
        out[tt] = s * invN + bout[tt];
    }
}

// ============ launcher ============

extern "C" void kernel_launch(void* const* d_in, const int* in_sizes, int n_in,
                              void* d_out, int out_size, void* d_ws, size_t ws_size,
                              hipStream_t stream) {
    const float* x    = (const float*)d_in[0];
    const int*   ei   = (const int*)d_in[1];
    const float* We   = (const float*)d_in[2];
    const float* Wg   = (const float*)d_in[3];
    const float* bg   = (const float*)d_in[4];
    const float* C    = (const float*)d_in[5];
    const float* Wout = (const float*)d_in[6];
    const float* bout = (const float*)d_in[7];
    float*       out  = (float*)d_out;

    const int N = in_sizes[0] / 128;          // 100000
    const int E = in_sizes[1] / 2;            // 1600000
    const int NBUCK = (N + 255) >> 8;         // 391 dst-buckets
    const int NCH = (E + CHUNK - 1) / CHUNK;  // 98 chunks
    const int NBC = (N + 127) / 128;          // k_cent blocks (782)
    const int NBA = (N + 63) / 64;            // k_agg blocks (1563): 64 dsts/block

    char* ws = (char*)d_ws;
    size_t off = 0;
    auto alloc = [&](size_t bytes) { void* p = ws + off; off += (bytes + 511) & ~(size_t)511; return p; };
    float*  dinv   = (float*)alloc((size_t)N * 4);
    int2*   rc     = (int2*) alloc((size_t)N * 8);
    int*    bcnt   = (int*)  alloc((size_t)NBUCK * NCH * 4);
    int*    bofs   = (int*)  alloc((size_t)NBUCK * NCH * 4);
    int*    btot   = (int*)  alloc((size_t)NBUCK * 4);
    int*    bbase  = (int*)  alloc((size_t)(NBUCK + 1) * 4);
    uint32* ebuf   = (uint32*)alloc((size_t)E * 4);
    int*    ssrc   = (int*)  alloc((size_t)(E + 64) * 4);     // pad for agg reads
    float*  hA     = (float*)alloc((size_t)N * 64 * 4);
    uint32* tab0   = (uint32*)alloc((size_t)(N + 1) * 32);    // fp8 feats 0..31 + sentinel
    uint32* tab1   = (uint32*)alloc((size_t)(N + 1) * 32);    // fp8 feats 32..63 + sentinel
    float*  c2     = (float*)alloc(512);
    float*  partials = (float*)alloc((size_t)NBC * 128 * 4);

    hipMemsetAsync(tab0 + (size_t)N * 8, 0, 32, stream);      // sentinel rows = 0
    hipMemsetAsync(tab1 + (size_t)N * 8, 0, 32, stream);

    // bucketed CSR build (no global atomics)
    k_bhist<<<NCH, 256, 0, stream>>>(ei + E, bcnt, E, NBUCK, NCH);
    k_bscan1<<<NBUCK, 128, 0, stream>>>(bcnt, bofs, btot, NCH);
    k_bscan2<<<1, 512, 0, stream>>>(btot, bbase, NBUCK);
    k_bscatter<<<NCH, 256, 0, stream>>>(ei, bbase, bofs, ebuf, E, NBUCK, NCH);
    k_bsort<<<NBUCK, 256, 0, stream>>>(ebuf, bbase, ssrc, rc, dinv, N);
    k_c2<<<1, 128, 0, stream>>>(C, c2);

    // embed (MFMA bf16, 256 rows/block)
    k_embed<<<(N + 255) / 256, 256, 0, stream>>>(x, We, hA, N);

    // 3 GCN layers: gemm (hA -> fp8 tab halves), aggregate per half (L2-resident)
    for (int l = 0; l < 3; ++l) {
        const float* bias_prev = (l == 0) ? bg : (bg + (l - 1) * 64);
        int act = (l == 0) ? 0 : 1;
        k_gcn<<<(N + 255) / 256, 256, 0, stream>>>(hA, Wg + (size_t)l * 64 * 64,
                                                   bias_prev, act, dinv, tab0, tab1, N);
        k_agg<<<NBA, 256, 0, stream>>>(rc, ssrc, dinv, (const uint2*)tab0, hA, N, E);
        k_agg<<<NBA, 256, 0, stream>>>(rc, ssrc, dinv, (const uint2*)tab1, hA + 32, N, E);
    }

    // centroid distances + pooling via MFMA (applies relu + b_gcn[2])
    k_cent<<<NBC, 256, 0, stream>>>(hA, bg + 2 * 64, C, c2, partials, N);

    // head: reduce partials + W_out
    k_out<<<1, 1024, 0, stream>>>(partials, NBC, Wout, bout, out, 1.0f / (float)N);
}

// Round 9
// 357.384 us; speedup vs baseline: 1.2371x; 1.0452x over previous
//
#include <hip/hip_runtime.h>
#include <hip/hip_bf16.h>

typedef unsigned int uint32;
typedef float floatx2 __attribute__((ext_vector_type(2)));
typedef __attribute__((ext_vector_type(8))) short bf16x8;
typedef __attribute__((ext_vector_type(4))) float f32x4;

#define CHUNK 16384

// ============ bucketed CSR build (dst>>8 buckets, LDS-atomic sort) ============

__global__ __launch_bounds__(256) void k_bhist(const int* __restrict__ dst,
                                               int* __restrict__ bcnt,
                                               int E, int NBUCK, int NCH) {
    __shared__ int h[512];
    int c = blockIdx.x, tid = threadIdx.x;
    for (int i = tid; i < NBUCK; i += 256) h[i] = 0;
    __syncthreads();
    int base = c * CHUNK;
#pragma unroll
    for (int k = 0; k < CHUNK / 256; ++k) {
        int e = base + k * 256 + tid;
        if (e < E) atomicAdd(&h[dst[e] >> 8], 1);
    }
    __syncthreads();
    for (int i = tid; i < NBUCK; i += 256) bcnt[(size_t)i * NCH + c] = h[i];
}

__global__ __launch_bounds__(128) void k_bscan1(const int* __restrict__ bcnt,
                                                int* __restrict__ bofs,
                                                int* __restrict__ btot, int NCH) {
    __shared__ int tmp[128];
    int b = blockIdx.x, t = threadIdx.x;
    int v = (t < NCH) ? bcnt[(size_t)b * NCH + t] : 0;
    tmp[t] = v;
    __syncthreads();
    for (int off = 1; off < 128; off <<= 1) {
        int u = (t >= off) ? tmp[t - off] : 0;
        __syncthreads();
        tmp[t] += u;
        __syncthreads();
    }
    if (t < NCH) bofs[(size_t)b * NCH + t] = tmp[t] - v;
    if (t == 127) btot[b] = tmp[127];
}

__global__ __launch_bounds__(512) void k_bscan2(const int* __restrict__ btot,
                                                int* __restrict__ bbase, int nb) {
    __shared__ int tmp[512];
    int t = threadIdx.x;
    int v = (t < nb) ? btot[t] : 0;
    tmp[t] = v;
    __syncthreads();
    for (int off = 1; off < 512; off <<= 1) {
        int u = (t >= off) ? tmp[t - off] : 0;
        __syncthreads();
        tmp[t] += u;
        __syncthreads();
    }
    if (t < nb) bbase[t] = tmp[t] - v;
    if (t == nb - 1) bbase[nb] = tmp[t];
}

__global__ __launch_bounds__(256) void k_bscatter(const int* __restrict__ ei,
                                                  const int* __restrict__ bbase,
                                                  const int* __restrict__ bofs,
                                                  uint32* __restrict__ ebuf,
                                                  int E, int NBUCK, int NCH) {
    __shared__ int cur[512];
    int c = blockIdx.x, tid = threadIdx.x;
    for (int i = tid; i < NBUCK; i += 256)
        cur[i] = bbase[i] + bofs[(size_t)i * NCH + c];
    __syncthreads();
    int base = c * CHUNK;
#pragma unroll
    for (int k = 0; k < CHUNK / 256; ++k) {
        int e = base + k * 256 + tid;
        if (e < E) {
            int s = ei[e];
            int d = ei[E + e];
            int p = atomicAdd(&cur[d >> 8], 1);
            ebuf[p] = (uint32)s | ((uint32)(d & 255) << 20);
        }
    }
}

__global__ __launch_bounds__(256) void k_bsort(const uint32* __restrict__ ebuf,
                                               const int* __restrict__ bbase,
                                               int* __restrict__ ssrc,
                                               int2* __restrict__ rc,
                                               float* __restrict__ dinv, int N) {
    __shared__ int h[256];
    __shared__ int sc[256];
    __shared__ int cur[256];
    int b = blockIdx.x, tid = threadIdx.x;
    int beg = bbase[b], end = bbase[b + 1];
    h[tid] = 0;
    __syncthreads();
    for (int j = beg + tid; j < end; j += 256)
        atomicAdd(&h[(ebuf[j] >> 20) & 255], 1);
    __syncthreads();
    int v = h[tid];
    sc[tid] = v;
    __syncthreads();
    for (int off = 1; off < 256; off <<= 1) {
        int u = (tid >= off) ? sc[tid - off] : 0;
        __syncthreads();
        sc[tid] += u;
        __syncthreads();
    }
    int rowbase = beg + sc[tid] - v;
    cur[tid] = rowbase;
    int d = b * 256 + tid;
    if (d < N) {
        rc[d] = make_int2(rowbase, v);
        dinv[d] = rsqrtf((float)(v + 1));   // +1 self loop
    }
    __syncthreads();
    for (int j = beg + tid; j < end; j += 256) {
        uint32 w = ebuf[j];
        int p = atomicAdd(&cur[(w >> 20) & 255], 1);
        ssrc[p] = (int)(w & 0xFFFFFu);
    }
}

// ============ fp32 -> bf16 (RNE) helpers ============

__device__ __forceinline__ short f2bf(float f) {
    __hip_bfloat16 b = __float2bfloat16(f);
    return __builtin_bit_cast(short, b);
}

__device__ __forceinline__ bf16x8 pack_bf16x8(float4 v0, float4 v1) {
    bf16x8 r;
    r[0] = f2bf(v0.x); r[1] = f2bf(v0.y); r[2] = f2bf(v0.z); r[3] = f2bf(v0.w);
    r[4] = f2bf(v1.x); r[5] = f2bf(v1.y); r[6] = f2bf(v1.z); r[7] = f2bf(v1.w);
    return r;
}

// ============ embed GEMM via MFMA: h = x @ We^T ([N,128] @ [128,64]^T) ============
// Layouts (m89-verified): A[lane&15][(lane>>4)*8+j], B[(lane>>4)*8+j][lane&15],
// D[(lane>>4)*4+r][lane&15].

__global__ __launch_bounds__(256) void k_embed(const float* __restrict__ x,
                                               const float* __restrict__ We,
                                               float* __restrict__ h, int N) {
    int lane = threadIdx.x & 63;
    int w = threadIdx.x >> 6;
    int l15 = lane & 15;
    int lg = lane >> 4;                       // 0..3

    bf16x8 B[4][4];
#pragma unroll
    for (int ct = 0; ct < 4; ++ct) {
        const float* wr = We + (size_t)(ct * 16 + l15) * 128 + lg * 8;
#pragma unroll
        for (int ks = 0; ks < 4; ++ks) {
            float4 v0 = *(const float4*)(wr + ks * 32);
            float4 v1 = *(const float4*)(wr + ks * 32 + 4);
            B[ct][ks] = pack_bf16x8(v0, v1);
        }
    }

    int rowbase = blockIdx.x * 256 + w * 64;

    f32x4 acc[4][4];
#pragma unroll
    for (int rt = 0; rt < 4; ++rt)
#pragma unroll
        for (int ct = 0; ct < 4; ++ct)
            acc[rt][ct] = (f32x4){0.f, 0.f, 0.f, 0.f};

#pragma unroll
    for (int ks = 0; ks < 4; ++ks) {
#pragma unroll
        for (int rt = 0; rt < 4; ++rt) {
            int row = rowbase + rt * 16 + l15;
            row = (row < N) ? row : (N - 1);          // clamp; stores predicated
            const float* xr = x + (size_t)row * 128 + ks * 32 + lg * 8;
            float4 v0 = *(const float4*)xr;
            float4 v1 = *(const float4*)(xr + 4);
            bf16x8 a = pack_bf16x8(v0, v1);
#pragma unroll
            for (int ct = 0; ct < 4; ++ct)
                acc[rt][ct] = __builtin_amdgcn_mfma_f32_16x16x32_bf16(
                    a, B[ct][ks], acc[rt][ct], 0, 0, 0);
        }
    }

#pragma unroll
    for (int rt = 0; rt < 4; ++rt) {
        int row0 = rowbase + rt * 16 + lg * 4;
#pragma unroll
        for (int r = 0; r < 4; ++r) {
            int row = row0 + r;
            if (row < N) {
#pragma unroll
                for (int ct = 0; ct < 4; ++ct)
                    h[(size_t)row * 64 + ct * 16 + l15] = acc[rt][ct][r];
            }
        }
    }
}

// ============ GCN layer GEMM via MFMA (swapped operands, split fp8 tables) ====
// D = Wg . act(h)^T. Output split by feature half into tab0 (features 0..31)
// and tab1 (features 32..63): 3.2 MB each -> each fits a 4 MB per-XCD L2 so the
// aggregation pass can keep its gather table L2-resident.

__global__ __launch_bounds__(256) void k_gcn(const float* __restrict__ hin,
                                             const float* __restrict__ Wg,
                                             const float* __restrict__ bias_prev, int act,
                                             const float* __restrict__ dinv,
                                             uint32* __restrict__ tab0,
                                             uint32* __restrict__ tab1, int N) {
    int lane = threadIdx.x & 63;
    int w = threadIdx.x >> 6;
    int l15 = lane & 15, lg = lane >> 4;

    bf16x8 A[4][2];
#pragma unroll
    for (int rt = 0; rt < 4; ++rt) {
        const float* wr = Wg + (size_t)(rt * 16 + l15) * 64 + lg * 8;
#pragma unroll
        for (int ks = 0; ks < 2; ++ks) {
            float4 v0 = *(const float4*)(wr + ks * 32);
            float4 v1 = *(const float4*)(wr + ks * 32 + 4);
            A[rt][ks] = pack_bf16x8(v0, v1);
        }
    }

    float bv[16];
#pragma unroll
    for (int ks = 0; ks < 2; ++ks) {
        float4 b0 = *(const float4*)(bias_prev + ks * 32 + lg * 8);
        float4 b1 = *(const float4*)(bias_prev + ks * 32 + lg * 8 + 4);
        bv[ks * 8 + 0] = b0.x; bv[ks * 8 + 1] = b0.y;
        bv[ks * 8 + 2] = b0.z; bv[ks * 8 + 3] = b0.w;
        bv[ks * 8 + 4] = b1.x; bv[ks * 8 + 5] = b1.y;
        bv[ks * 8 + 6] = b1.z; bv[ks * 8 + 7] = b1.w;
    }

    int nodebase = blockIdx.x * 256 + w * 64;   // wave: 64 nodes = 4 tiles of 16

#pragma unroll
    for (int nt = 0; nt < 4; ++nt) {
        int node = nodebase + nt * 16 + l15;
        int nodec = (node < N) ? node : (N - 1);
        const float* hr = hin + ((size_t)nodec << 6) + lg * 8;

        bf16x8 Bf[2];
#pragma unroll
        for (int ks = 0; ks < 2; ++ks) {
            float4 v0 = *(const float4*)(hr + ks * 32);
            float4 v1 = *(const float4*)(hr + ks * 32 + 4);
            if (act) {
                v0.x = fmaxf(v0.x + bv[ks * 8 + 0], 0.f);
                v0.y = fmaxf(v0.y + bv[ks * 8 + 1], 0.f);
                v0.z = fmaxf(v0.z + bv[ks * 8 + 2], 0.f);
                v0.w = fmaxf(v0.w + bv[ks * 8 + 3], 0.f);
                v1.x = fmaxf(v1.x + bv[ks * 8 + 4], 0.f);
                v1.y = fmaxf(v1.y + bv[ks * 8 + 5], 0.f);
                v1.z = fmaxf(v1.z + bv[ks * 8 + 6], 0.f);
                v1.w = fmaxf(v1.w + bv[ks * 8 + 7], 0.f);
            }
            Bf[ks] = pack_bf16x8(v0, v1);
        }

        f32x4 acc[4];
#pragma unroll
        for (int rt = 0; rt < 4; ++rt) acc[rt] = (f32x4){0.f, 0.f, 0.f, 0.f};
#pragma unroll
        for (int ks = 0; ks < 2; ++ks)
#pragma unroll
            for (int rt = 0; rt < 4; ++rt)
                acc[rt] = __builtin_amdgcn_mfma_f32_16x16x32_bf16(
                    A[rt][ks], Bf[ks], acc[rt], 0, 0, 0);

        float s = dinv[nodec];
        if (node < N) {
#pragma unroll
            for (int rt = 0; rt < 4; ++rt) {
                int u = 0;
                u = __builtin_amdgcn_cvt_pk_fp8_f32(acc[rt][0] * s, acc[rt][1] * s, u, false);
                u = __builtin_amdgcn_cvt_pk_fp8_f32(acc[rt][2] * s, acc[rt][3] * s, u, true);
                uint32* tp = (rt < 2) ? tab0 : tab1;
                tp[(size_t)node * 8 + (rt & 1) * 4 + lg] = u;
            }
        }
    }
}

// ============ fp8 CSR aggregate: half-feature pass, 16 dsts/wave =============
// Each 4-lane group owns ONE dst. Inner loop processes 8 edges per iteration:
// two coalesced ssrc quad-loads + 8 shfl + 8 INDEPENDENT table gathers issued
// back-to-back (R8 post-mortem: the rolled 1-gather/iter loop was a latency
// chain -- ~27 round trips/wave; this cuts it to ~4).

__global__ __launch_bounds__(256) void k_agg(const int2* __restrict__ rc,
                                             const int* __restrict__ ssrc,
                                             const float* __restrict__ dinv,
                                             const uint2* __restrict__ tabh,
                                             float* __restrict__ outh,
                                             int N, int E) {
    int lane = threadIdx.x & 63;
    int wid = threadIdx.x >> 6;
    int q = lane & 3;
    int g = lane >> 2;                          // group 0..15
    int dbase = (blockIdx.x * 4 + wid) * 16;
    if (dbase >= N) return;

    int2 r = rc[min(dbase + (lane & 15), N - 1)];
    int beg = __shfl(r.x, g);
    int deg = __shfl(r.y, g);
    int dg = dbase + g;
    if (dg >= N) deg = 0;

    floatx2 a01 = {0.f, 0.f}, a23 = {0.f, 0.f}, a45 = {0.f, 0.f}, a67 = {0.f, 0.f};
    auto accum = [&](uint2 v) {
        a01 += __builtin_amdgcn_cvt_pk_f32_fp8((int)v.x, false);
        a23 += __builtin_amdgcn_cvt_pk_f32_fp8((int)v.x, true);
        a45 += __builtin_amdgcn_cvt_pk_f32_fp8((int)v.y, false);
        a67 += __builtin_amdgcn_cvt_pk_f32_fp8((int)v.y, true);
    };

    // self loop (each group reads its own dst row once)
    accum(tabh[(size_t)((dg < N) ? dg : N) * 4 + q]);

    int m = deg;
    m = max(m, __shfl_xor(m, 4));
    m = max(m, __shfl_xor(m, 8));
    m = max(m, __shfl_xor(m, 16));
    m = max(m, __shfl_xor(m, 32));
    int maxd = __builtin_amdgcn_readfirstlane(m);

    int base4 = lane & 60;                      // group base lane
    for (int j = 0; j < maxd; j += 8) {
        int i0 = beg + j + q;                   // edges j..j+3 of this group
        int i1 = i0 + 4;                        // edges j+4..j+7
        int ev0 = ssrc[i0 < E ? i0 : 0];        // ssrc has tail pad; masked below
        int ev1 = ssrc[i1 < E ? i1 : 0];
        int t0 = __shfl(ev0, base4 | 0);
        int t1 = __shfl(ev0, base4 | 1);
        int t2 = __shfl(ev0, base4 | 2);
        int t3 = __shfl(ev0, base4 | 3);
        int t4 = __shfl(ev1, base4 | 0);
        int t5 = __shfl(ev1, base4 | 1);
        int t6 = __shfl(ev1, base4 | 2);
        int t7 = __shfl(ev1, base4 | 3);
        t0 = (j + 0 < deg) ? t0 : N;            // sentinel row N = zeros
        t1 = (j + 1 < deg) ? t1 : N;
        t2 = (j + 2 < deg) ? t2 : N;
        t3 = (j + 3 < deg) ? t3 : N;
        t4 = (j + 4 < deg) ? t4 : N;
        t5 = (j + 5 < deg) ? t5 : N;
        t6 = (j + 6 < deg) ? t6 : N;
        t7 = (j + 7 < deg) ? t7 : N;
        uint2 v0 = tabh[(size_t)t0 * 4 + q];    // 8 independent gathers in flight
        uint2 v1 = tabh[(size_t)t1 * 4 + q];
        uint2 v2 = tabh[(size_t)t2 * 4 + q];
        uint2 v3 = tabh[(size_t)t3 * 4 + q];
        uint2 v4 = tabh[(size_t)t4 * 4 + q];
        uint2 v5 = tabh[(size_t)t5 * 4 + q];
        uint2 v6 = tabh[(size_t)t6 * 4 + q];
        uint2 v7 = tabh[(size_t)t7 * 4 + q];
        accum(v0); accum(v1); accum(v2); accum(v3);
        accum(v4); accum(v5); accum(v6); accum(v7);
    }

    if (dg < N) {
        float dd = dinv[dg];
        float* orow = outh + (size_t)dg * 64 + q * 8;
        f32x4 o0 = {dd * a01.x, dd * a01.y, dd * a23.x, dd * a23.y};
        f32x4 o1 = {dd * a45.x, dd * a45.y, dd * a67.x, dd * a67.y};
        __builtin_nontemporal_store(o0, (f32x4*)orow);
        __builtin_nontemporal_store(o1, (f32x4*)(orow + 4));
    }
}

// ============ centroid squared norms ============

__global__ void k_c2(const float* __restrict__ C, float* __restrict__ c2) {
    int k = threadIdx.x;
    if (k < 100) {
        float s = 0.f;
        for (int d = 0; d < 64; ++d) { float v = C[k * 64 + d]; s = fmaf(v, v, s); }
        c2[k] = s;
    }
}

// ============ centroid distances + pooling via MFMA ============
// 128 rows/block (4 waves x 32 rows) -> 782 blocks for latency hiding.

__global__ __launch_bounds__(256) void k_cent(const float* __restrict__ hin,
                                              const float* __restrict__ b2,
                                              const float* __restrict__ C,
                                              const float* __restrict__ c2g,
                                              float* __restrict__ partials, int N) {
    __shared__ float pool4[4][112];
    __shared__ float h2_s[128];
    int tid = threadIdx.x;
    int lane = tid & 63, w = tid >> 6;
    int l15 = lane & 15, lg = lane >> 4;      // lg = 0..3

    bf16x8 B[7][2];
#pragma unroll
    for (int ct = 0; ct < 7; ++ct) {
        int col = ct * 16 + l15;
#pragma unroll
        for (int ks = 0; ks < 2; ++ks) {
            float4 v0 = make_float4(0.f, 0.f, 0.f, 0.f);
            float4 v1 = make_float4(0.f, 0.f, 0.f, 0.f);
            if (col < 100) {
                const float* cr = C + (size_t)col * 64 + ks * 32 + lg * 8;
                v0 = *(const float4*)cr;
                v1 = *(const float4*)(cr + 4);
            }
            B[ct][ks] = pack_bf16x8(v0, v1);
        }
    }

    float bv[16];
#pragma unroll
    for (int ks = 0; ks < 2; ++ks) {
        float4 b0 = *(const float4*)(b2 + ks * 32 + lg * 8);
        float4 b1 = *(const float4*)(b2 + ks * 32 + lg * 8 + 4);
        bv[ks * 8 + 0] = b0.x; bv[ks * 8 + 1] = b0.y;
        bv[ks * 8 + 2] = b0.z; bv[ks * 8 + 3] = b0.w;
        bv[ks * 8 + 4] = b1.x; bv[ks * 8 + 5] = b1.y;
        bv[ks * 8 + 6] = b1.z; bv[ks * 8 + 7] = b1.w;
    }

    int rowbase = blockIdx.x * 128 + w * 32;

    f32x4 acc[2][7];
#pragma unroll
    for (int rt = 0; rt < 2; ++rt)
#pragma unroll
        for (int ct = 0; ct < 7; ++ct)
            acc[rt][ct] = (f32x4){0.f, 0.f, 0.f, 0.f};

#pragma unroll
    for (int rt = 0; rt < 2; ++rt) {
        int row = rowbase + rt * 16 + l15;
        int rowc = (row < N) ? row : (N - 1);     // clamp; excluded from pooling
        const float* hr = hin + ((size_t)rowc << 6);
        float hp[16];
        float h2p = 0.f;
#pragma unroll
        for (int ks = 0; ks < 2; ++ks) {
            float4 v0 = *(const float4*)(hr + ks * 32 + lg * 8);
            float4 v1 = *(const float4*)(hr + ks * 32 + lg * 8 + 4);
            float t0 = fmaxf(v0.x + bv[ks * 8 + 0], 0.f);
            float t1 = fmaxf(v0.y + bv[ks * 8 + 1], 0.f);
            float t2 = fmaxf(v0.z + bv[ks * 8 + 2], 0.f);
            float t3 = fmaxf(v0.w + bv[ks * 8 + 3], 0.f);
            float t4 = fmaxf(v1.x + bv[ks * 8 + 4], 0.f);
            float t5 = fmaxf(v1.y + bv[ks * 8 + 5], 0.f);
            float t6 = fmaxf(v1.z + bv[ks * 8 + 6], 0.f);
            float t7 = fmaxf(v1.w + bv[ks * 8 + 7], 0.f);
            hp[ks * 8 + 0] = t0; hp[ks * 8 + 1] = t1;
            hp[ks * 8 + 2] = t2; hp[ks * 8 + 3] = t3;
            hp[ks * 8 + 4] = t4; hp[ks * 8 + 5] = t5;
            hp[ks * 8 + 6] = t6; hp[ks * 8 + 7] = t7;
            h2p = fmaf(t0, t0, h2p); h2p = fmaf(t1, t1, h2p);
            h2p = fmaf(t2, t2, h2p); h2p = fmaf(t3, t3, h2p);
            h2p = fmaf(t4, t4, h2p); h2p = fmaf(t5, t5, h2p);
            h2p = fmaf(t6, t6, h2p); h2p = fmaf(t7, t7, h2p);
        }
        h2p += __shfl_xor(h2p, 16);
        h2p += __shfl_xor(h2p, 32);
        if (lg == 0) h2_s[w * 32 + rt * 16 + l15] = h2p;

#pragma unroll
        for (int ks = 0; ks < 2; ++ks) {
            bf16x8 a;
#pragma unroll
            for (int j = 0; j < 8; ++j) a[j] = f2bf(hp[ks * 8 + j]);
#pragma unroll
            for (int ct = 0; ct < 7; ++ct)
                acc[rt][ct] = __builtin_amdgcn_mfma_f32_16x16x32_bf16(
                    a, B[ct][ks], acc[rt][ct], 0, 0, 0);
        }
    }

    float S[7] = {0.f, 0.f, 0.f, 0.f, 0.f, 0.f, 0.f};
#pragma unroll
    for (int rt = 0; rt < 2; ++rt) {
#pragma unroll
        for (int r = 0; r < 4; ++r) {
            int row = rowbase + rt * 16 + lg * 4 + r;
            float h2v = h2_s[w * 32 + rt * 16 + lg * 4 + r];
            bool rv = row < N;
#pragma unroll
            for (int ct = 0; ct < 7; ++ct) {
                int col = ct * 16 + l15;
                float c2v = (col < 100) ? c2g[col] : 0.f;
                float G = acc[rt][ct][r];
                float d2 = fmaxf(h2v + c2v - 2.f * G, 0.f);
                float xx = d2 + 1e-12f;
                float dist = xx * __frsqrt_rn(xx);       // sqrt via rsq, 1 trans op
                S[ct] += (rv && col < 100) ? dist : 0.f;
            }
        }
    }
#pragma unroll
    for (int ct = 0; ct < 7; ++ct) {
        float s = S[ct];
        s += __shfl_xor(s, 16);
        s += __shfl_xor(s, 32);
        if (lg == 0) pool4[w][ct * 16 + l15] = s;   // S[ct]=0 for padded cols
    }
    __syncthreads();
    if (tid < 112) {
        float s = pool4[0][tid] + pool4[1][tid] + pool4[2][tid] + pool4[3][tid];
        partials[(size_t)blockIdx.x * 128 + tid] = s;
    }
}

// ============ output head: reduce partials + apply W_out ============
// 8 groups x 128; 8-wide unrolled strided sum (independent accumulators for MLP).

__global__ __launch_bounds__(1024) void k_out(const float* __restrict__ partials, int nb,
                                              const float* __restrict__ Wout,
                                              const float* __restrict__ bout,
                                              float* __restrict__ out, float invN) {
    __shared__ float ps[8][112];
    int t = threadIdx.x & 127, g = threadIdx.x >> 7;
    if (t < 112) {
        float s0 = 0.f, s1 = 0.f, s2 = 0.f, s3 = 0.f;
        float s4 = 0.f, s5 = 0.f, s6 = 0.f, s7 = 0.f;
        int b = g;
        for (; b + 56 < nb; b += 64) {
            s0 += partials[(size_t)(b     ) * 128 + t];
            s1 += partials[(size_t)(b +  8) * 128 + t];
            s2 += partials[(size_t)(b + 16) * 128 + t];
            s3 += partials[(size_t)(b + 24) * 128 + t];
            s4 += partials[(size_t)(b + 32) * 128 + t];
            s5 += partials[(size_t)(b + 40) * 128 + t];
            s6 += partials[(size_t)(b + 48) * 128 + t];
            s7 += partials[(size_t)(b + 56) * 128 + t];
        }
        for (; b < nb; b += 8) s0 += partials[(size_t)b * 128 + t];
        ps[g][t] = ((s0 + s1) + (s2 + s3)) + ((s4 + s5) + (s6 + s7));
    }
    __syncthreads();
    if (threadIdx.x < 10) {
        int tt = threadIdx.x;
        float s = 0.f;
        for (int k = 0; k < 100; ++k) {
            float p = ps[0][k] + ps[1][k] + ps[2][k] + ps[3][k]
                    + ps[4][k] + ps[5][k] + ps[6][k] + ps[7][k];
            s = fmaf(p, Wout[tt * 100 + k], s);
        }
        out[tt] = s * invN + bout[tt];
    }
}

// ============ launcher ============

extern "C" void kernel_launch(void* const* d_in, const int* in_sizes, int n_in,
                              void* d_out, int out_size, void* d_ws, size_t ws_size,
                              hipStream_t stream) {
    const float* x    = (const float*)d_in[0];
    const int*   ei   = (const int*)d_in[1];
    const float* We   = (const float*)d_in[2];
    const float* Wg   = (const float*)d_in[3];
    const float* bg   = (const float*)d_in[4];
    const float* C    = (const float*)d_in[5];
    const float* Wout = (const float*)d_in[6];
    const float* bout = (const float*)d_in[7];
    float*       out  = (float*)d_out;

    const int N = in_sizes[0] / 128;          // 100000
    const int E = in_sizes[1] / 2;            // 1600000
    const int NBUCK = (N + 255) >> 8;         // 391 dst-buckets
    const int NCH = (E + CHUNK - 1) / CHUNK;  // 98 chunks
    const int NBC = (N + 127) / 128;          // k_cent blocks (782)
    const int NBA = (N + 63) / 64;            // k_agg blocks (1563): 64 dsts/block

    char* ws = (char*)d_ws;
    size_t off = 0;
    auto alloc = [&](size_t bytes) { void* p = ws + off; off += (bytes + 511) & ~(size_t)511; return p; };
    float*  dinv   = (float*)alloc((size_t)N * 4);
    int2*   rc     = (int2*) alloc((size_t)N * 8);
    int*    bcnt   = (int*)  alloc((size_t)NBUCK * NCH * 4);
    int*    bofs   = (int*)  alloc((size_t)NBUCK * NCH * 4);
    int*    btot   = (int*)  alloc((size_t)NBUCK * 4);
    int*    bbase  = (int*)  alloc((size_t)(NBUCK + 1) * 4);
    uint32* ebuf   = (uint32*)alloc((size_t)E * 4);
    int*    ssrc   = (int*)  alloc((size_t)(E + 64) * 4);     // pad for agg reads
    float*  hA     = (float*)alloc((size_t)N * 64 * 4);
    uint32* tab0   = (uint32*)alloc((size_t)(N + 1) * 32);    // fp8 feats 0..31 + sentinel
    uint32* tab1   = (uint32*)alloc((size_t)(N + 1) * 32);    // fp8 feats 32..63 + sentinel
    float*  c2     = (float*)alloc(512);
    float*  partials = (float*)alloc((size_t)NBC * 128 * 4);

    hipMemsetAsync(tab0 + (size_t)N * 8, 0, 32, stream);      // sentinel rows = 0
    hipMemsetAsync(tab1 + (size_t)N * 8, 0, 32, stream);

    // bucketed CSR build (no global atomics)
    k_bhist<<<NCH, 256, 0, stream>>>(ei + E, bcnt, E, NBUCK, NCH);
    k_bscan1<<<NBUCK, 128, 0, stream>>>(bcnt, bofs, btot, NCH);
    k_bscan2<<<1, 512, 0, stream>>>(btot, bbase, NBUCK);
    k_bscatter<<<NCH, 256, 0, stream>>>(ei, bbase, bofs, ebuf, E, NBUCK, NCH);
    k_bsort<<<NBUCK, 256, 0, stream>>>(ebuf, bbase, ssrc, rc, dinv, N);
    k_c2<<<1, 128, 0, stream>>>(C, c2);

    // embed (MFMA bf16, 256 rows/block)
    k_embed<<<(N + 255) / 256, 256, 0, stream>>>(x, We, hA, N);

    // 3 GCN layers: gemm (hA -> fp8 tab halves), aggregate per half (L2-resident)
    for (int l = 0; l < 3; ++l) {
        const float* bias_prev = (l == 0) ? bg : (bg + (l - 1) * 64);
        int act = (l == 0) ? 0 : 1;
        k_gcn<<<(N + 255) / 256, 256, 0, stream>>>(hA, Wg + (size_t)l * 64 * 64,
                                                   bias_prev, act, dinv, tab0, tab1, N);
        k_agg<<<NBA, 256, 0, stream>>>(rc, ssrc, dinv, (const uint2*)tab0, hA, N, E);
        k_agg<<<NBA, 256, 0, stream>>>(rc, ssrc, dinv, (const uint2*)tab1, hA + 32, N, E);
    }

    // centroid distances + pooling via MFMA (applies relu + b_gcn[2])
    k_cent<<<NBC, 256, 0, stream>>>(hA, bg + 2 * 64, C, c2, partials, N);

    // head: reduce partials + W_out
    k_out<<<1, 1024, 0, stream>>>(partials, NBC, Wout, bout, out, 1.0f / (float)N);
}

// Round 10
// 348.931 us; speedup vs baseline: 1.2671x; 1.0242x over previous
//
#include <hip/hip_runtime.h>
#include <hip/hip_bf16.h>

typedef unsigned int uint32;
typedef float floatx2 __attribute__((ext_vector_type(2)));
typedef __attribute__((ext_vector_type(8))) short bf16x8;
typedef __attribute__((ext_vector_type(4))) float f32x4;

#define CHUNK 16384

// ============ bucketed CSR build (dst>>8 buckets, LDS-atomic sort) ============

__global__ __launch_bounds__(256) void k_bhist(const int* __restrict__ dst,
                                               int* __restrict__ bcnt,
                                               int E, int NBUCK, int NCH) {
    __shared__ int h[512];
    int c = blockIdx.x, tid = threadIdx.x;
    for (int i = tid; i < NBUCK; i += 256) h[i] = 0;
    __syncthreads();
    int base = c * CHUNK;
#pragma unroll
    for (int k = 0; k < CHUNK / 256; ++k) {
        int e = base + k * 256 + tid;
        if (e < E) atomicAdd(&h[dst[e] >> 8], 1);
    }
    __syncthreads();
    for (int i = tid; i < NBUCK; i += 256) bcnt[(size_t)i * NCH + c] = h[i];
}

__global__ __launch_bounds__(128) void k_bscan1(const int* __restrict__ bcnt,
                                                int* __restrict__ bofs,
                                                int* __restrict__ btot, int NCH) {
    __shared__ int tmp[128];
    int b = blockIdx.x, t = threadIdx.x;
    int v = (t < NCH) ? bcnt[(size_t)b * NCH + t] : 0;
    tmp[t] = v;
    __syncthreads();
    for (int off = 1; off < 128; off <<= 1) {
        int u = (t >= off) ? tmp[t - off] : 0;
        __syncthreads();
        tmp[t] += u;
        __syncthreads();
    }
    if (t < NCH) bofs[(size_t)b * NCH + t] = tmp[t] - v;
    if (t == 127) btot[b] = tmp[127];
}

__global__ __launch_bounds__(512) void k_bscan2(const int* __restrict__ btot,
                                                int* __restrict__ bbase, int nb) {
    __shared__ int tmp[512];
    int t = threadIdx.x;
    int v = (t < nb) ? btot[t] : 0;
    tmp[t] = v;
    __syncthreads();
    for (int off = 1; off < 512; off <<= 1) {
        int u = (t >= off) ? tmp[t - off] : 0;
        __syncthreads();
        tmp[t] += u;
        __syncthreads();
    }
    if (t < nb) bbase[t] = tmp[t] - v;
    if (t == nb - 1) bbase[nb] = tmp[t];
}

__global__ __launch_bounds__(256) void k_bscatter(const int* __restrict__ ei,
                                                  const int* __restrict__ bbase,
                                                  const int* __restrict__ bofs,
                                                  uint32* __restrict__ ebuf,
                                                  int E, int NBUCK, int NCH) {
    __shared__ int cur[512];
    int c = blockIdx.x, tid = threadIdx.x;
    for (int i = tid; i < NBUCK; i += 256)
        cur[i] = bbase[i] + bofs[(size_t)i * NCH + c];
    __syncthreads();
    int base = c * CHUNK;
#pragma unroll
    for (int k = 0; k < CHUNK / 256; ++k) {
        int e = base + k * 256 + tid;
        if (e < E) {
            int s = ei[e];
            int d = ei[E + e];
            int p = atomicAdd(&cur[d >> 8], 1);
            ebuf[p] = (uint32)s | ((uint32)(d & 255) << 20);
        }
    }
}

__global__ __launch_bounds__(256) void k_bsort(const uint32* __restrict__ ebuf,
                                               const int* __restrict__ bbase,
                                               int* __restrict__ ssrc,
                                               int2* __restrict__ rc,
                                               float* __restrict__ dinv, int N) {
    __shared__ int h[256];
    __shared__ int sc[256];
    __shared__ int cur[256];
    int b = blockIdx.x, tid = threadIdx.x;
    int beg = bbase[b], end = bbase[b + 1];
    h[tid] = 0;
    __syncthreads();
    for (int j = beg + tid; j < end; j += 256)
        atomicAdd(&h[(ebuf[j] >> 20) & 255], 1);
    __syncthreads();
    int v = h[tid];
    sc[tid] = v;
    __syncthreads();
    for (int off = 1; off < 256; off <<= 1) {
        int u = (tid >= off) ? sc[tid - off] : 0;
        __syncthreads();
        sc[tid] += u;
        __syncthreads();
    }
    int rowbase = beg + sc[tid] - v;
    cur[tid] = rowbase;
    int d = b * 256 + tid;
    if (d < N) {
        rc[d] = make_int2(rowbase, v);
        dinv[d] = rsqrtf((float)(v + 1));   // +1 self loop
    }
    __syncthreads();
    for (int j = beg + tid; j < end; j += 256) {
        uint32 w = ebuf[j];
        int p = atomicAdd(&cur[(w >> 20) & 255], 1);
        ssrc[p] = (int)(w & 0xFFFFFu);
    }
}

// ============ bf16 helpers ============

__device__ __forceinline__ short f2bf(float f) {
    __hip_bfloat16 b = __float2bfloat16(f);
    return __builtin_bit_cast(short, b);
}

__device__ __forceinline__ float bf2f(short s) {
    uint32 u = ((uint32)(unsigned short)s) << 16;
    return __builtin_bit_cast(float, u);
}

__device__ __forceinline__ bf16x8 pack_bf16x8(float4 v0, float4 v1) {
    bf16x8 r;
    r[0] = f2bf(v0.x); r[1] = f2bf(v0.y); r[2] = f2bf(v0.z); r[3] = f2bf(v0.w);
    r[4] = f2bf(v1.x); r[5] = f2bf(v1.y); r[6] = f2bf(v1.z); r[7] = f2bf(v1.w);
    return r;
}

// ============ embed GEMM via MFMA: h = x @ We^T ([N,128] @ [128,64]^T) ============
// Output hA is bf16 (halved traffic for all downstream readers).
// Layouts (m89-verified): A[lane&15][(lane>>4)*8+j], B[(lane>>4)*8+j][lane&15],
// D[(lane>>4)*4+r][lane&15].

__global__ __launch_bounds__(256) void k_embed(const float* __restrict__ x,
                                               const float* __restrict__ We,
                                               short* __restrict__ h, int N) {
    int lane = threadIdx.x & 63;
    int w = threadIdx.x >> 6;
    int l15 = lane & 15;
    int lg = lane >> 4;                       // 0..3

    bf16x8 B[4][4];
#pragma unroll
    for (int ct = 0; ct < 4; ++ct) {
        const float* wr = We + (size_t)(ct * 16 + l15) * 128 + lg * 8;
#pragma unroll
        for (int ks = 0; ks < 4; ++ks) {
            float4 v0 = *(const float4*)(wr + ks * 32);
            float4 v1 = *(const float4*)(wr + ks * 32 + 4);
            B[ct][ks] = pack_bf16x8(v0, v1);
        }
    }

    int rowbase = blockIdx.x * 256 + w * 64;

    f32x4 acc[4][4];
#pragma unroll
    for (int rt = 0; rt < 4; ++rt)
#pragma unroll
        for (int ct = 0; ct < 4; ++ct)
            acc[rt][ct] = (f32x4){0.f, 0.f, 0.f, 0.f};

#pragma unroll
    for (int ks = 0; ks < 4; ++ks) {
#pragma unroll
        for (int rt = 0; rt < 4; ++rt) {
            int row = rowbase + rt * 16 + l15;
            row = (row < N) ? row : (N - 1);          // clamp; stores predicated
            const float* xr = x + (size_t)row * 128 + ks * 32 + lg * 8;
            float4 v0 = *(const float4*)xr;
            float4 v1 = *(const float4*)(xr + 4);
            bf16x8 a = pack_bf16x8(v0, v1);
#pragma unroll
            for (int ct = 0; ct < 4; ++ct)
                acc[rt][ct] = __builtin_amdgcn_mfma_f32_16x16x32_bf16(
                    a, B[ct][ks], acc[rt][ct], 0, 0, 0);
        }
    }

#pragma unroll
    for (int rt = 0; rt < 4; ++rt) {
        int row0 = rowbase + rt * 16 + lg * 4;
#pragma unroll
        for (int r = 0; r < 4; ++r) {
            int row = row0 + r;
            if (row < N) {
#pragma unroll
                for (int ct = 0; ct < 4; ++ct)
                    h[(size_t)row * 64 + ct * 16 + l15] = f2bf(acc[rt][ct][r]);
            }
        }
    }
}

// ============ GCN layer GEMM via MFMA (bf16 in, split fp8 tables out) ========
// D = Wg . h^T with h PRE-ACTIVATED bf16 (bias+relu fused into k_agg) ->
// B-frags are direct 16B loads, zero VALU prep. Output split by feature half
// into tab0/tab1 (3.2 MB each, fits per-XCD L2 for the aggregation pass).

__global__ __launch_bounds__(256) void k_gcn(const short* __restrict__ hin,
                                             const float* __restrict__ Wg,
                                             const float* __restrict__ dinv,
                                             uint32* __restrict__ tab0,
                                             uint32* __restrict__ tab1, int N) {
    int lane = threadIdx.x & 63;
    int w = threadIdx.x >> 6;
    int l15 = lane & 15, lg = lane >> 4;

    bf16x8 A[4][2];
#pragma unroll
    for (int rt = 0; rt < 4; ++rt) {
        const float* wr = Wg + (size_t)(rt * 16 + l15) * 64 + lg * 8;
#pragma unroll
        for (int ks = 0; ks < 2; ++ks) {
            float4 v0 = *(const float4*)(wr + ks * 32);
            float4 v1 = *(const float4*)(wr + ks * 32 + 4);
            A[rt][ks] = pack_bf16x8(v0, v1);
        }
    }

    int nodebase = blockIdx.x * 256 + w * 64;   // wave: 64 nodes = 4 tiles of 16

#pragma unroll
    for (int nt = 0; nt < 4; ++nt) {
        int node = nodebase + nt * 16 + l15;
        int nodec = (node < N) ? node : (N - 1);
        const short* hr = hin + ((size_t)nodec << 6) + lg * 8;

        bf16x8 Bf0 = *(const bf16x8*)(hr);
        bf16x8 Bf1 = *(const bf16x8*)(hr + 32);

        f32x4 acc[4];
#pragma unroll
        for (int rt = 0; rt < 4; ++rt) acc[rt] = (f32x4){0.f, 0.f, 0.f, 0.f};
#pragma unroll
        for (int rt = 0; rt < 4; ++rt)
            acc[rt] = __builtin_amdgcn_mfma_f32_16x16x32_bf16(A[rt][0], Bf0, acc[rt], 0, 0, 0);
#pragma unroll
        for (int rt = 0; rt < 4; ++rt)
            acc[rt] = __builtin_amdgcn_mfma_f32_16x16x32_bf16(A[rt][1], Bf1, acc[rt], 0, 0, 0);

        float s = dinv[nodec];
        if (node < N) {
#pragma unroll
            for (int rt = 0; rt < 4; ++rt) {
                int u = 0;
                u = __builtin_amdgcn_cvt_pk_fp8_f32(acc[rt][0] * s, acc[rt][1] * s, u, false);
                u = __builtin_amdgcn_cvt_pk_fp8_f32(acc[rt][2] * s, acc[rt][3] * s, u, true);
                uint32* tp = (rt < 2) ? tab0 : tab1;
                tp[(size_t)node * 8 + (rt & 1) * 4 + lg] = u;
            }
        }
    }
}

// ============ fp8 CSR aggregate: half-feature pass, 16 dsts/wave =============
// Each 4-lane group owns ONE dst; 8 independent gathers in flight per iter.
// Epilogue fuses the layer's bias + relu and stores bf16 (16B per group) --
// downstream consumers (next gcn / cent) read pre-activated bf16 directly.

__global__ __launch_bounds__(256) void k_agg(const int2* __restrict__ rc,
                                             const int* __restrict__ ssrc,
                                             const float* __restrict__ dinv,
                                             const uint2* __restrict__ tabh,
                                             short* __restrict__ outh,
                                             const float* __restrict__ bias,
                                             int N, int E) {
    int lane = threadIdx.x & 63;
    int wid = threadIdx.x >> 6;
    int q = lane & 3;
    int g = lane >> 2;                          // group 0..15
    int dbase = (blockIdx.x * 4 + wid) * 16;
    if (dbase >= N) return;

    int2 r = rc[min(dbase + (lane & 15), N - 1)];
    int beg = __shfl(r.x, g);
    int deg = __shfl(r.y, g);
    int dg = dbase + g;
    if (dg >= N) deg = 0;

    floatx2 a01 = {0.f, 0.f}, a23 = {0.f, 0.f}, a45 = {0.f, 0.f}, a67 = {0.f, 0.f};
    auto accum = [&](uint2 v) {
        a01 += __builtin_amdgcn_cvt_pk_f32_fp8((int)v.x, false);
        a23 += __builtin_amdgcn_cvt_pk_f32_fp8((int)v.x, true);
        a45 += __builtin_amdgcn_cvt_pk_f32_fp8((int)v.y, false);
        a67 += __builtin_amdgcn_cvt_pk_f32_fp8((int)v.y, true);
    };

    // self loop (each group reads its own dst row once)
    accum(tabh[(size_t)((dg < N) ? dg : N) * 4 + q]);

    int m = deg;
    m = max(m, __shfl_xor(m, 4));
    m = max(m, __shfl_xor(m, 8));
    m = max(m, __shfl_xor(m, 16));
    m = max(m, __shfl_xor(m, 32));
    int maxd = __builtin_amdgcn_readfirstlane(m);

    int base4 = lane & 60;                      // group base lane
    for (int j = 0; j < maxd; j += 8) {
        int i0 = beg + j + q;                   // edges j..j+3 of this group
        int i1 = i0 + 4;                        // edges j+4..j+7
        int ev0 = ssrc[i0 < E ? i0 : 0];        // ssrc has tail pad; masked below
        int ev1 = ssrc[i1 < E ? i1 : 0];
        int t0 = __shfl(ev0, base4 | 0);
        int t1 = __shfl(ev0, base4 | 1);
        int t2 = __shfl(ev0, base4 | 2);
        int t3 = __shfl(ev0, base4 | 3);
        int t4 = __shfl(ev1, base4 | 0);
        int t5 = __shfl(ev1, base4 | 1);
        int t6 = __shfl(ev1, base4 | 2);
        int t7 = __shfl(ev1, base4 | 3);
        t0 = (j + 0 < deg) ? t0 : N;            // sentinel row N = zeros
        t1 = (j + 1 < deg) ? t1 : N;
        t2 = (j + 2 < deg) ? t2 : N;
        t3 = (j + 3 < deg) ? t3 : N;
        t4 = (j + 4 < deg) ? t4 : N;
        t5 = (j + 5 < deg) ? t5 : N;
        t6 = (j + 6 < deg) ? t6 : N;
        t7 = (j + 7 < deg) ? t7 : N;
        uint2 v0 = tabh[(size_t)t0 * 4 + q];    // 8 independent gathers in flight
        uint2 v1 = tabh[(size_t)t1 * 4 + q];
        uint2 v2 = tabh[(size_t)t2 * 4 + q];
        uint2 v3 = tabh[(size_t)t3 * 4 + q];
        uint2 v4 = tabh[(size_t)t4 * 4 + q];
        uint2 v5 = tabh[(size_t)t5 * 4 + q];
        uint2 v6 = tabh[(size_t)t6 * 4 + q];
        uint2 v7 = tabh[(size_t)t7 * 4 + q];
        accum(v0); accum(v1); accum(v2); accum(v3);
        accum(v4); accum(v5); accum(v6); accum(v7);
    }

    if (dg < N) {
        float dd = dinv[dg];
        float4 b0 = *(const float4*)(bias + q * 8);
        float4 b1 = *(const float4*)(bias + q * 8 + 4);
        bf16x8 o;
        o[0] = f2bf(fmaxf(fmaf(dd, a01.x, b0.x), 0.f));
        o[1] = f2bf(fmaxf(fmaf(dd, a01.y, b0.y), 0.f));
        o[2] = f2bf(fmaxf(fmaf(dd, a23.x, b0.z), 0.f));
        o[3] = f2bf(fmaxf(fmaf(dd, a23.y, b0.w), 0.f));
        o[4] = f2bf(fmaxf(fmaf(dd, a45.x, b1.x), 0.f));
        o[5] = f2bf(fmaxf(fmaf(dd, a45.y, b1.y), 0.f));
        o[6] = f2bf(fmaxf(fmaf(dd, a67.x, b1.z), 0.f));
        o[7] = f2bf(fmaxf(fmaf(dd, a67.y, b1.w), 0.f));
        __builtin_nontemporal_store(o, (bf16x8*)(outh + (size_t)dg * 64 + q * 8));
    }
}

// ============ centroid squared norms ============

__global__ void k_c2(const float* __restrict__ C, float* __restrict__ c2) {
    int k = threadIdx.x;
    if (k < 100) {
        float s = 0.f;
        for (int d = 0; d < 64; ++d) { float v = C[k * 64 + d]; s = fmaf(v, v, s); }
        c2[k] = s;
    }
}

// ============ centroid distances + pooling via MFMA ============
// hin is pre-activated bf16 (bias+relu applied by last k_agg): A-frags load
// directly; h2 computed from the same bf16 values (exactly consistent with G).

__global__ __launch_bounds__(256) void k_cent(const short* __restrict__ hin,
                                              const float* __restrict__ C,
                                              const float* __restrict__ c2g,
                                              float* __restrict__ partials, int N) {
    __shared__ float pool4[4][112];
    __shared__ float h2_s[128];
    int tid = threadIdx.x;
    int lane = tid & 63, w = tid >> 6;
    int l15 = lane & 15, lg = lane >> 4;      // lg = 0..3

    bf16x8 B[7][2];
#pragma unroll
    for (int ct = 0; ct < 7; ++ct) {
        int col = ct * 16 + l15;
#pragma unroll
        for (int ks = 0; ks < 2; ++ks) {
            float4 v0 = make_float4(0.f, 0.f, 0.f, 0.f);
            float4 v1 = make_float4(0.f, 0.f, 0.f, 0.f);
            if (col < 100) {
                const float* cr = C + (size_t)col * 64 + ks * 32 + lg * 8;
                v0 = *(const float4*)cr;
                v1 = *(const float4*)(cr + 4);
            }
            B[ct][ks] = pack_bf16x8(v0, v1);
        }
    }

    int rowbase = blockIdx.x * 128 + w * 32;

    f32x4 acc[2][7];
#pragma unroll
    for (int rt = 0; rt < 2; ++rt)
#pragma unroll
        for (int ct = 0; ct < 7; ++ct)
            acc[rt][ct] = (f32x4){0.f, 0.f, 0.f, 0.f};

#pragma unroll
    for (int rt = 0; rt < 2; ++rt) {
        int row = rowbase + rt * 16 + l15;
        int rowc = (row < N) ? row : (N - 1);     // clamp; excluded from pooling
        const short* hr = hin + ((size_t)rowc << 6) + lg * 8;
        bf16x8 a0 = *(const bf16x8*)(hr);
        bf16x8 a1 = *(const bf16x8*)(hr + 32);

        float h2p = 0.f;
#pragma unroll
        for (int j = 0; j < 8; ++j) {
            float v0 = bf2f(a0[j]);
            float v1 = bf2f(a1[j]);
            h2p = fmaf(v0, v0, h2p);
            h2p = fmaf(v1, v1, h2p);
        }
        h2p += __shfl_xor(h2p, 16);
        h2p += __shfl_xor(h2p, 32);
        if (lg == 0) h2_s[w * 32 + rt * 16 + l15] = h2p;

#pragma unroll
        for (int ct = 0; ct < 7; ++ct)
            acc[rt][ct] = __builtin_amdgcn_mfma_f32_16x16x32_bf16(
                a0, B[ct][0], acc[rt][ct], 0, 0, 0);
#pragma unroll
        for (int ct = 0; ct < 7; ++ct)
            acc[rt][ct] = __builtin_amdgcn_mfma_f32_16x16x32_bf16(
                a1, B[ct][1], acc[rt][ct], 0, 0, 0);
    }

    float S[7] = {0.f, 0.f, 0.f, 0.f, 0.f, 0.f, 0.f};
#pragma unroll
    for (int rt = 0; rt < 2; ++rt) {
#pragma unroll
        for (int r = 0; r < 4; ++r) {
            int row = rowbase + rt * 16 + lg * 4 + r;
            float h2v = h2_s[w * 32 + rt * 16 + lg * 4 + r];
            bool rv = row < N;
#pragma unroll
            for (int ct = 0; ct < 7; ++ct) {
                int col = ct * 16 + l15;
                float c2v = (col < 100) ? c2g[col] : 0.f;
                float G = acc[rt][ct][r];
                float d2 = fmaxf(h2v + c2v - 2.f * G, 0.f);
                float xx = d2 + 1e-12f;
                float dist = xx * __frsqrt_rn(xx);       // sqrt via rsq, 1 trans op
                S[ct] += (rv && col < 100) ? dist : 0.f;
            }
        }
    }
#pragma unroll
    for (int ct = 0; ct < 7; ++ct) {
        float s = S[ct];
        s += __shfl_xor(s, 16);
        s += __shfl_xor(s, 32);
        if (lg == 0) pool4[w][ct * 16 + l15] = s;   // S[ct]=0 for padded cols
    }
    __syncthreads();
    if (tid < 112) {
        float s = pool4[0][tid] + pool4[1][tid] + pool4[2][tid] + pool4[3][tid];
        partials[(size_t)blockIdx.x * 128 + tid] = s;
    }
}

// ============ output head: reduce partials + apply W_out ============
// 8 groups x 128; 8-wide unrolled strided sum (independent accumulators for MLP).

__global__ __launch_bounds__(1024) void k_out(const float* __restrict__ partials, int nb,
                                              const float* __restrict__ Wout,
                                              const float* __restrict__ bout,
                                              float* __restrict__ out, float invN) {
    __shared__ float ps[8][112];
    int t = threadIdx.x & 127, g = threadIdx.x >> 7;
    if (t < 112) {
        float s0 = 0.f, s1 = 0.f, s2 = 0.f, s3 = 0.f;
        float s4 = 0.f, s5 = 0.f, s6 = 0.f, s7 = 0.f;
        int b = g;
        for (; b + 56 < nb; b += 64) {
            s0 += partials[(size_t)(b     ) * 128 + t];
            s1 += partials[(size_t)(b +  8) * 128 + t];
            s2 += partials[(size_t)(b + 16) * 128 + t];
            s3 += partials[(size_t)(b + 24) * 128 + t];
            s4 += partials[(size_t)(b + 32) * 128 + t];
            s5 += partials[(size_t)(b + 40) * 128 + t];
            s6 += partials[(size_t)(b + 48) * 128 + t];
            s7 += partials[(size_t)(b + 56) * 128 + t];
        }
        for (; b < nb; b += 8) s0 += partials[(size_t)b * 128 + t];
        ps[g][t] = ((s0 + s1) + (s2 + s3)) + ((s4 + s5) + (s6 + s7));
    }
    __syncthreads();
    if (threadIdx.x < 10) {
        int tt = threadIdx.x;
        float s = 0.f;
        for (int k = 0; k < 100; ++k) {
            float p = ps[0][k] + ps[1][k] + ps[2][k] + ps[3][k]
                    + ps[4][k] + ps[5][k] + ps[6][k] + ps[7][k];
            s = fmaf(p, Wout[tt * 100 + k], s);
        }
        out[tt] = s * invN + bout[tt];
    }
}

// ============ launcher ============

extern "C" void kernel_launch(void* const* d_in, const int* in_sizes, int n_in,
                              void* d_out, int out_size, void* d_ws, size_t ws_size,
                              hipStream_t stream) {
    const float* x    = (const float*)d_in[0];
    const int*   ei   = (const int*)d_in[1];
    const float* We   = (const float*)d_in[2];
    const float* Wg   = (const float*)d_in[3];
    const float* bg   = (const float*)d_in[4];
    const float* C    = (const float*)d_in[5];
    const float* Wout = (const float*)d_in[6];
    const float* bout = (const float*)d_in[7];
    float*       out  = (float*)d_out;

    const int N = in_sizes[0] / 128;          // 100000
    const int E = in_sizes[1] / 2;            // 1600000
    const int NBUCK = (N + 255) >> 8;         // 391 dst-buckets
    const int NCH = (E + CHUNK - 1) / CHUNK;  // 98 chunks
    const int NBC = (N + 127) / 128;          // k_cent blocks (782)
    const int NBA = (N + 63) / 64;            // k_agg blocks (1563): 64 dsts/block

    char* ws = (char*)d_ws;
    size_t off = 0;
    auto alloc = [&](size_t bytes) { void* p = ws + off; off += (bytes + 511) & ~(size_t)511; return p; };
    float*  dinv   = (float*)alloc((size_t)N * 4);
    int2*   rc     = (int2*) alloc((size_t)N * 8);
    int*    bcnt   = (int*)  alloc((size_t)NBUCK * NCH * 4);
    int*    bofs   = (int*)  alloc((size_t)NBUCK * NCH * 4);
    int*    btot   = (int*)  alloc((size_t)NBUCK * 4);
    int*    bbase  = (int*)  alloc((size_t)(NBUCK + 1) * 4);
    uint32* ebuf   = (uint32*)alloc((size_t)E * 4);
    int*    ssrc   = (int*)  alloc((size_t)(E + 64) * 4);     // pad for agg reads
    short*  hA     = (short*)alloc((size_t)N * 64 * 2);       // bf16 activations
    uint32* tab0   = (uint32*)alloc((size_t)(N + 1) * 32);    // fp8 feats 0..31 + sentinel
    uint32* tab1   = (uint32*)alloc((size_t)(N + 1) * 32);    // fp8 feats 32..63 + sentinel
    float*  c2     = (float*)alloc(512);
    float*  partials = (float*)alloc((size_t)NBC * 128 * 4);

    hipMemsetAsync(tab0 + (size_t)N * 8, 0, 32, stream);      // sentinel rows = 0
    hipMemsetAsync(tab1 + (size_t)N * 8, 0, 32, stream);

    // bucketed CSR build (no global atomics)
    k_bhist<<<NCH, 256, 0, stream>>>(ei + E, bcnt, E, NBUCK, NCH);
    k_bscan1<<<NBUCK, 128, 0, stream>>>(bcnt, bofs, btot, NCH);
    k_bscan2<<<1, 512, 0, stream>>>(btot, bbase, NBUCK);
    k_bscatter<<<NCH, 256, 0, stream>>>(ei, bbase, bofs, ebuf, E, NBUCK, NCH);
    k_bsort<<<NBUCK, 256, 0, stream>>>(ebuf, bbase, ssrc, rc, dinv, N);
    k_c2<<<1, 128, 0, stream>>>(C, c2);

    // embed (MFMA bf16 out, 256 rows/block). Layer 0 has no pre-activation.
    k_embed<<<(N + 255) / 256, 256, 0, stream>>>(x, We, hA, N);

    // 3 GCN layers: gemm (bf16 hA -> fp8 tab halves), aggregate per half.
    // k_agg fuses bias+relu of layer l and stores bf16.
    for (int l = 0; l < 3; ++l) {
        k_gcn<<<(N + 255) / 256, 256, 0, stream>>>(hA, Wg + (size_t)l * 64 * 64,
                                                   dinv, tab0, tab1, N);
        k_agg<<<NBA, 256, 0, stream>>>(rc, ssrc, dinv, (const uint2*)tab0,
                                       hA, bg + (size_t)l * 64, N, E);
        k_agg<<<NBA, 256, 0, stream>>>(rc, ssrc, dinv, (const uint2*)tab1,
                                       hA + 32, bg + (size_t)l * 64 + 32, N, E);
    }

    // centroid distances + pooling via MFMA (hA already activated)
    k_cent<<<NBC, 256, 0, stream>>>(hA, C, c2, partials, N);

    // head: reduce partials + W_out
    k_out<<<1, 1024, 0, stream>>>(partials, NBC, Wout, bout, out, 1.0f / (float)N);
}

// Round 11
// 339.051 us; speedup vs baseline: 1.3040x; 1.0291x over previous
//
#include <hip/hip_runtime.h>
#include <hip/hip_bf16.h>

typedef unsigned int uint32;
typedef float floatx2 __attribute__((ext_vector_type(2)));
typedef __attribute__((ext_vector_type(8))) short bf16x8;
typedef __attribute__((ext_vector_type(4))) float f32x4;

#define CHUNK 16384

// ============ bucketed CSR build (dst>>8 buckets, LDS-atomic sort) ============

__global__ __launch_bounds__(256) void k_bhist(const int* __restrict__ dst,
                                               int* __restrict__ bcnt,
                                               int E, int NBUCK, int NCH) {
    __shared__ int h[512];
    int c = blockIdx.x, tid = threadIdx.x;
    for (int i = tid; i < NBUCK; i += 256) h[i] = 0;
    __syncthreads();
    int base = c * CHUNK;
#pragma unroll
    for (int k = 0; k < CHUNK / 256; ++k) {
        int e = base + k * 256 + tid;
        if (e < E) atomicAdd(&h[dst[e] >> 8], 1);
    }
    __syncthreads();
    for (int i = tid; i < NBUCK; i += 256) bcnt[(size_t)i * NCH + c] = h[i];
}

__global__ __launch_bounds__(128) void k_bscan1(const int* __restrict__ bcnt,
                                                int* __restrict__ bofs,
                                                int* __restrict__ btot, int NCH) {
    __shared__ int tmp[128];
    int b = blockIdx.x, t = threadIdx.x;
    int v = (t < NCH) ? bcnt[(size_t)b * NCH + t] : 0;
    tmp[t] = v;
    __syncthreads();
    for (int off = 1; off < 128; off <<= 1) {
        int u = (t >= off) ? tmp[t - off] : 0;
        __syncthreads();
        tmp[t] += u;
        __syncthreads();
    }
    if (t < NCH) bofs[(size_t)b * NCH + t] = tmp[t] - v;
    if (t == 127) btot[b] = tmp[127];
}

// also zeroes the fp8 sentinel rows (replaces two hipMemsetAsync dispatches)
__global__ __launch_bounds__(512) void k_bscan2(const int* __restrict__ btot,
                                                int* __restrict__ bbase, int nb,
                                                uint32* __restrict__ sent0,
                                                uint32* __restrict__ sent1) {
    __shared__ int tmp[512];
    int t = threadIdx.x;
    if (t < 8) { sent0[t] = 0; sent1[t] = 0; }
    int v = (t < nb) ? btot[t] : 0;
    tmp[t] = v;
    __syncthreads();
    for (int off = 1; off < 512; off <<= 1) {
        int u = (t >= off) ? tmp[t - off] : 0;
        __syncthreads();
        tmp[t] += u;
        __syncthreads();
    }
    if (t < nb) bbase[t] = tmp[t] - v;
    if (t == nb - 1) bbase[nb] = tmp[t];
}

__global__ __launch_bounds__(256) void k_bscatter(const int* __restrict__ ei,
                                                  const int* __restrict__ bbase,
                                                  const int* __restrict__ bofs,
                                                  uint32* __restrict__ ebuf,
                                                  int E, int NBUCK, int NCH) {
    __shared__ int cur[512];
    int c = blockIdx.x, tid = threadIdx.x;
    for (int i = tid; i < NBUCK; i += 256)
        cur[i] = bbase[i] + bofs[(size_t)i * NCH + c];
    __syncthreads();
    int base = c * CHUNK;
#pragma unroll
    for (int k = 0; k < CHUNK / 256; ++k) {
        int e = base + k * 256 + tid;
        if (e < E) {
            int s = ei[e];
            int d = ei[E + e];
            int p = atomicAdd(&cur[d >> 8], 1);
            ebuf[p] = (uint32)s | ((uint32)(d & 255) << 20);
        }
    }
}

__global__ __launch_bounds__(256) void k_bsort(const uint32* __restrict__ ebuf,
                                               const int* __restrict__ bbase,
                                               int* __restrict__ ssrc,
                                               int2* __restrict__ rc,
                                               float* __restrict__ dinv, int N) {
    __shared__ int h[256];
    __shared__ int sc[256];
    __shared__ int cur[256];
    int b = blockIdx.x, tid = threadIdx.x;
    int beg = bbase[b], end = bbase[b + 1];
    h[tid] = 0;
    __syncthreads();
    for (int j = beg + tid; j < end; j += 256)
        atomicAdd(&h[(ebuf[j] >> 20) & 255], 1);
    __syncthreads();
    int v = h[tid];
    sc[tid] = v;
    __syncthreads();
    for (int off = 1; off < 256; off <<= 1) {
        int u = (tid >= off) ? sc[tid - off] : 0;
        __syncthreads();
        sc[tid] += u;
        __syncthreads();
    }
    int rowbase = beg + sc[tid] - v;
    cur[tid] = rowbase;
    int d = b * 256 + tid;
    if (d < N) {
        rc[d] = make_int2(rowbase, v);
        dinv[d] = rsqrtf((float)(v + 1));   // +1 self loop
    }
    __syncthreads();
    for (int j = beg + tid; j < end; j += 256) {
        uint32 w = ebuf[j];
        int p = atomicAdd(&cur[(w >> 20) & 255], 1);
        ssrc[p] = (int)(w & 0xFFFFFu);
    }
}

// ============ bf16 helpers ============

__device__ __forceinline__ short f2bf(float f) {
    __hip_bfloat16 b = __float2bfloat16(f);
    return __builtin_bit_cast(short, b);
}

__device__ __forceinline__ float bf2f(short s) {
    uint32 u = ((uint32)(unsigned short)s) << 16;
    return __builtin_bit_cast(float, u);
}

__device__ __forceinline__ bf16x8 pack_bf16x8(float4 v0, float4 v1) {
    bf16x8 r;
    r[0] = f2bf(v0.x); r[1] = f2bf(v0.y); r[2] = f2bf(v0.z); r[3] = f2bf(v0.w);
    r[4] = f2bf(v1.x); r[5] = f2bf(v1.y); r[6] = f2bf(v1.z); r[7] = f2bf(v1.w);
    return r;
}

// ============ embed GEMM via MFMA: h = x @ We^T ([N,128] @ [128,64]^T) ============
// Output hA is bf16. Layouts (m89-verified): A[lane&15][(lane>>4)*8+j],
// B[(lane>>4)*8+j][lane&15], D[(lane>>4)*4+r][lane&15].

__global__ __launch_bounds__(256) void k_embed(const float* __restrict__ x,
                                               const float* __restrict__ We,
                                               short* __restrict__ h, int N) {
    int lane = threadIdx.x & 63;
    int w = threadIdx.x >> 6;
    int l15 = lane & 15;
    int lg = lane >> 4;                       // 0..3

    bf16x8 B[4][4];
#pragma unroll
    for (int ct = 0; ct < 4; ++ct) {
        const float* wr = We + (size_t)(ct * 16 + l15) * 128 + lg * 8;
#pragma unroll
        for (int ks = 0; ks < 4; ++ks) {
            float4 v0 = *(const float4*)(wr + ks * 32);
            float4 v1 = *(const float4*)(wr + ks * 32 + 4);
            B[ct][ks] = pack_bf16x8(v0, v1);
        }
    }

    int rowbase = blockIdx.x * 256 + w * 64;

    f32x4 acc[4][4];
#pragma unroll
    for (int rt = 0; rt < 4; ++rt)
#pragma unroll
        for (int ct = 0; ct < 4; ++ct)
            acc[rt][ct] = (f32x4){0.f, 0.f, 0.f, 0.f};

#pragma unroll
    for (int ks = 0; ks < 4; ++ks) {
#pragma unroll
        for (int rt = 0; rt < 4; ++rt) {
            int row = rowbase + rt * 16 + l15;
            row = (row < N) ? row : (N - 1);          // clamp; stores predicated
            const float* xr = x + (size_t)row * 128 + ks * 32 + lg * 8;
            float4 v0 = *(const float4*)xr;
            float4 v1 = *(const float4*)(xr + 4);
            bf16x8 a = pack_bf16x8(v0, v1);
#pragma unroll
            for (int ct = 0; ct < 4; ++ct)
                acc[rt][ct] = __builtin_amdgcn_mfma_f32_16x16x32_bf16(
                    a, B[ct][ks], acc[rt][ct], 0, 0, 0);
        }
    }

#pragma unroll
    for (int rt = 0; rt < 4; ++rt) {
        int row0 = rowbase + rt * 16 + lg * 4;
#pragma unroll
        for (int r = 0; r < 4; ++r) {
            int row = row0 + r;
            if (row < N) {
#pragma unroll
                for (int ct = 0; ct < 4; ++ct)
                    h[(size_t)row * 64 + ct * 16 + l15] = f2bf(acc[rt][ct][r]);
            }
        }
    }
}

// ============ GCN layer GEMM via MFMA (bf16 in, split fp8 tables out) ========
// D = Wg . h^T with h PRE-ACTIVATED bf16 (bias+relu fused into k_agg).
// Output split by feature half into tab0/tab1 (3.2 MB each, fits per-XCD L2).

__global__ __launch_bounds__(256) void k_gcn(const short* __restrict__ hin,
                                             const float* __restrict__ Wg,
                                             const float* __restrict__ dinv,
                                             uint32* __restrict__ tab0,
                                             uint32* __restrict__ tab1, int N) {
    int lane = threadIdx.x & 63;
    int w = threadIdx.x >> 6;
    int l15 = lane & 15, lg = lane >> 4;

    bf16x8 A[4][2];
#pragma unroll
    for (int rt = 0; rt < 4; ++rt) {
        const float* wr = Wg + (size_t)(rt * 16 + l15) * 64 + lg * 8;
#pragma unroll
        for (int ks = 0; ks < 2; ++ks) {
            float4 v0 = *(const float4*)(wr + ks * 32);
            float4 v1 = *(const float4*)(wr + ks * 32 + 4);
            A[rt][ks] = pack_bf16x8(v0, v1);
        }
    }

    int nodebase = blockIdx.x * 256 + w * 64;   // wave: 64 nodes = 4 tiles of 16

#pragma unroll
    for (int nt = 0; nt < 4; ++nt) {
        int node = nodebase + nt * 16 + l15;
        int nodec = (node < N) ? node : (N - 1);
        const short* hr = hin + ((size_t)nodec << 6) + lg * 8;

        bf16x8 Bf0 = *(const bf16x8*)(hr);
        bf16x8 Bf1 = *(const bf16x8*)(hr + 32);

        f32x4 acc[4];
#pragma unroll
        for (int rt = 0; rt < 4; ++rt) acc[rt] = (f32x4){0.f, 0.f, 0.f, 0.f};
#pragma unroll
        for (int rt = 0; rt < 4; ++rt)
            acc[rt] = __builtin_amdgcn_mfma_f32_16x16x32_bf16(A[rt][0], Bf0, acc[rt], 0, 0, 0);
#pragma unroll
        for (int rt = 0; rt < 4; ++rt)
            acc[rt] = __builtin_amdgcn_mfma_f32_16x16x32_bf16(A[rt][1], Bf1, acc[rt], 0, 0, 0);

        float s = dinv[nodec];
        if (node < N) {
#pragma unroll
            for (int rt = 0; rt < 4; ++rt) {
                int u = 0;
                u = __builtin_amdgcn_cvt_pk_fp8_f32(acc[rt][0] * s, acc[rt][1] * s, u, false);
                u = __builtin_amdgcn_cvt_pk_fp8_f32(acc[rt][2] * s, acc[rt][3] * s, u, true);
                uint32* tp = (rt < 2) ? tab0 : tab1;
                tp[(size_t)node * 8 + (rt & 1) * 4 + lg] = u;
            }
        }
    }
}

// ============ fp8 CSR aggregate: half-feature pass, 16 dsts/wave =============
// Each 4-lane group owns ONE dst; 16 independent gathers in flight per iter
// (4 quad ssrc loads + 16 shfl + 16 gathers -- halves the remaining dependent
// round trips vs the 8-deep version). Epilogue fuses bias+relu, stores bf16.

__global__ __launch_bounds__(256) void k_agg(const int2* __restrict__ rc,
                                             const int* __restrict__ ssrc,
                                             const float* __restrict__ dinv,
                                             const uint2* __restrict__ tabh,
                                             short* __restrict__ outh,
                                             const float* __restrict__ bias,
                                             int N, int E) {
    int lane = threadIdx.x & 63;
    int wid = threadIdx.x >> 6;
    int q = lane & 3;
    int g = lane >> 2;                          // group 0..15
    int dbase = (blockIdx.x * 4 + wid) * 16;
    if (dbase >= N) return;

    int2 r = rc[min(dbase + (lane & 15), N - 1)];
    int beg = __shfl(r.x, g);
    int deg = __shfl(r.y, g);
    int dg = dbase + g;
    if (dg >= N) deg = 0;

    floatx2 a01 = {0.f, 0.f}, a23 = {0.f, 0.f}, a45 = {0.f, 0.f}, a67 = {0.f, 0.f};
    auto accum = [&](uint2 v) {
        a01 += __builtin_amdgcn_cvt_pk_f32_fp8((int)v.x, false);
        a23 += __builtin_amdgcn_cvt_pk_f32_fp8((int)v.x, true);
        a45 += __builtin_amdgcn_cvt_pk_f32_fp8((int)v.y, false);
        a67 += __builtin_amdgcn_cvt_pk_f32_fp8((int)v.y, true);
    };

    // self loop (each group reads its own dst row once)
    accum(tabh[(size_t)((dg < N) ? dg : N) * 4 + q]);

    int m = deg;
    m = max(m, __shfl_xor(m, 4));
    m = max(m, __shfl_xor(m, 8));
    m = max(m, __shfl_xor(m, 16));
    m = max(m, __shfl_xor(m, 32));
    int maxd = __builtin_amdgcn_readfirstlane(m);

    int base4 = lane & 60;                      // group base lane
    for (int j = 0; j < maxd; j += 16) {
        int i0 = beg + j + q;                   // edges j..j+3 of this group
        int i1 = i0 + 4;
        int i2 = i0 + 8;
        int i3 = i0 + 12;
        int ev0 = ssrc[i0 < E ? i0 : 0];        // ssrc has tail pad; masked below
        int ev1 = ssrc[i1 < E ? i1 : 0];
        int ev2 = ssrc[i2 < E ? i2 : 0];
        int ev3 = ssrc[i3 < E ? i3 : 0];
        int t0  = __shfl(ev0, base4 | 0);
        int t1  = __shfl(ev0, base4 | 1);
        int t2  = __shfl(ev0, base4 | 2);
        int t3  = __shfl(ev0, base4 | 3);
        int t4  = __shfl(ev1, base4 | 0);
        int t5  = __shfl(ev1, base4 | 1);
        int t6  = __shfl(ev1, base4 | 2);
        int t7  = __shfl(ev1, base4 | 3);
        int t8  = __shfl(ev2, base4 | 0);
        int t9  = __shfl(ev2, base4 | 1);
        int ta  = __shfl(ev2, base4 | 2);
        int tb  = __shfl(ev2, base4 | 3);
        int tc  = __shfl(ev3, base4 | 0);
        int td  = __shfl(ev3, base4 | 1);
        int te  = __shfl(ev3, base4 | 2);
        int tf  = __shfl(ev3, base4 | 3);
        t0 = (j +  0 < deg) ? t0 : N;           // sentinel row N = zeros
        t1 = (j +  1 < deg) ? t1 : N;
        t2 = (j +  2 < deg) ? t2 : N;
        t3 = (j +  3 < deg) ? t3 : N;
        t4 = (j +  4 < deg) ? t4 : N;
        t5 = (j +  5 < deg) ? t5 : N;
        t6 = (j +  6 < deg) ? t6 : N;
        t7 = (j +  7 < deg) ? t7 : N;
        t8 = (j +  8 < deg) ? t8 : N;
        t9 = (j +  9 < deg) ? t9 : N;
        ta = (j + 10 < deg) ? ta : N;
        tb = (j + 11 < deg) ? tb : N;
        tc = (j + 12 < deg) ? tc : N;
        td = (j + 13 < deg) ? td : N;
        te = (j + 14 < deg) ? te : N;
        tf = (j + 15 < deg) ? tf : N;
        uint2 v0 = tabh[(size_t)t0 * 4 + q];    // 16 independent gathers in flight
        uint2 v1 = tabh[(size_t)t1 * 4 + q];
        uint2 v2 = tabh[(size_t)t2 * 4 + q];
        uint2 v3 = tabh[(size_t)t3 * 4 + q];
        uint2 v4 = tabh[(size_t)t4 * 4 + q];
        uint2 v5 = tabh[(size_t)t5 * 4 + q];
        uint2 v6 = tabh[(size_t)t6 * 4 + q];
        uint2 v7 = tabh[(size_t)t7 * 4 + q];
        uint2 v8 = tabh[(size_t)t8 * 4 + q];
        uint2 v9 = tabh[(size_t)t9 * 4 + q];
        uint2 va = tabh[(size_t)ta * 4 + q];
        uint2 vb = tabh[(size_t)tb * 4 + q];
        uint2 vc = tabh[(size_t)tc * 4 + q];
        uint2 vd = tabh[(size_t)td * 4 + q];
        uint2 ve = tabh[(size_t)te * 4 + q];
        uint2 vf = tabh[(size_t)tf * 4 + q];
        accum(v0); accum(v1); accum(v2); accum(v3);
        accum(v4); accum(v5); accum(v6); accum(v7);
        accum(v8); accum(v9); accum(va); accum(vb);
        accum(vc); accum(vd); accum(ve); accum(vf);
    }

    if (dg < N) {
        float dd = dinv[dg];
        float4 b0 = *(const float4*)(bias + q * 8);
        float4 b1 = *(const float4*)(bias + q * 8 + 4);
        bf16x8 o;
        o[0] = f2bf(fmaxf(fmaf(dd, a01.x, b0.x), 0.f));
        o[1] = f2bf(fmaxf(fmaf(dd, a01.y, b0.y), 0.f));
        o[2] = f2bf(fmaxf(fmaf(dd, a23.x, b0.z), 0.f));
        o[3] = f2bf(fmaxf(fmaf(dd, a23.y, b0.w), 0.f));
        o[4] = f2bf(fmaxf(fmaf(dd, a45.x, b1.x), 0.f));
        o[5] = f2bf(fmaxf(fmaf(dd, a45.y, b1.y), 0.f));
        o[6] = f2bf(fmaxf(fmaf(dd, a67.x, b1.z), 0.f));
        o[7] = f2bf(fmaxf(fmaf(dd, a67.y, b1.w), 0.f));
        __builtin_nontemporal_store(o, (bf16x8*)(outh + (size_t)dg * 64 + q * 8));
    }
}

// ============ centroid distances + pooling via MFMA ============
// hin is pre-activated bf16. c2 computed in-register from the same fp32
// centroid values loaded for the B-frags (kills the separate k_c2 kernel).

__global__ __launch_bounds__(256) void k_cent(const short* __restrict__ hin,
                                              const float* __restrict__ C,
                                              float* __restrict__ partials, int N) {
    __shared__ float pool4[4][112];
    __shared__ float h2_s[128];
    int tid = threadIdx.x;
    int lane = tid & 63, w = tid >> 6;
    int l15 = lane & 15, lg = lane >> 4;      // lg = 0..3

    bf16x8 B[7][2];
    float c2r[7];
#pragma unroll
    for (int ct = 0; ct < 7; ++ct) {
        int col = ct * 16 + l15;
        float c2p = 0.f;
#pragma unroll
        for (int ks = 0; ks < 2; ++ks) {
            float4 v0 = make_float4(0.f, 0.f, 0.f, 0.f);
            float4 v1 = make_float4(0.f, 0.f, 0.f, 0.f);
            if (col < 100) {
                const float* cr = C + (size_t)col * 64 + ks * 32 + lg * 8;
                v0 = *(const float4*)cr;
                v1 = *(const float4*)(cr + 4);
            }
            B[ct][ks] = pack_bf16x8(v0, v1);
            c2p = fmaf(v0.x, v0.x, c2p); c2p = fmaf(v0.y, v0.y, c2p);
            c2p = fmaf(v0.z, v0.z, c2p); c2p = fmaf(v0.w, v0.w, c2p);
            c2p = fmaf(v1.x, v1.x, c2p); c2p = fmaf(v1.y, v1.y, c2p);
            c2p = fmaf(v1.z, v1.z, c2p); c2p = fmaf(v1.w, v1.w, c2p);
        }
        c2p += __shfl_xor(c2p, 16);
        c2p += __shfl_xor(c2p, 32);
        c2r[ct] = c2p;                         // full ||C[col]||^2, fp32
    }

    int rowbase = blockIdx.x * 128 + w * 32;

    f32x4 acc[2][7];
#pragma unroll
    for (int rt = 0; rt < 2; ++rt)
#pragma unroll
        for (int ct = 0; ct < 7; ++ct)
            acc[rt][ct] = (f32x4){0.f, 0.f, 0.f, 0.f};

#pragma unroll
    for (int rt = 0; rt < 2; ++rt) {
        int row = rowbase + rt * 16 + l15;
        int rowc = (row < N) ? row : (N - 1);     // clamp; excluded from pooling
        const short* hr = hin + ((size_t)rowc << 6) + lg * 8;
        bf16x8 a0 = *(const bf16x8*)(hr);
        bf16x8 a1 = *(const bf16x8*)(hr + 32);

        float h2p = 0.f;
#pragma unroll
        for (int j = 0; j < 8; ++j) {
            float v0 = bf2f(a0[j]);
            float v1 = bf2f(a1[j]);
            h2p = fmaf(v0, v0, h2p);
            h2p = fmaf(v1, v1, h2p);
        }
        h2p += __shfl_xor(h2p, 16);
        h2p += __shfl_xor(h2p, 32);
        if (lg == 0) h2_s[w * 32 + rt * 16 + l15] = h2p;

#pragma unroll
        for (int ct = 0; ct < 7; ++ct)
            acc[rt][ct] = __builtin_amdgcn_mfma_f32_16x16x32_bf16(
                a0, B[ct][0], acc[rt][ct], 0, 0, 0);
#pragma unroll
        for (int ct = 0; ct < 7; ++ct)
            acc[rt][ct] = __builtin_amdgcn_mfma_f32_16x16x32_bf16(
                a1, B[ct][1], acc[rt][ct], 0, 0, 0);
    }

    float S[7] = {0.f, 0.f, 0.f, 0.f, 0.f, 0.f, 0.f};
#pragma unroll
    for (int rt = 0; rt < 2; ++rt) {
#pragma unroll
        for (int r = 0; r < 4; ++r) {
            int row = rowbase + rt * 16 + lg * 4 + r;
            float h2v = h2_s[w * 32 + rt * 16 + lg * 4 + r];
            bool rv = row < N;
#pragma unroll
            for (int ct = 0; ct < 7; ++ct) {
                int col = ct * 16 + l15;
                float G = acc[rt][ct][r];
                float d2 = fmaxf(h2v + c2r[ct] - 2.f * G, 0.f);
                float xx = d2 + 1e-12f;
                float dist = xx * __frsqrt_rn(xx);       // sqrt via rsq, 1 trans op
                S[ct] += (rv && col < 100) ? dist : 0.f;
            }
        }
    }
#pragma unroll
    for (int ct = 0; ct < 7; ++ct) {
        float s = S[ct];
        s += __shfl_xor(s, 16);
        s += __shfl_xor(s, 32);
        if (lg == 0) pool4[w][ct * 16 + l15] = s;   // S[ct]=0 for padded cols
    }
    __syncthreads();
    if (tid < 112) {
        float s = pool4[0][tid] + pool4[1][tid] + pool4[2][tid] + pool4[3][tid];
        partials[(size_t)blockIdx.x * 128 + tid] = s;
    }
}

// ============ output head: reduce partials + apply W_out ============
// 8 groups x 128; 8-wide unrolled strided sum (independent accumulators for MLP).

__global__ __launch_bounds__(1024) void k_out(const float* __restrict__ partials, int nb,
                                              const float* __restrict__ Wout,
                                              const float* __restrict__ bout,
                                              float* __restrict__ out, float invN) {
    __shared__ float ps[8][112];
    int t = threadIdx.x & 127, g = threadIdx.x >> 7;
    if (t < 112) {
        float s0 = 0.f, s1 = 0.f, s2 = 0.f, s3 = 0.f;
        float s4 = 0.f, s5 = 0.f, s6 = 0.f, s7 = 0.f;
        int b = g;
        for (; b + 56 < nb; b += 64) {
            s0 += partials[(size_t)(b     ) * 128 + t];
            s1 += partials[(size_t)(b +  8) * 128 + t];
            s2 += partials[(size_t)(b + 16) * 128 + t];
            s3 += partials[(size_t)(b + 24) * 128 + t];
            s4 += partials[(size_t)(b + 32) * 128 + t];
            s5 += partials[(size_t)(b + 40) * 128 + t];
            s6 += partials[(size_t)(b + 48) * 128 + t];
            s7 += partials[(size_t)(b + 56) * 128 + t];
        }
        for (; b < nb; b += 8) s0 += partials[(size_t)b * 128 + t];
        ps[g][t] = ((s0 + s1) + (s2 + s3)) + ((s4 + s5) + (s6 + s7));
    }
    __syncthreads();
    if (threadIdx.x < 10) {
        int tt = threadIdx.x;
        float s = 0.f;
        for (int k = 0; k < 100; ++k) {
            float p = ps[0][k] + ps[1][k] + ps[2][k] + ps[3][k]
                    + ps[4][k] + ps[5][k] + ps[6][k] + ps[7][k];
            s = fmaf(p, Wout[tt * 100 + k], s);
        }
        out[tt] = s * invN + bout[tt];
    }
}

// ============ launcher ============

extern "C" void kernel_launch(void* const* d_in, const int* in_sizes, int n_in,
                              void* d_out, int out_size, void* d_ws, size_t ws_size,
                              hipStream_t stream) {
    const float* x    = (const float*)d_in[0];
    const int*   ei   = (const int*)d_in[1];
    const float* We   = (const float*)d_in[2];
    const float* Wg   = (const float*)d_in[3];
    const float* bg   = (const float*)d_in[4];
    const float* C    = (const float*)d_in[5];
    const float* Wout = (const float*)d_in[6];
    const float* bout = (const float*)d_in[7];
    float*       out  = (float*)d_out;

    const int N = in_sizes[0] / 128;          // 100000
    const int E = in_sizes[1] / 2;            // 1600000
    const int NBUCK = (N + 255) >> 8;         // 391 dst-buckets
    const int NCH = (E + CHUNK - 1) / CHUNK;  // 98 chunks
    const int NBC = (N + 127) / 128;          // k_cent blocks (782)
    const int NBA = (N + 63) / 64;            // k_agg blocks (1563): 64 dsts/block

    char* ws = (char*)d_ws;
    size_t off = 0;
    auto alloc = [&](size_t bytes) { void* p = ws + off; off += (bytes + 511) & ~(size_t)511; return p; };
    float*  dinv   = (float*)alloc((size_t)N * 4);
    int2*   rc     = (int2*) alloc((size_t)N * 8);
    int*    bcnt   = (int*)  alloc((size_t)NBUCK * NCH * 4);
    int*    bofs   = (int*)  alloc((size_t)NBUCK * NCH * 4);
    int*    btot   = (int*)  alloc((size_t)NBUCK * 4);
    int*    bbase  = (int*)  alloc((size_t)(NBUCK + 1) * 4);
    uint32* ebuf   = (uint32*)alloc((size_t)E * 4);
    int*    ssrc   = (int*)  alloc((size_t)(E + 64) * 4);     // pad for agg reads
    short*  hA     = (short*)alloc((size_t)N * 64 * 2);       // bf16 activations
    uint32* tab0   = (uint32*)alloc((size_t)(N + 1) * 32);    // fp8 feats 0..31 + sentinel
    uint32* tab1   = (uint32*)alloc((size_t)(N + 1) * 32);    // fp8 feats 32..63 + sentinel
    float*  partials = (float*)alloc((size_t)NBC * 128 * 4);

    // bucketed CSR build (no global atomics); k_bscan2 also zeroes sentinels
    k_bhist<<<NCH, 256, 0, stream>>>(ei + E, bcnt, E, NBUCK, NCH);
    k_bscan1<<<NBUCK, 128, 0, stream>>>(bcnt, bofs, btot, NCH);
    k_bscan2<<<1, 512, 0, stream>>>(btot, bbase, NBUCK,
                                    tab0 + (size_t)N * 8, tab1 + (size_t)N * 8);
    k_bscatter<<<NCH, 256, 0, stream>>>(ei, bbase, bofs, ebuf, E, NBUCK, NCH);
    k_bsort<<<NBUCK, 256, 0, stream>>>(ebuf, bbase, ssrc, rc, dinv, N);

    // embed (MFMA bf16 out, 256 rows/block). Layer 0 has no pre-activation.
    k_embed<<<(N + 255) / 256, 256, 0, stream>>>(x, We, hA, N);

    // 3 GCN layers: gemm (bf16 hA -> fp8 tab halves), aggregate per half.
    // k_agg fuses bias+relu of layer l and stores bf16.
    for (int l = 0; l < 3; ++l) {
        k_gcn<<<(N + 255) / 256, 256, 0, stream>>>(hA, Wg + (size_t)l * 64 * 64,
                                                   dinv, tab0, tab1, N);
        k_agg<<<NBA, 256, 0, stream>>>(rc, ssrc, dinv, (const uint2*)tab0,
                                       hA, bg + (size_t)l * 64, N, E);
        k_agg<<<NBA, 256, 0, stream>>>(rc, ssrc, dinv, (const uint2*)tab1,
                                       hA + 32, bg + (size_t)l * 64 + 32, N, E);
    }

    // centroid distances + pooling via MFMA (hA already activated; c2 in-reg)
    k_cent<<<NBC, 256, 0, stream>>>(hA, C, partials, N);

    // head: reduce partials + W_out
    k_out<<<1, 1024, 0, stream>>>(partials, NBC, Wout, bout, out, 1.0f / (float)N);
}